// Round 1
// baseline (1960.935 us; speedup 1.0000x reference)
//
#include <hip/hip_runtime.h>
#include <math.h>

// ---------------- problem constants (from reference) ----------------
constexpr int N0 = 262144, S1 = 32768, S2 = 4096, S3 = 512;
constexpr int E1 = 327680, E2 = 40960, E3 = 5120;
constexpr float NEG = 0.2f, BN_EPS = 1e-5f;

__device__ __forceinline__ float lrelu(float x) { return x > 0.f ? x : NEG * x; }

// ---- fold attention vector into weight: v[h,k] = sum_j att[h,j] * w[(h*256+j)*din + k]
__global__ void fold_kernel(const float* __restrict__ att, const float* __restrict__ w,
                            float* __restrict__ v, int din)
{
    int h = blockIdx.y;
    int k = blockIdx.x * 64 + threadIdx.x;
    if (k >= din) return;
    float acc = 0.f;
    const float* wr = w + (size_t)(h * 256) * din + k;
    const float* ar = att + h * 256;
    for (int j = 0; j < 256; ++j) acc += ar[j] * wr[(size_t)j * din];
    v[h * din + k] = acc;
}

// ---- al[n,h] = dot(x[n,:], v[h,:]) ; one wave per node, 4 waves per block
template<int DIN>
__global__ void al_kernel(const float* __restrict__ x, const float* __restrict__ v,
                          float* __restrict__ al, int n)
{
    __shared__ float vs[4 * DIN];
    int t = threadIdx.x;
    for (int i = t; i < 4 * DIN; i += 256) vs[i] = v[i];
    __syncthreads();
    int node = blockIdx.x * 4 + (t >> 6);
    int lane = t & 63;
    if (node >= n) return;
    float a0 = 0, a1 = 0, a2 = 0, a3 = 0;
    const float* xr = x + (size_t)node * DIN;
    for (int j = lane; j < DIN; j += 64) {
        float xv = xr[j];
        a0 += xv * vs[0 * DIN + j];
        a1 += xv * vs[1 * DIN + j];
        a2 += xv * vs[2 * DIN + j];
        a3 += xv * vs[3 * DIN + j];
    }
    #pragma unroll
    for (int off = 32; off > 0; off >>= 1) {
        a0 += __shfl_down(a0, off);
        a1 += __shfl_down(a1, off);
        a2 += __shfl_down(a2, off);
        a3 += __shfl_down(a3, off);
    }
    if (lane == 0) {
        float* o = al + (size_t)node * 4;
        o[0] = a0; o[1] = a1; o[2] = a2; o[3] = a3;
    }
}

// ---- CSR build ----
__global__ void count_kernel(const int* __restrict__ dst, int E, int* __restrict__ counts)
{
    int e = blockIdx.x * 256 + threadIdx.x;
    if (e < E) atomicAdd(&counts[dst[e]], 1);
}

__global__ void scan_kernel(const int* __restrict__ counts, int* __restrict__ offsets, int size)
{
    __shared__ int lds[1024];
    int t = threadIdx.x;
    int chunk = (size + 1023) >> 10;
    int begin = t * chunk;
    int end = begin + chunk; if (end > size) end = size;
    if (begin > size) begin = size;
    int s = 0;
    for (int i = begin; i < end; ++i) s += counts[i];
    lds[t] = s;
    __syncthreads();
    for (int d = 1; d < 1024; d <<= 1) {
        int v = (t >= d) ? lds[t - d] : 0;
        __syncthreads();
        lds[t] += v;
        __syncthreads();
    }
    int base = (t > 0) ? lds[t - 1] : 0;
    for (int i = begin; i < end; ++i) { offsets[i] = base; base += counts[i]; }
    if (t == 1023) offsets[size] = lds[1023];
}

__global__ void scatter_kernel(const int* __restrict__ dst, int E,
                               int* __restrict__ cursor, int* __restrict__ elist)
{
    int e = blockIdx.x * 256 + threadIdx.x;
    if (e < E) { int p = atomicAdd(&cursor[dst[e]], 1); elist[p] = e; }
}

// ---- fused per-destination softmax + input aggregation ----
// agg[d, h, :] = sum over in-edges (+self loop) of alpha_{e,h} * x[src_e, :]
template<int DIN, int BLOCK>
__global__ void agg_kernel(const float* __restrict__ xa, const float* __restrict__ al_src,
                           const float* __restrict__ al_dst,
                           const int* __restrict__ offsets, const int* __restrict__ elist,
                           const int* __restrict__ edge_src,
                           float* __restrict__ agg)
{
    constexpr int KPT = DIN / BLOCK;
    int d = blockIdx.x;
    int t = threadIdx.x;
    int beg = offsets[d], end = offsets[d + 1];
    float ad[4], m[4], dn[4], w[4];
    #pragma unroll
    for (int h = 0; h < 4; ++h) ad[h] = al_dst[(size_t)d * 4 + h];
    // pass 1: segment max (self loop + edges)
    #pragma unroll
    for (int h = 0; h < 4; ++h) m[h] = lrelu(al_src[(size_t)d * 4 + h] + ad[h]);
    for (int e = beg; e < end; ++e) {
        int s = edge_src[elist[e]];
        #pragma unroll
        for (int h = 0; h < 4; ++h) m[h] = fmaxf(m[h], lrelu(al_src[(size_t)s * 4 + h] + ad[h]));
    }
    // pass 2: denom
    #pragma unroll
    for (int h = 0; h < 4; ++h) dn[h] = expf(lrelu(al_src[(size_t)d * 4 + h] + ad[h]) - m[h]);
    for (int e = beg; e < end; ++e) {
        int s = edge_src[elist[e]];
        #pragma unroll
        for (int h = 0; h < 4; ++h) dn[h] += expf(lrelu(al_src[(size_t)s * 4 + h] + ad[h]) - m[h]);
    }
    #pragma unroll
    for (int h = 0; h < 4; ++h) dn[h] = 1.f / (dn[h] + 1e-16f);
    // pass 3: weighted aggregation of x rows
    float acc[4][KPT];
    {
        #pragma unroll
        for (int h = 0; h < 4; ++h)
            w[h] = expf(lrelu(al_src[(size_t)d * 4 + h] + ad[h]) - m[h]) * dn[h];
        const float* xr = xa + (size_t)d * DIN;
        #pragma unroll
        for (int j = 0; j < KPT; ++j) {
            float xv = xr[t + j * BLOCK];
            #pragma unroll
            for (int h = 0; h < 4; ++h) acc[h][j] = w[h] * xv;
        }
    }
    for (int e = beg; e < end; ++e) {
        int s = edge_src[elist[e]];
        #pragma unroll
        for (int h = 0; h < 4; ++h)
            w[h] = expf(lrelu(al_src[(size_t)s * 4 + h] + ad[h]) - m[h]) * dn[h];
        const float* xr = xa + (size_t)s * DIN;
        #pragma unroll
        for (int j = 0; j < KPT; ++j) {
            float xv = xr[t + j * BLOCK];
            #pragma unroll
            for (int h = 0; h < 4; ++h) acc[h][j] += w[h] * xv;
        }
    }
    float* ag = agg + (size_t)d * 4 * DIN;
    #pragma unroll
    for (int h = 0; h < 4; ++h)
        #pragma unroll
        for (int j = 0; j < KPT; ++j) ag[h * DIN + t + j * BLOCK] = acc[h][j];
}

// ---- tiled fp32 GEMM: C[m,n] (+)= sum_k A[m*lda + aoff(n) + k] * W[n*ldw + k]
// aoff(n) = (n/cph)*headStride if cph>0 (per-head GAT projection), else 0.
// mode: 0 = write, 1 = accumulate, 2 = atomicAdd (split-K over blockIdx.z)
__global__ __launch_bounds__(256) void gemm_kernel(
    const float* __restrict__ A, int lda, int headStride, int cph,
    const float* __restrict__ W, int ldw, int K, int ksplit,
    float* __restrict__ C, int N, int mode)
{
    __shared__ float As[16][65];
    __shared__ float Ws[16][65];
    int n0 = blockIdx.x * 64, m0 = blockIdx.y * 64;
    int ks = blockIdx.z * ksplit;
    int ke = ks + ksplit; if (ke > K) ke = K;
    size_t aoff = cph ? (size_t)(n0 / cph) * headStride : 0;
    int tid = threadIdx.x;
    int lr = tid >> 2, lk = (tid & 3) * 4;
    int tx = tid & 15, ty = tid >> 4;
    float c[4][4] = {};
    const float* Abase = A + (size_t)(m0 + lr) * lda + aoff + lk;
    const float* Wbase = W + (size_t)(n0 + lr) * ldw + lk;
    for (int k0 = ks; k0 < ke; k0 += 16) {
        float4 a4 = *(const float4*)(Abase + k0);
        float4 w4 = *(const float4*)(Wbase + k0);
        As[lk + 0][lr] = a4.x; As[lk + 1][lr] = a4.y;
        As[lk + 2][lr] = a4.z; As[lk + 3][lr] = a4.w;
        Ws[lk + 0][lr] = w4.x; Ws[lk + 1][lr] = w4.y;
        Ws[lk + 2][lr] = w4.z; Ws[lk + 3][lr] = w4.w;
        __syncthreads();
        #pragma unroll
        for (int kk = 0; kk < 16; ++kk) {
            float av[4], wv[4];
            #pragma unroll
            for (int i = 0; i < 4; ++i) av[i] = As[kk][ty * 4 + i];
            #pragma unroll
            for (int j = 0; j < 4; ++j) wv[j] = Ws[kk][tx * 4 + j];
            #pragma unroll
            for (int i = 0; i < 4; ++i)
                #pragma unroll
                for (int j = 0; j < 4; ++j) c[i][j] += av[i] * wv[j];
        }
        __syncthreads();
    }
    #pragma unroll
    for (int i = 0; i < 4; ++i) {
        int m = m0 + ty * 4 + i;
        float* crow = C + (size_t)m * N + n0 + tx * 4;
        #pragma unroll
        for (int j = 0; j < 4; ++j) {
            if (mode == 0) crow[j] = c[i][j];
            else if (mode == 1) crow[j] += c[i][j];
            else atomicAdd(&crow[j], c[i][j]);
        }
    }
}

// ---- repack layer-3 weights: wp[j, h*1024+k] = 0.25 * w[(h*256+j)*1024 + k]
__global__ void repack_w3(const float* __restrict__ w, float* __restrict__ wp)
{
    long i = (long)blockIdx.x * 256 + threadIdx.x;
    if (i >= 256L * 4096) return;
    int j = (int)(i >> 12);
    int hk = (int)(i & 4095);
    int h = hk >> 10, k = hk & 1023;
    wp[i] = 0.25f * w[((size_t)(h * 256 + j)) * 1024 + k];
}

// ---- batchnorm: column sums / sums of squares ----
__global__ void bn_reduce(const float* __restrict__ h, int M, int N,
                          float* __restrict__ sum, float* __restrict__ sumsq)
{
    int c = blockIdx.x * 64 + (threadIdx.x & 63);
    int rbeg = blockIdx.y * 2048 + (threadIdx.x >> 6);
    int rend = blockIdx.y * 2048 + 2048; if (rend > M) rend = M;
    float s = 0.f, q = 0.f;
    for (int r = rbeg; r < rend; r += 4) {
        float v = h[(size_t)r * N + c];
        s += v; q += v * v;
    }
    __shared__ float ls[256], lq[256];
    ls[threadIdx.x] = s; lq[threadIdx.x] = q;
    __syncthreads();
    if (threadIdx.x < 64) {
        int t = threadIdx.x;
        s = ls[t] + ls[t + 64] + ls[t + 128] + ls[t + 192];
        q = lq[t] + lq[t + 64] + lq[t + 128] + lq[t + 192];
        atomicAdd(&sum[c], s);
        atomicAdd(&sumsq[c], q);
    }
}

__global__ void bn_finalize(const float* __restrict__ sum, const float* __restrict__ sumsq,
                            const float* __restrict__ gamma, const float* __restrict__ beta,
                            float* __restrict__ scale, float* __restrict__ shift, int M, int N)
{
    int c = blockIdx.x * 256 + threadIdx.x;
    if (c >= N) return;
    float mu = sum[c] / (float)M;
    float var = sumsq[c] / (float)M - mu * mu;
    float sc = gamma[c] * rsqrtf(var + BN_EPS);
    scale[c] = sc;
    shift[c] = beta[c] - mu * sc;
}

__global__ void norm_elu(float* __restrict__ h, const float* __restrict__ scale,
                         const float* __restrict__ shift, int N, long total)
{
    long i = (long)blockIdx.x * 256 + threadIdx.x;
    if (i >= total) return;
    int c = (int)(i % N);
    float v = h[i] * scale[c] + shift[c];
    h[i] = v > 0.f ? v : expm1f(v);
}

// =====================================================================
extern "C" void kernel_launch(void* const* d_in, const int* in_sizes, int n_in,
                              void* d_out, int out_size, void* d_ws, size_t ws_size,
                              hipStream_t stream)
{
    const float* x = (const float*)d_in[0];
    // per-layer params: base index 1 + (layer-1)*9
    auto P = [&](int layer, int slot) -> const float* {
        return (const float*)d_in[1 + (layer - 1) * 9 + slot];
    };
    const int* edge_src[3] = { (const int*)d_in[28], (const int*)d_in[30], (const int*)d_in[32] };
    const int* edge_dst[3] = { (const int*)d_in[29], (const int*)d_in[31], (const int*)d_in[33] };
    const int Es[3] = { E1, E2, E3 };

    // -------- workspace carve --------
    char* wsb = (char*)d_ws;
    size_t off = 0;
    auto alloc = [&](size_t bytes) -> void* {
        void* p = wsb + off;
        off = (off + bytes + 255) & ~(size_t)255;
        return p;
    };
    float* x1     = (float*)alloc((size_t)S1 * 1024 * 4);      // 134.2 MB
    float* x2     = (float*)alloc((size_t)S2 * 1024 * 4);      // 16.8 MB
    float* agg    = (float*)alloc((size_t)S1 * 4 * 128 * 4);   // 67.1 MB (max over layers)
    float* al_src = (float*)alloc((size_t)N0 * 4 * 4);         // 4.2 MB
    float* al_dst = (float*)alloc((size_t)S1 * 4 * 4);
    float* vsrc   = (float*)alloc(4 * 1024 * 4);
    float* vdst   = (float*)alloc(4 * 1024 * 4);
    float* w3p    = (float*)alloc((size_t)256 * 4096 * 4);     // 4.2 MB
    int*   offsets= (int*)alloc((size_t)(S1 + 1) * 4);
    int*   cursor = (int*)alloc((size_t)S1 * 4);
    int*   counts = (int*)alloc((size_t)S1 * 4);
    int*   elist  = (int*)alloc((size_t)E1 * 4);
    float* bnsum  = (float*)alloc(1024 * 4);
    float* bnsq   = (float*)alloc(1024 * 4);

    auto run_layer = [&](int L, const float* xa, int n_all, int size, int din, int dfull,
                         float* hbuf, bool concat)
    {
        const float* wsrc  = P(L, 0);
        const float* wdst  = P(L, 1);
        const float* asrc  = P(L, 2);
        const float* adst  = P(L, 3);
        const float* wskip = P(L, 5);
        const float* gamma = P(L, 7);
        const float* beta  = P(L, 8);
        const int* esrc = edge_src[L - 1];
        const int* edst = edge_dst[L - 1];
        int E = Es[L - 1];

        // fold attention into weights
        fold_kernel<<<dim3((din + 63) / 64, 4), 64, 0, stream>>>(asrc, wsrc, vsrc, din);
        fold_kernel<<<dim3((din + 63) / 64, 4), 64, 0, stream>>>(adst, wdst, vdst, din);
        // attention logits per node
        if (din == 128) {
            al_kernel<128><<<(n_all + 3) / 4, 256, 0, stream>>>(xa, vsrc, al_src, n_all);
            al_kernel<128><<<(size + 3) / 4, 256, 0, stream>>>(xa, vdst, al_dst, size);
        } else {
            al_kernel<1024><<<(n_all + 3) / 4, 256, 0, stream>>>(xa, vsrc, al_src, n_all);
            al_kernel<1024><<<(size + 3) / 4, 256, 0, stream>>>(xa, vdst, al_dst, size);
        }
        // CSR by destination
        hipMemsetAsync(counts, 0, (size_t)size * 4, stream);
        count_kernel<<<(E + 255) / 256, 256, 0, stream>>>(edst, E, counts);
        scan_kernel<<<1, 1024, 0, stream>>>(counts, offsets, size);
        hipMemcpyAsync(cursor, offsets, (size_t)size * 4, hipMemcpyDeviceToDevice, stream);
        scatter_kernel<<<(E + 255) / 256, 256, 0, stream>>>(edst, E, cursor, elist);
        // fused softmax + aggregation
        if (din == 128)
            agg_kernel<128, 128><<<size, 128, 0, stream>>>(xa, al_src, al_dst, offsets, elist, esrc, agg);
        else
            agg_kernel<1024, 256><<<size, 256, 0, stream>>>(xa, al_src, al_dst, offsets, elist, esrc, agg);
        // projections (biases cancel under batchnorm)
        if (concat) {
            gemm_kernel<<<dim3(dfull / 64, size / 64, 1), 256, 0, stream>>>(
                xa, din, 0, 0, wskip, din, din, din, hbuf, dfull, 0);
            gemm_kernel<<<dim3(dfull / 64, size / 64, 1), 256, 0, stream>>>(
                agg, 4 * din, din, 256, wsrc, din, din, din, hbuf, dfull, 1);
        } else {
            repack_w3<<<(256 * 4096 + 255) / 256, 256, 0, stream>>>(wsrc, w3p);
            hipMemsetAsync(hbuf, 0, (size_t)size * dfull * 4, stream);
            gemm_kernel<<<dim3(dfull / 64, size / 64, din / 256), 256, 0, stream>>>(
                xa, din, 0, 0, wskip, din, din, 256, hbuf, dfull, 2);
            gemm_kernel<<<dim3(dfull / 64, size / 64, 16), 256, 0, stream>>>(
                agg, 4096, 0, 0, w3p, 4096, 4096, 256, hbuf, dfull, 2);
        }
        // batchnorm + elu (in place on hbuf)
        hipMemsetAsync(bnsum, 0, (size_t)dfull * 4, stream);
        hipMemsetAsync(bnsq, 0, (size_t)dfull * 4, stream);
        bn_reduce<<<dim3(dfull / 64, (size + 2047) / 2048), 256, 0, stream>>>(hbuf, size, dfull, bnsum, bnsq);
        bn_finalize<<<(dfull + 255) / 256, 256, 0, stream>>>(bnsum, bnsq, gamma, beta, bnsum, bnsq, size, dfull);
        norm_elu<<<(int)(((long)size * dfull + 255) / 256), 256, 0, stream>>>(
            hbuf, bnsum, bnsq, dfull, (long)size * dfull);
    };

    run_layer(1, x,  N0, S1, 128,  1024, x1, true);
    run_layer(2, x1, S1, S2, 1024, 1024, x2, true);
    run_layer(3, x2, S2, S3, 1024, 256, (float*)d_out, false);
}

// Round 2
// 1037.042 us; speedup vs baseline: 1.8909x; 1.8909x over previous
//
#include <hip/hip_runtime.h>
#include <math.h>

// ---------------- problem constants (from reference) ----------------
constexpr int N0 = 262144, S1 = 32768, S2 = 4096, S3 = 512;
constexpr int E1 = 327680, E2 = 40960, E3 = 5120;
constexpr float NEG = 0.2f, BN_EPS = 1e-5f;

typedef __attribute__((ext_vector_type(8))) short short8;   // 8 bf16 (4 VGPRs)
typedef __attribute__((ext_vector_type(4))) float f32x4;    // MFMA acc

__device__ __forceinline__ float lrelu(float x) { return x > 0.f ? x : NEG * x; }

__device__ __forceinline__ unsigned short f2b(float f) {  // f32 -> bf16 RNE
    unsigned int u = __float_as_uint(f);
    return (unsigned short)((u + 0x7FFFu + ((u >> 16) & 1u)) >> 16);
}

__device__ __forceinline__ void ld4(const float* __restrict__ p, float* o) {
    float4 v = *(const float4*)p;
    o[0] = v.x; o[1] = v.y; o[2] = v.z; o[3] = v.w;
}

// ---- fold attention vector into weight: v[h,k] = sum_j att[h,j] * w[(h*256+j)*din + k]
__global__ void fold_kernel(const float* __restrict__ att, const float* __restrict__ w,
                            float* __restrict__ v, int din)
{
    int h = blockIdx.y;
    int k = blockIdx.x * 64 + threadIdx.x;
    if (k >= din) return;
    float acc = 0.f;
    const float* wr = w + (size_t)(h * 256) * din + k;
    const float* ar = att + h * 256;
    for (int j = 0; j < 256; ++j) acc += ar[j] * wr[(size_t)j * din];
    v[h * din + k] = acc;
}

// ---- al[n,h] = dot(x[n,:], v[h,:]) ; one wave per node, 4 waves per block
template<int DIN>
__global__ void al_kernel(const float* __restrict__ x, const float* __restrict__ v,
                          float* __restrict__ al, int n)
{
    __shared__ float vs[4 * DIN];
    int t = threadIdx.x;
    for (int i = t; i < 4 * DIN; i += 256) vs[i] = v[i];
    __syncthreads();
    int node = blockIdx.x * 4 + (t >> 6);
    int lane = t & 63;
    if (node >= n) return;
    float a0 = 0, a1 = 0, a2 = 0, a3 = 0;
    const float* xr = x + (size_t)node * DIN;
    for (int j = lane; j < DIN; j += 64) {
        float xv = xr[j];
        a0 += xv * vs[0 * DIN + j];
        a1 += xv * vs[1 * DIN + j];
        a2 += xv * vs[2 * DIN + j];
        a3 += xv * vs[3 * DIN + j];
    }
    #pragma unroll
    for (int off = 32; off > 0; off >>= 1) {
        a0 += __shfl_down(a0, off);
        a1 += __shfl_down(a1, off);
        a2 += __shfl_down(a2, off);
        a3 += __shfl_down(a3, off);
    }
    if (lane == 0) {
        float* o = al + (size_t)node * 4;
        o[0] = a0; o[1] = a1; o[2] = a2; o[3] = a3;
    }
}

// ---- CSR build ----
__global__ void count_kernel(const int* __restrict__ dst, int E, int* __restrict__ counts)
{
    int e = blockIdx.x * 256 + threadIdx.x;
    if (e < E) atomicAdd(&counts[dst[e]], 1);
}

__global__ void scan_kernel(const int* __restrict__ counts, int* __restrict__ offsets, int size)
{
    __shared__ int lds[1024];
    int t = threadIdx.x;
    int chunk = (size + 1023) >> 10;
    int begin = t * chunk;
    int end = begin + chunk; if (end > size) end = size;
    if (begin > size) begin = size;
    int s = 0;
    for (int i = begin; i < end; ++i) s += counts[i];
    lds[t] = s;
    __syncthreads();
    for (int d = 1; d < 1024; d <<= 1) {
        int v = (t >= d) ? lds[t - d] : 0;
        __syncthreads();
        lds[t] += v;
        __syncthreads();
    }
    int base = (t > 0) ? lds[t - 1] : 0;
    for (int i = begin; i < end; ++i) { offsets[i] = base; base += counts[i]; }
    if (t == 1023) offsets[size] = lds[1023];
}

__global__ void scatter_kernel(const int* __restrict__ dst, int E,
                               int* __restrict__ cursor, int* __restrict__ elist)
{
    int e = blockIdx.x * 256 + threadIdx.x;
    if (e < E) { int p = atomicAdd(&cursor[dst[e]], 1); elist[p] = e; }
}

// ---- per-destination softmax stats: m, 1/(denom+eps), self-alpha ----
__global__ void mdn_kernel(const float* __restrict__ als, const float* __restrict__ ald,
                           const int* __restrict__ offsets, const int* __restrict__ elist,
                           const int* __restrict__ esrc, int size,
                           float* __restrict__ m4, float* __restrict__ rdn,
                           float* __restrict__ aself)
{
    int d = blockIdx.x * 256 + threadIdx.x;
    if (d >= size) return;
    float ad[4], sl[4], m[4], q[4], dn[4];
    ld4(ald + 4 * (size_t)d, ad);
    ld4(als + 4 * (size_t)d, q);
    #pragma unroll
    for (int h = 0; h < 4; ++h) { sl[h] = lrelu(q[h] + ad[h]); m[h] = sl[h]; }
    int beg = offsets[d], end = offsets[d + 1];
    for (int p = beg; p < end; ++p) {
        int s = esrc[elist[p]];
        ld4(als + 4 * (size_t)s, q);
        #pragma unroll
        for (int h = 0; h < 4; ++h) m[h] = fmaxf(m[h], lrelu(q[h] + ad[h]));
    }
    #pragma unroll
    for (int h = 0; h < 4; ++h) dn[h] = expf(sl[h] - m[h]);
    for (int p = beg; p < end; ++p) {
        int s = esrc[elist[p]];
        ld4(als + 4 * (size_t)s, q);
        #pragma unroll
        for (int h = 0; h < 4; ++h) dn[h] += expf(lrelu(q[h] + ad[h]) - m[h]);
    }
    #pragma unroll
    for (int h = 0; h < 4; ++h) {
        float r = 1.f / (dn[h] + 1e-16f);
        m4[4 * (size_t)d + h] = m[h];
        rdn[4 * (size_t)d + h] = r;
        aself[4 * (size_t)d + h] = expf(sl[h] - m[h]) * r;
    }
}

// ---- per-edge alpha ----
__global__ void alpha_kernel(const float* __restrict__ als, const float* __restrict__ ald,
                             const int* __restrict__ esrc, const int* __restrict__ edst,
                             const float* __restrict__ m4, const float* __restrict__ rdn,
                             int E, float* __restrict__ walpha)
{
    int e = blockIdx.x * 256 + threadIdx.x;
    if (e >= E) return;
    int d = edst[e], s = esrc[e];
    float as_[4], ad_[4], m[4], r[4];
    ld4(als + 4 * (size_t)s, as_);
    ld4(ald + 4 * (size_t)d, ad_);
    ld4(m4 + 4 * (size_t)d, m);
    ld4(rdn + 4 * (size_t)d, r);
    float4 w;
    w.x = expf(lrelu(as_[0] + ad_[0]) - m[0]) * r[0];
    w.y = expf(lrelu(as_[1] + ad_[1]) - m[1]) * r[1];
    w.z = expf(lrelu(as_[2] + ad_[2]) - m[2]) * r[2];
    w.w = expf(lrelu(as_[3] + ad_[3]) - m[3]) * r[3];
    *(float4*)(walpha + 4 * (size_t)e) = w;
}

// ---- aggregation with precomputed alpha; writes bf16 ----
template<int DIN, int BLOCK>
__global__ void agg_kernel(const float* __restrict__ xa, const float* __restrict__ walpha,
                           const float* __restrict__ aself,
                           const int* __restrict__ offsets, const int* __restrict__ elist,
                           const int* __restrict__ esrc, unsigned short* __restrict__ aggb)
{
    constexpr int VEC = DIN / BLOCK;  // 1 or 4
    int d = blockIdx.x, t = threadIdx.x;
    int beg = offsets[d], end = offsets[d + 1];
    float w[4], xv[4];
    float acc[4][VEC];
    ld4(aself + 4 * (size_t)d, w);
    {
        const float* xr = xa + (size_t)d * DIN + VEC * t;
        if constexpr (VEC == 4) ld4(xr, xv); else xv[0] = xr[0];
        #pragma unroll
        for (int h = 0; h < 4; ++h)
            #pragma unroll
            for (int j = 0; j < VEC; ++j) acc[h][j] = w[h] * xv[j];
    }
    for (int p = beg; p < end; ++p) {
        int e = elist[p];
        int s = esrc[e];
        ld4(walpha + 4 * (size_t)e, w);
        const float* xr = xa + (size_t)s * DIN + VEC * t;
        if constexpr (VEC == 4) ld4(xr, xv); else xv[0] = xr[0];
        #pragma unroll
        for (int h = 0; h < 4; ++h)
            #pragma unroll
            for (int j = 0; j < VEC; ++j) acc[h][j] += w[h] * xv[j];
    }
    unsigned short* og = aggb + (size_t)d * 4 * DIN;
    #pragma unroll
    for (int h = 0; h < 4; ++h) {
        if constexpr (VEC == 4) {
            ushort4 u;
            u.x = f2b(acc[h][0]); u.y = f2b(acc[h][1]);
            u.z = f2b(acc[h][2]); u.w = f2b(acc[h][3]);
            *(ushort4*)(og + h * DIN + 4 * t) = u;
        } else {
            og[h * DIN + t] = f2b(acc[h][0]);
        }
    }
}

// ---- f32 -> bf16 convert ----
__global__ void conv_kernel(const float* __restrict__ src, unsigned short* __restrict__ dst, long n)
{
    long i = ((long)blockIdx.x * 256 + threadIdx.x) * 4;
    if (i >= n) return;
    float4 v = *(const float4*)(src + i);
    ushort4 u;
    u.x = f2b(v.x); u.y = f2b(v.y); u.z = f2b(v.z); u.w = f2b(v.w);
    *(ushort4*)(dst + i) = u;
}

// ---- repack layer-3 GAT weights to bf16 with mean fold: wp[j][h*1024+k] = 0.25*w[(h*256+j)*1024+k]
__global__ void repack_w3b(const float* __restrict__ w, unsigned short* __restrict__ wp)
{
    long i = (long)blockIdx.x * 256 + threadIdx.x;
    if (i >= 256L * 4096) return;
    int j = (int)(i >> 12);
    int hk = (int)(i & 4095);
    int h = hk >> 10, k = hk & 1023;
    wp[i] = f2b(0.25f * w[((size_t)(h * 256 + j)) * 1024 + k]);
}

// ---- fused dual-phase bf16 MFMA GEMM + BN column stats ----
// C[m,n] = sum_k A1[m,k]*W1[n,k]  +  sum_k A2[m, aoff2(n)+k]*W2[n,k]
// aoff2(n) = (n0/cph2)*hs2 for the GAT per-head window (cph2=0 -> 0).
template<int BM, int BN>
__global__ __launch_bounds__(256) void gemm2_kernel(
    const unsigned short* __restrict__ A1, int lda1, const unsigned short* __restrict__ W1, int K1,
    const unsigned short* __restrict__ A2, int lda2, const unsigned short* __restrict__ W2, int K2,
    int hs2, int cph2,
    float* __restrict__ C, int N,
    float* __restrict__ bnsum, float* __restrict__ bnsq, int doStats)
{
    constexpr int WM = BM / 2, WN = BN / 2;    // per-wave output tile (2x2 waves)
    constexpr int TM = WM / 16, TN = WN / 16;  // 16x16 fragments per wave
    __shared__ __align__(16) unsigned short As[BM * 40];  // 32 k + 8 pad per row
    __shared__ __align__(16) unsigned short Bs[BN * 40];
    __shared__ float sbn[2 * BN];
    int tid = threadIdx.x;
    int n0 = blockIdx.x * BN, m0 = blockIdx.y * BM;
    int l = tid & 63, l16 = l & 15, kq = l >> 4;
    int wid = tid >> 6, wr = wid >> 1, wc = wid & 1;

    f32x4 acc[TM][TN];
    #pragma unroll
    for (int mi = 0; mi < TM; ++mi)
        #pragma unroll
        for (int ni = 0; ni < TN; ++ni) acc[mi][ni] = (f32x4){0.f, 0.f, 0.f, 0.f};

    #pragma unroll
    for (int ph = 0; ph < 2; ++ph) {
        const unsigned short* Ap = ph ? A2 + (size_t)m0 * lda2 + (cph2 ? (size_t)(n0 / cph2) * hs2 : 0)
                                      : A1 + (size_t)m0 * lda1;
        int lda = ph ? lda2 : lda1;
        const unsigned short* Wp = ph ? W2 + (size_t)n0 * K2 : W1 + (size_t)n0 * K1;
        int ldw = ph ? K2 : K1;
        int K = ph ? K2 : K1;
        for (int k0 = 0; k0 < K; k0 += 32) {
            for (int c = tid; c < BM * 4; c += 256) {
                int r = c >> 2, ch = (c & 3) << 3;
                *(uint4*)&As[r * 40 + ch] = *(const uint4*)(Ap + (size_t)r * lda + k0 + ch);
            }
            for (int c = tid; c < BN * 4; c += 256) {
                int r = c >> 2, ch = (c & 3) << 3;
                *(uint4*)&Bs[r * 40 + ch] = *(const uint4*)(Wp + (size_t)r * ldw + k0 + ch);
            }
            __syncthreads();
            short8 af[TM], bfr[TN];
            #pragma unroll
            for (int mi = 0; mi < TM; ++mi)
                af[mi] = *(const short8*)&As[(wr * WM + mi * 16 + l16) * 40 + (kq << 3)];
            #pragma unroll
            for (int ni = 0; ni < TN; ++ni)
                bfr[ni] = *(const short8*)&Bs[(wc * WN + ni * 16 + l16) * 40 + (kq << 3)];
            #pragma unroll
            for (int mi = 0; mi < TM; ++mi)
                #pragma unroll
                for (int ni = 0; ni < TN; ++ni)
                    acc[mi][ni] = __builtin_amdgcn_mfma_f32_16x16x32_bf16(
                        af[mi], bfr[ni], acc[mi][ni], 0, 0, 0);
            __syncthreads();
        }
    }

    if (tid < 2 * BN) sbn[tid] = 0.f;
    __syncthreads();

    #pragma unroll
    for (int ni = 0; ni < TN; ++ni) {
        int col = wc * WN + ni * 16 + l16;
        float s = 0.f, q = 0.f;
        #pragma unroll
        for (int mi = 0; mi < TM; ++mi) {
            int rowb = wr * WM + mi * 16 + (kq << 2);
            #pragma unroll
            for (int r = 0; r < 4; ++r) {
                float v = acc[mi][ni][r];
                C[(size_t)(m0 + rowb + r) * N + n0 + col] = v;
                s += v; q += v * v;
            }
        }
        if (doStats) {
            atomicAdd(&sbn[col * 2 + 0], s);
            atomicAdd(&sbn[col * 2 + 1], q);
        }
    }
    if (doStats) {
        __syncthreads();
        if (tid < BN) {
            atomicAdd(&bnsum[n0 + tid], sbn[tid * 2 + 0]);
            atomicAdd(&bnsq[n0 + tid], sbn[tid * 2 + 1]);
        }
    }
}

// ---- BN finalize + apply ----
__global__ void bn_finalize(const float* __restrict__ sum, const float* __restrict__ sumsq,
                            const float* __restrict__ gamma, const float* __restrict__ beta,
                            float* __restrict__ scale, float* __restrict__ shift, int M, int N)
{
    int c = blockIdx.x * 256 + threadIdx.x;
    if (c >= N) return;
    float mu = sum[c] / (float)M;
    float var = sumsq[c] / (float)M - mu * mu;
    float sc = gamma[c] * rsqrtf(var + BN_EPS);
    scale[c] = sc;
    shift[c] = beta[c] - mu * sc;
}

__global__ void norm_elu(float* __restrict__ h, const float* __restrict__ scale,
                         const float* __restrict__ shift, int N, long total)
{
    long i = (long)blockIdx.x * 256 + threadIdx.x;
    if (i >= total) return;
    int c = (int)(i % N);
    float v = h[i] * scale[c] + shift[c];
    h[i] = v > 0.f ? v : expm1f(v);
}

// =====================================================================
extern "C" void kernel_launch(void* const* d_in, const int* in_sizes, int n_in,
                              void* d_out, int out_size, void* d_ws, size_t ws_size,
                              hipStream_t stream)
{
    const float* x = (const float*)d_in[0];
    auto P = [&](int layer, int slot) -> const float* {
        return (const float*)d_in[1 + (layer - 1) * 9 + slot];
    };
    const int* edge_src[3] = { (const int*)d_in[28], (const int*)d_in[30], (const int*)d_in[32] };
    const int* edge_dst[3] = { (const int*)d_in[29], (const int*)d_in[31], (const int*)d_in[33] };
    const int Es[3] = { E1, E2, E3 };

    // -------- workspace carve --------
    char* wsb = (char*)d_ws;
    size_t off = 0;
    auto alloc = [&](size_t bytes) -> void* {
        void* p = wsb + off;
        off = (off + bytes + 255) & ~(size_t)255;
        return p;
    };
    float* x1      = (float*)alloc((size_t)S1 * 1024 * 4);          // 134.2 MB
    float* x2      = (float*)alloc((size_t)S2 * 1024 * 4);          // 16.8 MB
    unsigned short* aggb   = (unsigned short*)alloc((size_t)S2 * 4096 * 2); // 33.6 MB (max layer)
    unsigned short* xb     = (unsigned short*)alloc((size_t)S1 * 128 * 2);  // 8.4 MB (max layer)
    unsigned short* wskipb = (unsigned short*)alloc((size_t)1024 * 1024 * 2);
    unsigned short* wsrcb  = (unsigned short*)alloc((size_t)1024 * 1024 * 2);
    float* al_src  = (float*)alloc((size_t)N0 * 4 * 4);             // 4.2 MB
    float* al_dst  = (float*)alloc((size_t)S1 * 4 * 4);
    float* vsrc    = (float*)alloc(4 * 1024 * 4);
    float* vdst    = (float*)alloc(4 * 1024 * 4);
    float* m4      = (float*)alloc((size_t)S1 * 4 * 4);
    float* rdn     = (float*)alloc((size_t)S1 * 4 * 4);
    float* aself   = (float*)alloc((size_t)S1 * 4 * 4);
    float* walpha  = (float*)alloc((size_t)E1 * 4 * 4);             // 5.2 MB
    int*   offsets = (int*)alloc((size_t)(S1 + 1) * 4);
    int*   cursor  = (int*)alloc((size_t)S1 * 4);
    int*   counts  = (int*)alloc((size_t)S1 * 4);
    int*   elist   = (int*)alloc((size_t)E1 * 4);
    float* bnsum   = (float*)alloc(1024 * 4);
    float* bnsq    = (float*)alloc(1024 * 4);

    auto run_layer = [&](int L, const float* xa, int n_all, int size, int din, int dfull,
                         float* hbuf)
    {
        const float* wsrc  = P(L, 0);
        const float* wdst  = P(L, 1);
        const float* asrc  = P(L, 2);
        const float* adst  = P(L, 3);
        const float* wskip = P(L, 5);
        const float* gamma = P(L, 7);
        const float* beta  = P(L, 8);
        const int* esrc = edge_src[L - 1];
        const int* edst = edge_dst[L - 1];
        int E = Es[L - 1];

        // fold attention into weights; attention logits
        fold_kernel<<<dim3((din + 63) / 64, 4), 64, 0, stream>>>(asrc, wsrc, vsrc, din);
        fold_kernel<<<dim3((din + 63) / 64, 4), 64, 0, stream>>>(adst, wdst, vdst, din);
        if (din == 128) {
            al_kernel<128><<<(n_all + 3) / 4, 256, 0, stream>>>(xa, vsrc, al_src, n_all);
            al_kernel<128><<<(size + 3) / 4, 256, 0, stream>>>(xa, vdst, al_dst, size);
        } else {
            al_kernel<1024><<<(n_all + 3) / 4, 256, 0, stream>>>(xa, vsrc, al_src, n_all);
            al_kernel<1024><<<(size + 3) / 4, 256, 0, stream>>>(xa, vdst, al_dst, size);
        }
        // CSR by destination
        hipMemsetAsync(counts, 0, (size_t)size * 4, stream);
        count_kernel<<<(E + 255) / 256, 256, 0, stream>>>(edst, E, counts);
        scan_kernel<<<1, 1024, 0, stream>>>(counts, offsets, size);
        hipMemcpyAsync(cursor, offsets, (size_t)size * 4, hipMemcpyDeviceToDevice, stream);
        scatter_kernel<<<(E + 255) / 256, 256, 0, stream>>>(edst, E, cursor, elist);
        // softmax stats + per-edge alpha
        mdn_kernel<<<(size + 255) / 256, 256, 0, stream>>>(al_src, al_dst, offsets, elist, esrc,
                                                           size, m4, rdn, aself);
        alpha_kernel<<<(E + 255) / 256, 256, 0, stream>>>(al_src, al_dst, esrc, edst, m4, rdn,
                                                          E, walpha);
        // aggregation (bf16 out)
        if (din == 128)
            agg_kernel<128, 128><<<size, 128, 0, stream>>>(xa, walpha, aself, offsets, elist, esrc, aggb);
        else
            agg_kernel<1024, 256><<<size, 256, 0, stream>>>(xa, walpha, aself, offsets, elist, esrc, aggb);
        // bf16 operand prep
        conv_kernel<<<(int)(((long)size * din / 4 + 255) / 256), 256, 0, stream>>>(xa, xb, (long)size * din);
        conv_kernel<<<(int)(((long)dfull * din / 4 + 255) / 256), 256, 0, stream>>>(wskip, wskipb, (long)dfull * din);
        if (L < 3)
            conv_kernel<<<(int)((1024L * din / 4 + 255) / 256), 256, 0, stream>>>(wsrc, wsrcb, 1024L * din);
        else
            repack_w3b<<<(256 * 4096 + 255) / 256, 256, 0, stream>>>(wsrc, wsrcb);
        // fused GEMM (skip + GAT) with BN stats
        hipMemsetAsync(bnsum, 0, (size_t)dfull * 4, stream);
        hipMemsetAsync(bnsq, 0, (size_t)dfull * 4, stream);
        if (L < 3) {
            gemm2_kernel<128, 128><<<dim3(dfull / 128, size / 128), 256, 0, stream>>>(
                xb, din, wskipb, din,
                aggb, 4 * din, wsrcb, din, din, 256,
                hbuf, dfull, bnsum, bnsq, 1);
        } else {
            gemm2_kernel<64, 64><<<dim3(dfull / 64, size / 64), 256, 0, stream>>>(
                xb, din, wskipb, din,
                aggb, 4 * din, wsrcb, 4 * din, 0, 0,
                hbuf, dfull, bnsum, bnsq, 1);
        }
        // batchnorm + elu
        bn_finalize<<<(dfull + 255) / 256, 256, 0, stream>>>(bnsum, bnsq, gamma, beta, bnsum, bnsq, size, dfull);
        norm_elu<<<(int)(((long)size * dfull + 255) / 256), 256, 0, stream>>>(
            hbuf, bnsum, bnsq, dfull, (long)size * dfull);
    };

    run_layer(1, x,  N0, S1, 128,  1024, x1);
    run_layer(2, x1, S1, S2, 1024, 1024, x2);
    run_layer(3, x2, S2, S3, 1024, 256, (float*)d_out);
}

// Round 3
// 895.174 us; speedup vs baseline: 2.1906x; 1.1585x over previous
//
#include <hip/hip_runtime.h>
#include <math.h>

// ---------------- problem constants (from reference) ----------------
constexpr int N0 = 262144, S1 = 32768, S2 = 4096, S3 = 512;
constexpr int E1 = 327680, E2 = 40960, E3 = 5120;
constexpr float NEG = 0.2f, BN_EPS = 1e-5f;

typedef __attribute__((ext_vector_type(8))) short short8;   // 8 bf16 (4 VGPRs)
typedef __attribute__((ext_vector_type(4))) float f32x4;    // MFMA acc

__device__ __forceinline__ float lrelu(float x) { return x > 0.f ? x : NEG * x; }

__device__ __forceinline__ unsigned short f2b(float f) {  // f32 -> bf16 RNE
    unsigned int u = __float_as_uint(f);
    return (unsigned short)((u + 0x7FFFu + ((u >> 16) & 1u)) >> 16);
}
__device__ __forceinline__ float b2f(unsigned short u) {
    return __uint_as_float(((unsigned int)u) << 16);
}
__device__ __forceinline__ void ld4(const float* __restrict__ p, float* o) {
    float4 v = *(const float4*)p;
    o[0] = v.x; o[1] = v.y; o[2] = v.z; o[3] = v.w;
}

// ---- f32 -> bf16 convert ----
__global__ void conv_kernel(const float* __restrict__ src, unsigned short* __restrict__ dst, long n)
{
    long i = ((long)blockIdx.x * 256 + threadIdx.x) * 4;
    if (i >= n) return;
    float4 v = *(const float4*)(src + i);
    ushort4 u;
    u.x = f2b(v.x); u.y = f2b(v.y); u.z = f2b(v.z); u.w = f2b(v.w);
    *(ushort4*)(dst + i) = u;
}

// ---- fold attention vector into weight: v[h,k] = sum_j att[h,j] * w[(h*256+j)*din + k]
__global__ void fold_kernel(const float* __restrict__ att, const float* __restrict__ w,
                            float* __restrict__ v, int din)
{
    int h = blockIdx.y;
    int k = blockIdx.x * 64 + threadIdx.x;
    if (k >= din) return;
    float acc = 0.f;
    const float* wr = w + (size_t)(h * 256) * din + k;
    const float* ar = att + h * 256;
    for (int j = 0; j < 256; ++j) acc += ar[j] * wr[(size_t)j * din];
    v[h * din + k] = acc;
}

// ---- al[n,h] = dot(x[n,:], v[h,:]), bf16 features, v in registers, grid-stride waves
__global__ void al128_kernel(const unsigned short* __restrict__ xb, const float* __restrict__ v,
                             float* __restrict__ al, int n)
{
    int lane = threadIdx.x & 63;
    int wave = (blockIdx.x * 256 + threadIdx.x) >> 6;
    int nwaves = (gridDim.x * 256) >> 6;
    int j32 = lane & 31, half = lane >> 5;
    float vr[4][4];
    #pragma unroll
    for (int h = 0; h < 4; ++h) ld4(v + h * 128 + j32 * 4, vr[h]);
    for (long node = (long)wave * 2 + half; node < n; node += (long)nwaves * 2) {
        ushort4 u = *(const ushort4*)(xb + node * 128 + j32 * 4);
        float xv[4] = { b2f(u.x), b2f(u.y), b2f(u.z), b2f(u.w) };
        float a[4];
        #pragma unroll
        for (int h = 0; h < 4; ++h)
            a[h] = xv[0]*vr[h][0] + xv[1]*vr[h][1] + xv[2]*vr[h][2] + xv[3]*vr[h][3];
        #pragma unroll
        for (int off = 16; off > 0; off >>= 1)
            #pragma unroll
            for (int h = 0; h < 4; ++h) a[h] += __shfl_xor(a[h], off);
        if (j32 == 0) *(float4*)(al + node * 4) = make_float4(a[0], a[1], a[2], a[3]);
    }
}

__global__ void al1024_kernel(const unsigned short* __restrict__ xb, const float* __restrict__ v,
                              float* __restrict__ al, int n)
{
    int lane = threadIdx.x & 63;
    int wave = (blockIdx.x * 256 + threadIdx.x) >> 6;
    int nwaves = (gridDim.x * 256) >> 6;
    float vr[4][16];
    #pragma unroll
    for (int h = 0; h < 4; ++h)
        #pragma unroll
        for (int it = 0; it < 2; ++it) {
            ld4(v + h * 1024 + it * 512 + lane * 8,     &vr[h][it * 8]);
            ld4(v + h * 1024 + it * 512 + lane * 8 + 4, &vr[h][it * 8 + 4]);
        }
    for (long node = wave; node < n; node += nwaves) {
        const unsigned short* xr = xb + node * 1024;
        float a[4] = {0.f, 0.f, 0.f, 0.f};
        #pragma unroll
        for (int it = 0; it < 2; ++it) {
            short8 u = *(const short8*)(xr + it * 512 + lane * 8);
            #pragma unroll
            for (int j = 0; j < 8; ++j) {
                float xv = b2f((unsigned short)u[j]);
                #pragma unroll
                for (int h = 0; h < 4; ++h) a[h] += xv * vr[h][it * 8 + j];
            }
        }
        #pragma unroll
        for (int off = 32; off > 0; off >>= 1)
            #pragma unroll
            for (int h = 0; h < 4; ++h) a[h] += __shfl_xor(a[h], off);
        if (lane == 0) *(float4*)(al + node * 4) = make_float4(a[0], a[1], a[2], a[3]);
    }
}

// ---- CSR build ----
__global__ void count_kernel(const int* __restrict__ dst, int E, int* __restrict__ counts)
{
    int e = blockIdx.x * 256 + threadIdx.x;
    if (e < E) atomicAdd(&counts[dst[e]], 1);
}

__global__ void scan_kernel(const int* __restrict__ counts, int* __restrict__ offsets, int size)
{
    __shared__ int lds[1024];
    int t = threadIdx.x;
    int chunk = (size + 1023) >> 10;
    int begin = t * chunk;
    int end = begin + chunk; if (end > size) end = size;
    if (begin > size) begin = size;
    int s = 0;
    for (int i = begin; i < end; ++i) s += counts[i];
    lds[t] = s;
    __syncthreads();
    for (int d = 1; d < 1024; d <<= 1) {
        int v = (t >= d) ? lds[t - d] : 0;
        __syncthreads();
        lds[t] += v;
        __syncthreads();
    }
    int base = (t > 0) ? lds[t - 1] : 0;
    for (int i = begin; i < end; ++i) { offsets[i] = base; base += counts[i]; }
    if (t == 1023) offsets[size] = lds[1023];
}

__global__ void scatter_kernel(const int* __restrict__ dst, int E,
                               int* __restrict__ cursor, int* __restrict__ elist)
{
    int e = blockIdx.x * 256 + threadIdx.x;
    if (e < E) { int p = atomicAdd(&cursor[dst[e]], 1); elist[p] = e; }
}

// ---- per-destination softmax stats: m, 1/(denom+eps), self-alpha ----
__global__ void mdn_kernel(const float* __restrict__ als, const float* __restrict__ ald,
                           const int* __restrict__ offsets, const int* __restrict__ elist,
                           const int* __restrict__ esrc, int size,
                           float* __restrict__ m4, float* __restrict__ rdn,
                           float* __restrict__ aself)
{
    int d = blockIdx.x * 256 + threadIdx.x;
    if (d >= size) return;
    float ad[4], sl[4], m[4], q[4], dn[4];
    ld4(ald + 4 * (size_t)d, ad);
    ld4(als + 4 * (size_t)d, q);
    #pragma unroll
    for (int h = 0; h < 4; ++h) { sl[h] = lrelu(q[h] + ad[h]); m[h] = sl[h]; }
    int beg = offsets[d], end = offsets[d + 1];
    for (int p = beg; p < end; ++p) {
        int s = esrc[elist[p]];
        ld4(als + 4 * (size_t)s, q);
        #pragma unroll
        for (int h = 0; h < 4; ++h) m[h] = fmaxf(m[h], lrelu(q[h] + ad[h]));
    }
    #pragma unroll
    for (int h = 0; h < 4; ++h) dn[h] = expf(sl[h] - m[h]);
    for (int p = beg; p < end; ++p) {
        int s = esrc[elist[p]];
        ld4(als + 4 * (size_t)s, q);
        #pragma unroll
        for (int h = 0; h < 4; ++h) dn[h] += expf(lrelu(q[h] + ad[h]) - m[h]);
    }
    #pragma unroll
    for (int h = 0; h < 4; ++h) {
        float r = 1.f / (dn[h] + 1e-16f);
        m4[4 * (size_t)d + h] = m[h];
        rdn[4 * (size_t)d + h] = r;
        aself[4 * (size_t)d + h] = expf(sl[h] - m[h]) * r;
    }
}

// ---- per-edge alpha ----
__global__ void alpha_kernel(const float* __restrict__ als, const float* __restrict__ ald,
                             const int* __restrict__ esrc, const int* __restrict__ edst,
                             const float* __restrict__ m4, const float* __restrict__ rdn,
                             int E, float* __restrict__ walpha)
{
    int e = blockIdx.x * 256 + threadIdx.x;
    if (e >= E) return;
    int d = edst[e], s = esrc[e];
    float as_[4], ad_[4], m[4], r[4];
    ld4(als + 4 * (size_t)s, as_);
    ld4(ald + 4 * (size_t)d, ad_);
    ld4(m4 + 4 * (size_t)d, m);
    ld4(rdn + 4 * (size_t)d, r);
    float4 w;
    w.x = expf(lrelu(as_[0] + ad_[0]) - m[0]) * r[0];
    w.y = expf(lrelu(as_[1] + ad_[1]) - m[1]) * r[1];
    w.z = expf(lrelu(as_[2] + ad_[2]) - m[2]) * r[2];
    w.w = expf(lrelu(as_[3] + ad_[3]) - m[3]) * r[3];
    *(float4*)(walpha + 4 * (size_t)e) = w;
}

// ---- aggregation with precomputed alpha; bf16 in, bf16 out ----
// DIN=128: one wave per dst, 2 bf16 per lane.
__global__ void agg128_kernel(const unsigned short* __restrict__ xb, const float* __restrict__ walpha,
                              const float* __restrict__ aself,
                              const int* __restrict__ offsets, const int* __restrict__ elist,
                              const int* __restrict__ esrc, unsigned short* __restrict__ aggb)
{
    int d = blockIdx.x, lane = threadIdx.x;
    int beg = offsets[d], end = offsets[d + 1];
    float w[4], acc[4][2];
    ld4(aself + 4 * (size_t)d, w);
    {
        unsigned int u = *(const unsigned int*)(xb + (size_t)d * 128 + lane * 2);
        float x0 = b2f((unsigned short)(u & 0xFFFF)), x1 = b2f((unsigned short)(u >> 16));
        #pragma unroll
        for (int h = 0; h < 4; ++h) { acc[h][0] = w[h] * x0; acc[h][1] = w[h] * x1; }
    }
    for (int p = beg; p < end; ++p) {
        int e = elist[p];
        int s = esrc[e];
        ld4(walpha + 4 * (size_t)e, w);
        unsigned int u = *(const unsigned int*)(xb + (size_t)s * 128 + lane * 2);
        float x0 = b2f((unsigned short)(u & 0xFFFF)), x1 = b2f((unsigned short)(u >> 16));
        #pragma unroll
        for (int h = 0; h < 4; ++h) { acc[h][0] += w[h] * x0; acc[h][1] += w[h] * x1; }
    }
    unsigned int* og = (unsigned int*)(aggb + (size_t)d * 512);
    #pragma unroll
    for (int h = 0; h < 4; ++h) {
        unsigned int u = (unsigned int)f2b(acc[h][0]) | ((unsigned int)f2b(acc[h][1]) << 16);
        og[h * 64 + lane] = u;
    }
}

// DIN=1024: block 256, 4 bf16 per thread.
__global__ void agg1024_kernel(const unsigned short* __restrict__ xb, const float* __restrict__ walpha,
                               const float* __restrict__ aself,
                               const int* __restrict__ offsets, const int* __restrict__ elist,
                               const int* __restrict__ esrc, unsigned short* __restrict__ aggb)
{
    int d = blockIdx.x, t = threadIdx.x;
    int beg = offsets[d], end = offsets[d + 1];
    float w[4], acc[4][4];
    ld4(aself + 4 * (size_t)d, w);
    {
        ushort4 u = *(const ushort4*)(xb + (size_t)d * 1024 + t * 4);
        float xv[4] = { b2f(u.x), b2f(u.y), b2f(u.z), b2f(u.w) };
        #pragma unroll
        for (int h = 0; h < 4; ++h)
            #pragma unroll
            for (int j = 0; j < 4; ++j) acc[h][j] = w[h] * xv[j];
    }
    for (int p = beg; p < end; ++p) {
        int e = elist[p];
        int s = esrc[e];
        ld4(walpha + 4 * (size_t)e, w);
        ushort4 u = *(const ushort4*)(xb + (size_t)s * 1024 + t * 4);
        float xv[4] = { b2f(u.x), b2f(u.y), b2f(u.z), b2f(u.w) };
        #pragma unroll
        for (int h = 0; h < 4; ++h)
            #pragma unroll
            for (int j = 0; j < 4; ++j) acc[h][j] += w[h] * xv[j];
    }
    unsigned short* og = aggb + (size_t)d * 4096;
    #pragma unroll
    for (int h = 0; h < 4; ++h) {
        ushort4 u;
        u.x = f2b(acc[h][0]); u.y = f2b(acc[h][1]);
        u.z = f2b(acc[h][2]); u.w = f2b(acc[h][3]);
        *(ushort4*)(og + h * 1024 + t * 4) = u;
    }
}

// ---- repack layer-3 GAT weights to bf16 with mean fold ----
__global__ void repack_w3b(const float* __restrict__ w, unsigned short* __restrict__ wp)
{
    long i = (long)blockIdx.x * 256 + threadIdx.x;
    if (i >= 256L * 4096) return;
    int j = (int)(i >> 12);
    int hk = (int)(i & 4095);
    int h = hk >> 10, k = hk & 1023;
    wp[i] = f2b(0.25f * w[((size_t)(h * 256 + j)) * 1024 + k]);
}

// ---- fused dual-phase bf16 MFMA GEMM + BN column stats; bf16 C out ----
template<int BM, int BN>
__global__ __launch_bounds__(256) void gemm2_kernel(
    const unsigned short* __restrict__ A1, int lda1, const unsigned short* __restrict__ W1, int K1,
    const unsigned short* __restrict__ A2, int lda2, const unsigned short* __restrict__ W2, int K2,
    int hs2, int cph2,
    unsigned short* __restrict__ C, int N,
    float* __restrict__ bnsum, float* __restrict__ bnsq)
{
    constexpr int WM = BM / 2, WN = BN / 2;
    constexpr int TM = WM / 16, TN = WN / 16;
    __shared__ __align__(16) unsigned short As[BM * 40];
    __shared__ __align__(16) unsigned short Bs[BN * 40];
    __shared__ float sbn[2 * BN];
    int tid = threadIdx.x;
    int n0 = blockIdx.x * BN, m0 = blockIdx.y * BM;
    int l = tid & 63, l16 = l & 15, kq = l >> 4;
    int wid = tid >> 6, wr = wid >> 1, wc = wid & 1;

    f32x4 acc[TM][TN];
    #pragma unroll
    for (int mi = 0; mi < TM; ++mi)
        #pragma unroll
        for (int ni = 0; ni < TN; ++ni) acc[mi][ni] = (f32x4){0.f, 0.f, 0.f, 0.f};

    #pragma unroll
    for (int ph = 0; ph < 2; ++ph) {
        const unsigned short* Ap = ph ? A2 + (size_t)m0 * lda2 + (cph2 ? (size_t)(n0 / cph2) * hs2 : 0)
                                      : A1 + (size_t)m0 * lda1;
        int lda = ph ? lda2 : lda1;
        const unsigned short* Wp = ph ? W2 + (size_t)n0 * K2 : W1 + (size_t)n0 * K1;
        int ldw = ph ? K2 : K1;
        int K = ph ? K2 : K1;
        for (int k0 = 0; k0 < K; k0 += 32) {
            for (int c = tid; c < BM * 4; c += 256) {
                int r = c >> 2, ch = (c & 3) << 3;
                *(uint4*)&As[r * 40 + ch] = *(const uint4*)(Ap + (size_t)r * lda + k0 + ch);
            }
            for (int c = tid; c < BN * 4; c += 256) {
                int r = c >> 2, ch = (c & 3) << 3;
                *(uint4*)&Bs[r * 40 + ch] = *(const uint4*)(Wp + (size_t)r * ldw + k0 + ch);
            }
            __syncthreads();
            short8 af[TM], bfr[TN];
            #pragma unroll
            for (int mi = 0; mi < TM; ++mi)
                af[mi] = *(const short8*)&As[(wr * WM + mi * 16 + l16) * 40 + (kq << 3)];
            #pragma unroll
            for (int ni = 0; ni < TN; ++ni)
                bfr[ni] = *(const short8*)&Bs[(wc * WN + ni * 16 + l16) * 40 + (kq << 3)];
            #pragma unroll
            for (int mi = 0; mi < TM; ++mi)
                #pragma unroll
                for (int ni = 0; ni < TN; ++ni)
                    acc[mi][ni] = __builtin_amdgcn_mfma_f32_16x16x32_bf16(
                        af[mi], bfr[ni], acc[mi][ni], 0, 0, 0);
            __syncthreads();
        }
    }

    if (tid < 2 * BN) sbn[tid] = 0.f;
    __syncthreads();

    #pragma unroll
    for (int ni = 0; ni < TN; ++ni) {
        int col = wc * WN + ni * 16 + l16;
        float s = 0.f, q = 0.f;
        #pragma unroll
        for (int mi = 0; mi < TM; ++mi) {
            int rowb = wr * WM + mi * 16 + (kq << 2);
            #pragma unroll
            for (int r = 0; r < 4; ++r) {
                float v = acc[mi][ni][r];
                C[(size_t)(m0 + rowb + r) * N + n0 + col] = f2b(v);
                s += v; q += v * v;
            }
        }
        atomicAdd(&sbn[col * 2 + 0], s);
        atomicAdd(&sbn[col * 2 + 1], q);
    }
    __syncthreads();
    if (tid < BN) {
        atomicAdd(&bnsum[n0 + tid], sbn[tid * 2 + 0]);
        atomicAdd(&bnsq[n0 + tid], sbn[tid * 2 + 1]);
    }
}

// ---- BN finalize ----
__global__ void bn_finalize(const float* __restrict__ sum, const float* __restrict__ sumsq,
                            const float* __restrict__ gamma, const float* __restrict__ beta,
                            float* __restrict__ scale, float* __restrict__ shift, int M, int N)
{
    int c = blockIdx.x * 256 + threadIdx.x;
    if (c >= N) return;
    float mu = sum[c] / (float)M;
    float var = sumsq[c] / (float)M - mu * mu;
    float sc = gamma[c] * rsqrtf(var + BN_EPS);
    scale[c] = sc;
    shift[c] = beta[c] - mu * sc;
}

// ---- BN apply + ELU: bf16 h -> bf16 out ----
__global__ void norm_elu_bb(const unsigned short* __restrict__ h, const float* __restrict__ scale,
                            const float* __restrict__ shift, unsigned short* __restrict__ out,
                            int N, long total)
{
    long i = ((long)blockIdx.x * 256 + threadIdx.x) * 4;
    if (i >= total) return;
    int c = (int)(i % N);
    ushort4 u = *(const ushort4*)(h + i);
    float4 sc = *(const float4*)(scale + c);
    float4 sh = *(const float4*)(shift + c);
    float v0 = b2f(u.x) * sc.x + sh.x;
    float v1 = b2f(u.y) * sc.y + sh.y;
    float v2 = b2f(u.z) * sc.z + sh.z;
    float v3 = b2f(u.w) * sc.w + sh.w;
    v0 = v0 > 0.f ? v0 : expm1f(v0);
    v1 = v1 > 0.f ? v1 : expm1f(v1);
    v2 = v2 > 0.f ? v2 : expm1f(v2);
    v3 = v3 > 0.f ? v3 : expm1f(v3);
    ushort4 o;
    o.x = f2b(v0); o.y = f2b(v1); o.z = f2b(v2); o.w = f2b(v3);
    *(ushort4*)(out + i) = o;
}

// ---- BN apply + ELU: bf16 h -> f32 out (final layer) ----
__global__ void norm_elu_bf(const unsigned short* __restrict__ h, const float* __restrict__ scale,
                            const float* __restrict__ shift, float* __restrict__ out,
                            int N, long total)
{
    long i = ((long)blockIdx.x * 256 + threadIdx.x) * 4;
    if (i >= total) return;
    int c = (int)(i % N);
    ushort4 u = *(const ushort4*)(h + i);
    float4 sc = *(const float4*)(scale + c);
    float4 sh = *(const float4*)(shift + c);
    float4 o;
    o.x = b2f(u.x) * sc.x + sh.x;
    o.y = b2f(u.y) * sc.y + sh.y;
    o.z = b2f(u.z) * sc.z + sh.z;
    o.w = b2f(u.w) * sc.w + sh.w;
    o.x = o.x > 0.f ? o.x : expm1f(o.x);
    o.y = o.y > 0.f ? o.y : expm1f(o.y);
    o.z = o.z > 0.f ? o.z : expm1f(o.z);
    o.w = o.w > 0.f ? o.w : expm1f(o.w);
    *(float4*)(out + i) = o;
}

// =====================================================================
extern "C" void kernel_launch(void* const* d_in, const int* in_sizes, int n_in,
                              void* d_out, int out_size, void* d_ws, size_t ws_size,
                              hipStream_t stream)
{
    const float* x = (const float*)d_in[0];
    auto P = [&](int layer, int slot) -> const float* {
        return (const float*)d_in[1 + (layer - 1) * 9 + slot];
    };
    const int* edge_src[3] = { (const int*)d_in[28], (const int*)d_in[30], (const int*)d_in[32] };
    const int* edge_dst[3] = { (const int*)d_in[29], (const int*)d_in[31], (const int*)d_in[33] };
    const int Es[3] = { E1, E2, E3 };

    // -------- workspace carve --------
    char* wsb = (char*)d_ws;
    size_t off = 0;
    auto alloc = [&](size_t bytes) -> void* {
        void* p = wsb + off;
        off = (off + bytes + 255) & ~(size_t)255;
        return p;
    };
    unsigned short* xb0   = (unsigned short*)alloc((size_t)N0 * 128 * 2);   // 67.1 MB
    unsigned short* x1b   = (unsigned short*)alloc((size_t)S1 * 1024 * 2);  // 67.1 MB
    unsigned short* x2b   = (unsigned short*)alloc((size_t)S2 * 1024 * 2);  // 8.4 MB
    unsigned short* hb    = (unsigned short*)alloc((size_t)S1 * 1024 * 2);  // 67.1 MB
    unsigned short* aggb  = (unsigned short*)alloc((size_t)S2 * 4096 * 2);  // 33.6 MB
    unsigned short* wskipb= (unsigned short*)alloc((size_t)1024 * 1024 * 2);
    unsigned short* wsrcb = (unsigned short*)alloc((size_t)1024 * 1024 * 2);
    float* al_src  = (float*)alloc((size_t)N0 * 4 * 4);
    float* al_dst  = (float*)alloc((size_t)S1 * 4 * 4);
    float* vsrc    = (float*)alloc(4 * 1024 * 4);
    float* vdst    = (float*)alloc(4 * 1024 * 4);
    float* m4      = (float*)alloc((size_t)S1 * 4 * 4);
    float* rdn     = (float*)alloc((size_t)S1 * 4 * 4);
    float* aself   = (float*)alloc((size_t)S1 * 4 * 4);
    float* walpha  = (float*)alloc((size_t)E1 * 4 * 4);
    int*   offsets = (int*)alloc((size_t)(S1 + 1) * 4);
    int*   cursor  = (int*)alloc((size_t)S1 * 4);
    int*   counts  = (int*)alloc((size_t)S1 * 4);
    int*   elist   = (int*)alloc((size_t)E1 * 4);
    float* bnsum   = (float*)alloc(1024 * 4);
    float* bnsq    = (float*)alloc(1024 * 4);

    // input features -> bf16 once
    conv_kernel<<<(int)(((long)N0 * 128 / 4 + 255) / 256), 256, 0, stream>>>(x, xb0, (long)N0 * 128);

    auto run_layer = [&](int L, const unsigned short* xa, int n_all, int size, int din, int dfull,
                         unsigned short* outb, float* outf)
    {
        const float* wsrc  = P(L, 0);
        const float* wdst  = P(L, 1);
        const float* asrc  = P(L, 2);
        const float* adst  = P(L, 3);
        const float* wskip = P(L, 5);
        const float* gamma = P(L, 7);
        const float* beta  = P(L, 8);
        const int* esrc = edge_src[L - 1];
        const int* edst = edge_dst[L - 1];
        int E = Es[L - 1];

        // fold attention into weights; attention logits
        fold_kernel<<<dim3((din + 63) / 64, 4), 64, 0, stream>>>(asrc, wsrc, vsrc, din);
        fold_kernel<<<dim3((din + 63) / 64, 4), 64, 0, stream>>>(adst, wdst, vdst, din);
        if (din == 128) {
            al128_kernel<<<512, 256, 0, stream>>>(xa, vsrc, al_src, n_all);
            al128_kernel<<<512, 256, 0, stream>>>(xa, vdst, al_dst, size);
        } else {
            al1024_kernel<<<256, 256, 0, stream>>>(xa, vsrc, al_src, n_all);
            al1024_kernel<<<256, 256, 0, stream>>>(xa, vdst, al_dst, size);
        }
        // CSR by destination
        hipMemsetAsync(counts, 0, (size_t)size * 4, stream);
        count_kernel<<<(E + 255) / 256, 256, 0, stream>>>(edst, E, counts);
        scan_kernel<<<1, 1024, 0, stream>>>(counts, offsets, size);
        hipMemcpyAsync(cursor, offsets, (size_t)size * 4, hipMemcpyDeviceToDevice, stream);
        scatter_kernel<<<(E + 255) / 256, 256, 0, stream>>>(edst, E, cursor, elist);
        // softmax stats + per-edge alpha
        mdn_kernel<<<(size + 255) / 256, 256, 0, stream>>>(al_src, al_dst, offsets, elist, esrc,
                                                           size, m4, rdn, aself);
        alpha_kernel<<<(E + 255) / 256, 256, 0, stream>>>(al_src, al_dst, esrc, edst, m4, rdn,
                                                          E, walpha);
        // aggregation (bf16 in/out)
        if (din == 128)
            agg128_kernel<<<size, 64, 0, stream>>>(xa, walpha, aself, offsets, elist, esrc, aggb);
        else
            agg1024_kernel<<<size, 256, 0, stream>>>(xa, walpha, aself, offsets, elist, esrc, aggb);
        // weight prep (bf16)
        conv_kernel<<<(int)(((long)dfull * din / 4 + 255) / 256), 256, 0, stream>>>(
            wskip, wskipb, (long)dfull * din);
        if (L < 3)
            conv_kernel<<<(int)((1024L * din / 4 + 255) / 256), 256, 0, stream>>>(wsrc, wsrcb, 1024L * din);
        else
            repack_w3b<<<(256 * 4096 + 255) / 256, 256, 0, stream>>>(wsrc, wsrcb);
        // fused GEMM (skip + GAT) with BN stats, bf16 out
        hipMemsetAsync(bnsum, 0, (size_t)dfull * 4, stream);
        hipMemsetAsync(bnsq, 0, (size_t)dfull * 4, stream);
        if (L < 3) {
            gemm2_kernel<128, 128><<<dim3(dfull / 128, size / 128), 256, 0, stream>>>(
                xa, din, wskipb, din,
                aggb, 4 * din, wsrcb, din, din, 256,
                hb, dfull, bnsum, bnsq);
        } else {
            gemm2_kernel<64, 64><<<dim3(dfull / 64, size / 64), 256, 0, stream>>>(
                xa, din, wskipb, din,
                aggb, 4 * din, wsrcb, 4 * din, 0, 0,
                hb, dfull, bnsum, bnsq);
        }
        // batchnorm + elu
        bn_finalize<<<(dfull + 255) / 256, 256, 0, stream>>>(bnsum, bnsq, gamma, beta, bnsum, bnsq, size, dfull);
        long total = (long)size * dfull;
        if (outb)
            norm_elu_bb<<<(int)((total / 4 + 255) / 256), 256, 0, stream>>>(hb, bnsum, bnsq, outb, dfull, total);
        else
            norm_elu_bf<<<(int)((total / 4 + 255) / 256), 256, 0, stream>>>(hb, bnsum, bnsq, outf, dfull, total);
    };

    run_layer(1, xb0, N0, S1, 128,  1024, x1b, nullptr);
    run_layer(2, x1b, S1, S2, 1024, 1024, x2b, nullptr);
    run_layer(3, x2b, S2, S3, 1024, 256, nullptr, (float*)d_out);
}

// Round 5
// 876.110 us; speedup vs baseline: 2.2382x; 1.0218x over previous
//
#include <hip/hip_runtime.h>
#include <math.h>

// ---------------- problem constants (from reference) ----------------
constexpr int N0 = 262144, S1 = 32768, S2 = 4096, S3 = 512;
constexpr int E1 = 327680, E2 = 40960, E3 = 5120;
constexpr float NEG = 0.2f, BN_EPS = 1e-5f;

typedef __attribute__((ext_vector_type(8))) short short8;   // 8 bf16 (4 VGPRs)
typedef __attribute__((ext_vector_type(4))) float f32x4;    // MFMA acc

__device__ __forceinline__ float lrelu(float x) { return x > 0.f ? x : NEG * x; }

__device__ __forceinline__ unsigned short f2b(float f) {  // f32 -> bf16 RNE
    unsigned int u = __float_as_uint(f);
    return (unsigned short)((u + 0x7FFFu + ((u >> 16) & 1u)) >> 16);
}
__device__ __forceinline__ float b2f(unsigned short u) {
    return __uint_as_float(((unsigned int)u) << 16);
}
__device__ __forceinline__ void ld4(const float* __restrict__ p, float* o) {
    float4 v = *(const float4*)p;
    o[0] = v.x; o[1] = v.y; o[2] = v.z; o[3] = v.w;
}

// ---- f32 -> bf16 convert ----
__global__ void conv_kernel(const float* __restrict__ src, unsigned short* __restrict__ dst, long n)
{
    long i = ((long)blockIdx.x * 256 + threadIdx.x) * 4;
    if (i >= n) return;
    float4 v = *(const float4*)(src + i);
    ushort4 u;
    u.x = f2b(v.x); u.y = f2b(v.y); u.z = f2b(v.z); u.w = f2b(v.w);
    *(ushort4*)(dst + i) = u;
}

// ---- fold attention vector into weight: v[h,k] = sum_j att[h,j] * w[(h*256+j)*din + k]
__global__ void fold_kernel(const float* __restrict__ att, const float* __restrict__ w,
                            float* __restrict__ v, int din)
{
    int h = blockIdx.y;
    int k = blockIdx.x * 64 + threadIdx.x;
    if (k >= din) return;
    float acc = 0.f;
    const float* wr = w + (size_t)(h * 256) * din + k;
    const float* ar = att + h * 256;
    for (int j = 0; j < 256; ++j) acc += ar[j] * wr[(size_t)j * din];
    v[h * din + k] = acc;
}

// ---- al[n,h] = dot(x[n,:], v[h,:]), bf16 features, v in registers, grid-stride waves
__global__ void al128_kernel(const unsigned short* __restrict__ xb, const float* __restrict__ v,
                             float* __restrict__ al, int n)
{
    int lane = threadIdx.x & 63;
    int wave = (blockIdx.x * 256 + threadIdx.x) >> 6;
    int nwaves = (gridDim.x * 256) >> 6;
    int j32 = lane & 31, half = lane >> 5;
    float vr[4][4];
    #pragma unroll
    for (int h = 0; h < 4; ++h) ld4(v + h * 128 + j32 * 4, vr[h]);
    for (long node = (long)wave * 2 + half; node < n; node += (long)nwaves * 2) {
        ushort4 u = *(const ushort4*)(xb + node * 128 + j32 * 4);
        float xv[4] = { b2f(u.x), b2f(u.y), b2f(u.z), b2f(u.w) };
        float a[4];
        #pragma unroll
        for (int h = 0; h < 4; ++h)
            a[h] = xv[0]*vr[h][0] + xv[1]*vr[h][1] + xv[2]*vr[h][2] + xv[3]*vr[h][3];
        #pragma unroll
        for (int off = 16; off > 0; off >>= 1)
            #pragma unroll
            for (int h = 0; h < 4; ++h) a[h] += __shfl_xor(a[h], off);
        if (j32 == 0) *(float4*)(al + node * 4) = make_float4(a[0], a[1], a[2], a[3]);
    }
}

__global__ void al1024_kernel(const unsigned short* __restrict__ xb, const float* __restrict__ v,
                              float* __restrict__ al, int n)
{
    int lane = threadIdx.x & 63;
    int wave = (blockIdx.x * 256 + threadIdx.x) >> 6;
    int nwaves = (gridDim.x * 256) >> 6;
    float vr[4][16];
    #pragma unroll
    for (int h = 0; h < 4; ++h)
        #pragma unroll
        for (int it = 0; it < 2; ++it) {
            ld4(v + h * 1024 + it * 512 + lane * 8,     &vr[h][it * 8]);
            ld4(v + h * 1024 + it * 512 + lane * 8 + 4, &vr[h][it * 8 + 4]);
        }
    for (long node = wave; node < n; node += nwaves) {
        const unsigned short* xr = xb + node * 1024;
        float a[4] = {0.f, 0.f, 0.f, 0.f};
        #pragma unroll
        for (int it = 0; it < 2; ++it) {
            short8 u = *(const short8*)(xr + it * 512 + lane * 8);
            #pragma unroll
            for (int j = 0; j < 8; ++j) {
                float xv = b2f((unsigned short)u[j]);
                #pragma unroll
                for (int h = 0; h < 4; ++h) a[h] += xv * vr[h][it * 8 + j];
            }
        }
        #pragma unroll
        for (int off = 32; off > 0; off >>= 1)
            #pragma unroll
            for (int h = 0; h < 4; ++h) a[h] += __shfl_xor(a[h], off);
        if (lane == 0) *(float4*)(al + node * 4) = make_float4(a[0], a[1], a[2], a[3]);
    }
}

// ---- CSR build ----
__global__ void count_kernel(const int* __restrict__ dst, int E, int* __restrict__ counts)
{
    int e = blockIdx.x * 256 + threadIdx.x;
    if (e < E) atomicAdd(&counts[dst[e]], 1);
}

__global__ void scan_kernel(const int* __restrict__ counts, int* __restrict__ offsets,
                            int* __restrict__ cursor, int size)
{
    __shared__ int lds[1024];
    int t = threadIdx.x;
    int chunk = (size + 1023) >> 10;
    int begin = t * chunk;
    int end = begin + chunk; if (end > size) end = size;
    if (begin > size) begin = size;
    int s = 0;
    for (int i = begin; i < end; ++i) s += counts[i];
    lds[t] = s;
    __syncthreads();
    for (int d = 1; d < 1024; d <<= 1) {
        int v = (t >= d) ? lds[t - d] : 0;
        __syncthreads();
        lds[t] += v;
        __syncthreads();
    }
    int base = (t > 0) ? lds[t - 1] : 0;
    for (int i = begin; i < end; ++i) {
        offsets[i] = base; cursor[i] = base;
        base += counts[i];
    }
    if (t == 1023) offsets[size] = lds[1023];
}

__global__ void scatter_kernel(const int* __restrict__ dst, int E,
                               int* __restrict__ cursor, int* __restrict__ elist)
{
    int e = blockIdx.x * 256 + threadIdx.x;
    if (e < E) { int p = atomicAdd(&cursor[dst[e]], 1); elist[p] = e; }
}

// ---- per-destination softmax stats: m, 1/(denom+eps), self-alpha ----
__global__ void mdn_kernel(const float* __restrict__ als, const float* __restrict__ ald,
                           const int* __restrict__ offsets, const int* __restrict__ elist,
                           const int* __restrict__ esrc, int size,
                           float* __restrict__ m4, float* __restrict__ rdn,
                           float* __restrict__ aself)
{
    int d = blockIdx.x * 256 + threadIdx.x;
    if (d >= size) return;
    float ad[4], sl[4], m[4], q[4], dn[4];
    ld4(ald + 4 * (size_t)d, ad);
    ld4(als + 4 * (size_t)d, q);
    #pragma unroll
    for (int h = 0; h < 4; ++h) { sl[h] = lrelu(q[h] + ad[h]); m[h] = sl[h]; }
    int beg = offsets[d], end = offsets[d + 1];
    for (int p = beg; p < end; ++p) {
        int s = esrc[elist[p]];
        ld4(als + 4 * (size_t)s, q);
        #pragma unroll
        for (int h = 0; h < 4; ++h) m[h] = fmaxf(m[h], lrelu(q[h] + ad[h]));
    }
    #pragma unroll
    for (int h = 0; h < 4; ++h) dn[h] = expf(sl[h] - m[h]);
    for (int p = beg; p < end; ++p) {
        int s = esrc[elist[p]];
        ld4(als + 4 * (size_t)s, q);
        #pragma unroll
        for (int h = 0; h < 4; ++h) dn[h] += expf(lrelu(q[h] + ad[h]) - m[h]);
    }
    #pragma unroll
    for (int h = 0; h < 4; ++h) {
        float r = 1.f / (dn[h] + 1e-16f);
        m4[4 * (size_t)d + h] = m[h];
        rdn[4 * (size_t)d + h] = r;
        aself[4 * (size_t)d + h] = expf(sl[h] - m[h]) * r;
    }
}

// ---- per-edge alpha ----
__global__ void alpha_kernel(const float* __restrict__ als, const float* __restrict__ ald,
                             const int* __restrict__ esrc, const int* __restrict__ edst,
                             const float* __restrict__ m4, const float* __restrict__ rdn,
                             int E, float* __restrict__ walpha)
{
    int e = blockIdx.x * 256 + threadIdx.x;
    if (e >= E) return;
    int d = edst[e], s = esrc[e];
    float as_[4], ad_[4], m[4], r[4];
    ld4(als + 4 * (size_t)s, as_);
    ld4(ald + 4 * (size_t)d, ad_);
    ld4(m4 + 4 * (size_t)d, m);
    ld4(rdn + 4 * (size_t)d, r);
    float4 w;
    w.x = expf(lrelu(as_[0] + ad_[0]) - m[0]) * r[0];
    w.y = expf(lrelu(as_[1] + ad_[1]) - m[1]) * r[1];
    w.z = expf(lrelu(as_[2] + ad_[2]) - m[2]) * r[2];
    w.w = expf(lrelu(as_[3] + ad_[3]) - m[3]) * r[3];
    *(float4*)(walpha + 4 * (size_t)e) = w;
}

// ---- aggregation with precomputed alpha; bf16 in, bf16 out ----
// DIN=128: one wave per dst, 2 bf16 per lane.
__global__ void agg128_kernel(const unsigned short* __restrict__ xb, const float* __restrict__ walpha,
                              const float* __restrict__ aself,
                              const int* __restrict__ offsets, const int* __restrict__ elist,
                              const int* __restrict__ esrc, unsigned short* __restrict__ aggb)
{
    int d = blockIdx.x, lane = threadIdx.x;
    int beg = offsets[d], end = offsets[d + 1];
    float w[4], acc[4][2];
    ld4(aself + 4 * (size_t)d, w);
    {
        unsigned int u = *(const unsigned int*)(xb + (size_t)d * 128 + lane * 2);
        float x0 = b2f((unsigned short)(u & 0xFFFF)), x1 = b2f((unsigned short)(u >> 16));
        #pragma unroll
        for (int h = 0; h < 4; ++h) { acc[h][0] = w[h] * x0; acc[h][1] = w[h] * x1; }
    }
    for (int p = beg; p < end; ++p) {
        int e = elist[p];
        int s = esrc[e];
        ld4(walpha + 4 * (size_t)e, w);
        unsigned int u = *(const unsigned int*)(xb + (size_t)s * 128 + lane * 2);
        float x0 = b2f((unsigned short)(u & 0xFFFF)), x1 = b2f((unsigned short)(u >> 16));
        #pragma unroll
        for (int h = 0; h < 4; ++h) { acc[h][0] += w[h] * x0; acc[h][1] += w[h] * x1; }
    }
    unsigned int* og = (unsigned int*)(aggb + (size_t)d * 512);
    #pragma unroll
    for (int h = 0; h < 4; ++h)
        og[h * 64 + lane] = (unsigned int)f2b(acc[h][0]) | ((unsigned int)f2b(acc[h][1]) << 16);
}

// DIN=1024: block 256, 4 bf16 per thread.
__global__ void agg1024_kernel(const unsigned short* __restrict__ xb, const float* __restrict__ walpha,
                               const float* __restrict__ aself,
                               const int* __restrict__ offsets, const int* __restrict__ elist,
                               const int* __restrict__ esrc, unsigned short* __restrict__ aggb)
{
    int d = blockIdx.x, t = threadIdx.x;
    int beg = offsets[d], end = offsets[d + 1];
    float w[4], acc[4][4];
    ld4(aself + 4 * (size_t)d, w);
    {
        ushort4 u = *(const ushort4*)(xb + (size_t)d * 1024 + t * 4);
        float xv[4] = { b2f(u.x), b2f(u.y), b2f(u.z), b2f(u.w) };
        #pragma unroll
        for (int h = 0; h < 4; ++h)
            #pragma unroll
            for (int j = 0; j < 4; ++j) acc[h][j] = w[h] * xv[j];
    }
    for (int p = beg; p < end; ++p) {
        int e = elist[p];
        int s = esrc[e];
        ld4(walpha + 4 * (size_t)e, w);
        ushort4 u = *(const ushort4*)(xb + (size_t)s * 1024 + t * 4);
        float xv[4] = { b2f(u.x), b2f(u.y), b2f(u.z), b2f(u.w) };
        #pragma unroll
        for (int h = 0; h < 4; ++h)
            #pragma unroll
            for (int j = 0; j < 4; ++j) acc[h][j] += w[h] * xv[j];
    }
    unsigned short* og = aggb + (size_t)d * 4096;
    #pragma unroll
    for (int h = 0; h < 4; ++h) {
        ushort4 u;
        u.x = f2b(acc[h][0]); u.y = f2b(acc[h][1]);
        u.z = f2b(acc[h][2]); u.w = f2b(acc[h][3]);
        *(ushort4*)(og + h * 1024 + t * 4) = u;
    }
}

// ---- repack layer-3 GAT weights to bf16 with mean fold ----
__global__ void repack_w3b(const float* __restrict__ w, unsigned short* __restrict__ wp)
{
    long i = (long)blockIdx.x * 256 + threadIdx.x;
    if (i >= 256L * 4096) return;
    int j = (int)(i >> 12);
    int hk = (int)(i & 4095);
    int h = hk >> 10, k = hk & 1023;
    wp[i] = f2b(0.25f * w[((size_t)(h * 256 + j)) * 1024 + k]);
}

// ---- fused dual-phase bf16 MFMA GEMM + BN column stats; bf16 C out ----
// LDS row stride 32 shorts; 16B chunk c of row r stored at chunk (c ^ ((r>>1)&3)).
// Both store and ds_read_b128 patterns distribute 8 lanes per 4-bank set -> conflict-free floor.
#define SWZ(r, c) ((((c) ^ (((r) >> 1) & 3)) << 3))

template<int BM, int BN>
__global__ __launch_bounds__(256) void gemm2_kernel(
    const unsigned short* __restrict__ A1, int lda1, const unsigned short* __restrict__ W1, int K1,
    const unsigned short* __restrict__ A2, int lda2, const unsigned short* __restrict__ W2, int K2,
    int hs2, int cph2,
    unsigned short* __restrict__ C, int N,
    float* __restrict__ bnsum, float* __restrict__ bnsq)
{
    constexpr int WM = BM / 2, WN = BN / 2;
    constexpr int TM = WM / 16, TN = WN / 16;
    __shared__ __align__(16) unsigned short As[BM * 32];
    __shared__ __align__(16) unsigned short Bs[BN * 32];
    __shared__ float sbn[2 * BN];
    int tid = threadIdx.x;
    int n0 = blockIdx.x * BN, m0 = blockIdx.y * BM;
    int l = tid & 63, l16 = l & 15, kq = l >> 4;
    int wid = tid >> 6, wr = wid >> 1, wc = wid & 1;

    f32x4 acc[TM][TN];
    #pragma unroll
    for (int mi = 0; mi < TM; ++mi)
        #pragma unroll
        for (int ni = 0; ni < TN; ++ni) acc[mi][ni] = (f32x4){0.f, 0.f, 0.f, 0.f};

    #pragma unroll
    for (int ph = 0; ph < 2; ++ph) {
        const unsigned short* Ap = ph ? A2 + (size_t)m0 * lda2 + (cph2 ? (size_t)(n0 / cph2) * hs2 : 0)
                                      : A1 + (size_t)m0 * lda1;
        int lda = ph ? lda2 : lda1;
        const unsigned short* Wp = ph ? W2 + (size_t)n0 * K2 : W1 + (size_t)n0 * K1;
        int ldw = ph ? K2 : K1;
        int K = ph ? K2 : K1;
        for (int k0 = 0; k0 < K; k0 += 32) {
            for (int c = tid; c < BM * 4; c += 256) {
                int r = c >> 2, ch = c & 3;
                *(uint4*)&As[r * 32 + SWZ(r, ch)] = *(const uint4*)(Ap + (size_t)r * lda + k0 + (ch << 3));
            }
            for (int c = tid; c < BN * 4; c += 256) {
                int r = c >> 2, ch = c & 3;
                *(uint4*)&Bs[r * 32 + SWZ(r, ch)] = *(const uint4*)(Wp + (size_t)r * ldw + k0 + (ch << 3));
            }
            __syncthreads();
            short8 af[TM], bfr[TN];
            #pragma unroll
            for (int mi = 0; mi < TM; ++mi) {
                int r = wr * WM + mi * 16 + l16;
                af[mi] = *(const short8*)&As[r * 32 + SWZ(r, kq)];
            }
            #pragma unroll
            for (int ni = 0; ni < TN; ++ni) {
                int r = wc * WN + ni * 16 + l16;
                bfr[ni] = *(const short8*)&Bs[r * 32 + SWZ(r, kq)];
            }
            #pragma unroll
            for (int mi = 0; mi < TM; ++mi)
                #pragma unroll
                for (int ni = 0; ni < TN; ++ni)
                    acc[mi][ni] = __builtin_amdgcn_mfma_f32_16x16x32_bf16(
                        af[mi], bfr[ni], acc[mi][ni], 0, 0, 0);
            __syncthreads();
        }
    }

    if (tid < 2 * BN) sbn[tid] = 0.f;
    __syncthreads();

    #pragma unroll
    for (int ni = 0; ni < TN; ++ni) {
        int col = wc * WN + ni * 16 + l16;
        float s = 0.f, q = 0.f;
        #pragma unroll
        for (int mi = 0; mi < TM; ++mi) {
            int rowb = wr * WM + mi * 16 + (kq << 2);
            #pragma unroll
            for (int r = 0; r < 4; ++r) {
                float v = acc[mi][ni][r];
                C[(size_t)(m0 + rowb + r) * N + n0 + col] = f2b(v);
                s += v; q += v * v;
            }
        }
        atomicAdd(&sbn[col * 2 + 0], s);
        atomicAdd(&sbn[col * 2 + 1], q);
    }
    __syncthreads();
    if (tid < BN) {
        atomicAdd(&bnsum[n0 + tid], sbn[tid * 2 + 0]);
        atomicAdd(&bnsq[n0 + tid], sbn[tid * 2 + 1]);
    }
}

// ---- BN finalize ----
__global__ void bn_finalize(const float* __restrict__ sum, const float* __restrict__ sumsq,
                            const float* __restrict__ gamma, const float* __restrict__ beta,
                            float* __restrict__ scale, float* __restrict__ shift, int M, int N)
{
    int c = blockIdx.x * 256 + threadIdx.x;
    if (c >= N) return;
    float mu = sum[c] / (float)M;
    float var = sumsq[c] / (float)M - mu * mu;
    float sc = gamma[c] * rsqrtf(var + BN_EPS);
    scale[c] = sc;
    shift[c] = beta[c] - mu * sc;
}

// ---- BN apply + ELU: bf16 h -> bf16 out ----
__global__ void norm_elu_bb(const unsigned short* __restrict__ h, const float* __restrict__ scale,
                            const float* __restrict__ shift, unsigned short* __restrict__ out,
                            int N, long total)
{
    long i = ((long)blockIdx.x * 256 + threadIdx.x) * 4;
    if (i >= total) return;
    int c = (int)(i % N);
    ushort4 u = *(const ushort4*)(h + i);
    float4 sc = *(const float4*)(scale + c);
    float4 sh = *(const float4*)(shift + c);
    float v0 = b2f(u.x) * sc.x + sh.x;
    float v1 = b2f(u.y) * sc.y + sh.y;
    float v2 = b2f(u.z) * sc.z + sh.z;
    float v3 = b2f(u.w) * sc.w + sh.w;
    v0 = v0 > 0.f ? v0 : expm1f(v0);
    v1 = v1 > 0.f ? v1 : expm1f(v1);
    v2 = v2 > 0.f ? v2 : expm1f(v2);
    v3 = v3 > 0.f ? v3 : expm1f(v3);
    ushort4 o;
    o.x = f2b(v0); o.y = f2b(v1); o.z = f2b(v2); o.w = f2b(v3);
    *(ushort4*)(out + i) = o;
}

// ---- BN apply + ELU: bf16 h -> f32 out (final layer) ----
__global__ void norm_elu_bf(const unsigned short* __restrict__ h, const float* __restrict__ scale,
                            const float* __restrict__ shift, float* __restrict__ out,
                            int N, long total)
{
    long i = ((long)blockIdx.x * 256 + threadIdx.x) * 4;
    if (i >= total) return;
    int c = (int)(i % N);
    ushort4 u = *(const ushort4*)(h + i);
    float4 sc = *(const float4*)(scale + c);
    float4 sh = *(const float4*)(shift + c);
    float4 o;
    o.x = b2f(u.x) * sc.x + sh.x;
    o.y = b2f(u.y) * sc.y + sh.y;
    o.z = b2f(u.z) * sc.z + sh.z;
    o.w = b2f(u.w) * sc.w + sh.w;
    o.x = o.x > 0.f ? o.x : expm1f(o.x);
    o.y = o.y > 0.f ? o.y : expm1f(o.y);
    o.z = o.z > 0.f ? o.z : expm1f(o.z);
    o.w = o.w > 0.f ? o.w : expm1f(o.w);
    *(float4*)(out + i) = o;
}

// =====================================================================
extern "C" void kernel_launch(void* const* d_in, const int* in_sizes, int n_in,
                              void* d_out, int out_size, void* d_ws, size_t ws_size,
                              hipStream_t stream)
{
    const float* x = (const float*)d_in[0];
    auto P = [&](int layer, int slot) -> const float* {
        return (const float*)d_in[1 + (layer - 1) * 9 + slot];
    };
    const int* edge_src[3] = { (const int*)d_in[28], (const int*)d_in[30], (const int*)d_in[32] };
    const int* edge_dst[3] = { (const int*)d_in[29], (const int*)d_in[31], (const int*)d_in[33] };
    const int Es[3] = { E1, E2, E3 };

    // -------- workspace carve --------
    char* wsb = (char*)d_ws;
    size_t off = 0;
    auto alloc = [&](size_t bytes) -> void* {
        void* p = wsb + off;
        off = (off + bytes + 255) & ~(size_t)255;
        return p;
    };
    unsigned short* xb0   = (unsigned short*)alloc((size_t)N0 * 128 * 2);
    unsigned short* x1b   = (unsigned short*)alloc((size_t)S1 * 1024 * 2);
    unsigned short* x2b   = (unsigned short*)alloc((size_t)S2 * 1024 * 2);
    unsigned short* hb    = (unsigned short*)alloc((size_t)S1 * 1024 * 2);
    unsigned short* aggb  = (unsigned short*)alloc((size_t)S2 * 4096 * 2);
    unsigned short* wskipb= (unsigned short*)alloc((size_t)1024 * 1024 * 2);
    unsigned short* wsrcb = (unsigned short*)alloc((size_t)1024 * 1024 * 2);
    float* al_src  = (float*)alloc((size_t)N0 * 4 * 4);
    float* al_dst  = (float*)alloc((size_t)S1 * 4 * 4);
    float* vsrc    = (float*)alloc(4 * 1024 * 4);
    float* vdst    = (float*)alloc(4 * 1024 * 4);
    float* m4      = (float*)alloc((size_t)S1 * 4 * 4);
    float* rdn     = (float*)alloc((size_t)S1 * 4 * 4);
    float* aself   = (float*)alloc((size_t)S1 * 4 * 4);
    float* walpha  = (float*)alloc((size_t)E1 * 4 * 4);
    int*   offsets = (int*)alloc((size_t)(S1 + 1) * 4);
    int*   cursor  = (int*)alloc((size_t)S1 * 4);
    int*   counts  = (int*)alloc((size_t)S1 * 4);
    int*   elist   = (int*)alloc((size_t)E1 * 4);
    float* bnsum   = (float*)alloc(1024 * 4);
    float* bnsq    = (float*)alloc(1024 * 4);

    // input features -> bf16 once
    conv_kernel<<<(int)(((long)N0 * 128 / 4 + 255) / 256), 256, 0, stream>>>(x, xb0, (long)N0 * 128);

    auto run_layer = [&](int L, const unsigned short* xa, int n_all, int size, int din, int dfull,
                         unsigned short* outb, float* outf)
    {
        const float* wsrc  = P(L, 0);
        const float* wdst  = P(L, 1);
        const float* asrc  = P(L, 2);
        const float* adst  = P(L, 3);
        const float* wskip = P(L, 5);
        const float* gamma = P(L, 7);
        const float* beta  = P(L, 8);
        const int* esrc = edge_src[L - 1];
        const int* edst = edge_dst[L - 1];
        int E = Es[L - 1];

        // fold attention into weights; attention logits
        fold_kernel<<<dim3((din + 63) / 64, 4), 64, 0, stream>>>(asrc, wsrc, vsrc, din);
        fold_kernel<<<dim3((din + 63) / 64, 4), 64, 0, stream>>>(adst, wdst, vdst, din);
        if (din == 128) {
            al128_kernel<<<512, 256, 0, stream>>>(xa, vsrc, al_src, n_all);
            al128_kernel<<<512, 256, 0, stream>>>(xa, vdst, al_dst, size);
        } else {
            al1024_kernel<<<256, 256, 0, stream>>>(xa, vsrc, al_src, n_all);
            al1024_kernel<<<256, 256, 0, stream>>>(xa, vdst, al_dst, size);
        }
        // CSR by destination (scan also seeds cursor)
        hipMemsetAsync(counts, 0, (size_t)size * 4, stream);
        count_kernel<<<(E + 255) / 256, 256, 0, stream>>>(edst, E, counts);
        scan_kernel<<<1, 1024, 0, stream>>>(counts, offsets, cursor, size);
        scatter_kernel<<<(E + 255) / 256, 256, 0, stream>>>(edst, E, cursor, elist);
        // softmax stats + per-edge alpha
        mdn_kernel<<<(size + 255) / 256, 256, 0, stream>>>(al_src, al_dst, offsets, elist, esrc,
                                                           size, m4, rdn, aself);
        alpha_kernel<<<(E + 255) / 256, 256, 0, stream>>>(al_src, al_dst, esrc, edst, m4, rdn,
                                                          E, walpha);
        // aggregation (bf16 in/out)
        if (din == 128)
            agg128_kernel<<<size, 64, 0, stream>>>(xa, walpha, aself, offsets, elist, esrc, aggb);
        else
            agg1024_kernel<<<size, 256, 0, stream>>>(xa, walpha, aself, offsets, elist, esrc, aggb);
        // weight prep (bf16)
        conv_kernel<<<(int)(((long)dfull * din / 4 + 255) / 256), 256, 0, stream>>>(
            wskip, wskipb, (long)dfull * din);
        if (L < 3)
            conv_kernel<<<(int)((1024L * din / 4 + 255) / 256), 256, 0, stream>>>(wsrc, wsrcb, 1024L * din);
        else
            repack_w3b<<<(256 * 4096 + 255) / 256, 256, 0, stream>>>(wsrc, wsrcb);
        // fused GEMM (skip + GAT) with BN stats, bf16 out
        hipMemsetAsync(bnsum, 0, (size_t)dfull * 4, stream);
        hipMemsetAsync(bnsq, 0, (size_t)dfull * 4, stream);
        if (L == 1) {
            gemm2_kernel<128, 128><<<dim3(1024 / 128, S1 / 128), 256, 0, stream>>>(
                xa, din, wskipb, din,
                aggb, 4 * din, wsrcb, din, din, 256,
                hb, dfull, bnsum, bnsq);
        } else if (L == 2) {
            gemm2_kernel<64, 64><<<dim3(1024 / 64, S2 / 64), 256, 0, stream>>>(
                xa, din, wskipb, din,
                aggb, 4 * din, wsrcb, din, din, 256,
                hb, dfull, bnsum, bnsq);
        } else {
            gemm2_kernel<64, 64><<<dim3(256 / 64, S3 / 64), 256, 0, stream>>>(
                xa, din, wskipb, din,
                aggb, 4 * din, wsrcb, 4 * din, 0, 0,
                hb, dfull, bnsum, bnsq);
        }
        // batchnorm + elu
        bn_finalize<<<(dfull + 255) / 256, 256, 0, stream>>>(bnsum, bnsq, gamma, beta, bnsum, bnsq, size, dfull);
        long total = (long)size * dfull;
        if (outb)
            norm_elu_bb<<<(int)((total / 4 + 255) / 256), 256, 0, stream>>>(hb, bnsum, bnsq, outb, dfull, total);
        else
            norm_elu_bf<<<(int)((total / 4 + 255) / 256), 256, 0, stream>>>(hb, bnsum, bnsq, outf, dfull, total);
    };

    run_layer(1, xb0, N0, S1, 128,  1024, x1b, nullptr);
    run_layer(2, x1b, S1, S2, 1024, 1024, x2b, nullptr);
    run_layer(3, x2b, S2, S3, 1024, 256, nullptr, (float*)d_out);
}

// Round 6
// 757.567 us; speedup vs baseline: 2.5885x; 1.1565x over previous
//
#include <hip/hip_runtime.h>
#include <math.h>

// ---------------- problem constants (from reference) ----------------
constexpr int N0 = 262144, S1 = 32768, S2 = 4096, S3 = 512;
constexpr int E1 = 327680, E2 = 40960, E3 = 5120;
constexpr float NEG = 0.2f, BN_EPS = 1e-5f;

typedef __attribute__((ext_vector_type(8))) short short8;   // 8 bf16 (4 VGPRs)
typedef __attribute__((ext_vector_type(4))) float f32x4;    // MFMA acc

__device__ __forceinline__ float lrelu(float x) { return x > 0.f ? x : NEG * x; }

__device__ __forceinline__ unsigned short f2b(float f) {  // f32 -> bf16 RNE
    unsigned int u = __float_as_uint(f);
    return (unsigned short)((u + 0x7FFFu + ((u >> 16) & 1u)) >> 16);
}
__device__ __forceinline__ float b2f(unsigned short u) {
    return __uint_as_float(((unsigned int)u) << 16);
}
__device__ __forceinline__ void ld4(const float* __restrict__ p, float* o) {
    float4 v = *(const float4*)p;
    o[0] = v.x; o[1] = v.y; o[2] = v.z; o[3] = v.w;
}

// ==================== one-shot prep ====================
// blocks 0..67   : attention folds, 256 outputs/block
//   fold job f: v[f][h*din+k] = sum_j att[f][h*256+j] * w[f][(h*256+j)*din+k]
//   chunks per job: {2,2,16,16,16,16}  (4*din/256)
// blocks 68..123 : weight f32->bf16 convs, 65536 elems/block
//   jobs: wskip1(131072), wsrc1(131072), wskip2(1048576), wsrc2(1048576),
//         wskip3(262144), w3-repack(1048576)  -> blocks {2,2,16,16,4,16}
// blocks 124..166: zero region (counts x3 + bn stats x6), int4 stores
struct PrepArgs {
    const float* att[6]; const float* wf[6]; float* v[6];
    const float* csrc[6]; unsigned short* cdst[6];
    int* zptr; int zn4;
};

__global__ void prep_kernel(PrepArgs a)
{
    int b = blockIdx.x, t = threadIdx.x;
    if (b < 68) {
        int f, cb;
        if (b < 2)       { f = 0; cb = b; }
        else if (b < 4)  { f = 1; cb = b - 2; }
        else if (b < 20) { f = 2; cb = b - 4; }
        else if (b < 36) { f = 3; cb = b - 20; }
        else if (b < 52) { f = 4; cb = b - 36; }
        else             { f = 5; cb = b - 52; }
        int din = (f < 2) ? 128 : 1024;
        int idx = cb * 256 + t;           // < 4*din by construction
        int h = idx / din, k = idx - h * din;
        const float* ar = a.att[f] + h * 256;
        const float* wr = a.wf[f] + (size_t)(h * 256) * din + k;
        float acc = 0.f;
        for (int j = 0; j < 256; ++j) acc += ar[j] * wr[(size_t)j * din];
        a.v[f][idx] = acc;
    } else if (b < 124) {
        int c = b - 68, j, ob;
        if (c < 2)       { j = 0; ob = c; }
        else if (c < 4)  { j = 1; ob = c - 2; }
        else if (c < 20) { j = 2; ob = c - 4; }
        else if (c < 36) { j = 3; ob = c - 20; }
        else if (c < 40) { j = 4; ob = c - 36; }
        else             { j = 5; ob = c - 40; }
        long base = (long)ob * 65536;
        if (j < 5) {
            const float* src = a.csrc[j];
            unsigned short* dst = a.cdst[j];
            for (int it = 0; it < 64; ++it) {
                long e = base + (long)(it * 256 + t) * 4;
                float4 v = *(const float4*)(src + e);
                ushort4 u;
                u.x = f2b(v.x); u.y = f2b(v.y); u.z = f2b(v.z); u.w = f2b(v.w);
                *(ushort4*)(dst + e) = u;
            }
        } else {  // w3 repack: wp[row*4096 + h*1024 + k] = 0.25*w[(h*256+row)*1024+k]
            const float* src = a.csrc[5];
            unsigned short* dst = a.cdst[5];
            for (int it = 0; it < 64; ++it) {
                long e = base + (long)(it * 256 + t) * 4;
                int row = (int)(e >> 12);
                int hk = (int)(e & 4095);
                int h = hk >> 10, k = hk & 1023;
                float4 v = *(const float4*)(src + ((size_t)(h * 256 + row) << 10) + k);
                ushort4 u;
                u.x = f2b(0.25f * v.x); u.y = f2b(0.25f * v.y);
                u.z = f2b(0.25f * v.z); u.w = f2b(0.25f * v.w);
                *(ushort4*)(dst + e) = u;
            }
        }
    } else {
        int i = (b - 124) * 256 + t;
        if (i < a.zn4) ((int4*)a.zptr)[i] = make_int4(0, 0, 0, 0);
    }
}

// ==================== L1: fused f32->bf16 conv + al_src + al_dst ====================
__global__ void al128f_kernel(const float* __restrict__ x, const float* __restrict__ vs,
                              const float* __restrict__ vd, unsigned short* __restrict__ xb,
                              float* __restrict__ als, float* __restrict__ ald, int n, int ndst)
{
    int lane = threadIdx.x & 63;
    int wave = (blockIdx.x * 256 + threadIdx.x) >> 6;
    int nw = (gridDim.x * 256) >> 6;
    int j32 = lane & 31, half = lane >> 5;
    float vsr[4][4], vdr[4][4];
    #pragma unroll
    for (int h = 0; h < 4; ++h) {
        ld4(vs + h * 128 + j32 * 4, vsr[h]);
        ld4(vd + h * 128 + j32 * 4, vdr[h]);
    }
    for (long node = (long)wave * 2 + half; node < n; node += (long)nw * 2) {
        float4 xv = *(const float4*)(x + node * 128 + j32 * 4);
        ushort4 u;
        u.x = f2b(xv.x); u.y = f2b(xv.y); u.z = f2b(xv.z); u.w = f2b(xv.w);
        *(ushort4*)(xb + node * 128 + j32 * 4) = u;
        float xf[4] = { xv.x, xv.y, xv.z, xv.w };
        float a[4], bv[4];
        bool isd = node < ndst;   // uniform within each 32-lane half
        #pragma unroll
        for (int h = 0; h < 4; ++h)
            a[h] = xf[0]*vsr[h][0] + xf[1]*vsr[h][1] + xf[2]*vsr[h][2] + xf[3]*vsr[h][3];
        if (isd) {
            #pragma unroll
            for (int h = 0; h < 4; ++h)
                bv[h] = xf[0]*vdr[h][0] + xf[1]*vdr[h][1] + xf[2]*vdr[h][2] + xf[3]*vdr[h][3];
        }
        #pragma unroll
        for (int off = 16; off > 0; off >>= 1) {
            #pragma unroll
            for (int h = 0; h < 4; ++h) a[h] += __shfl_xor(a[h], off);
            if (isd)
                #pragma unroll
                for (int h = 0; h < 4; ++h) bv[h] += __shfl_xor(bv[h], off);
        }
        if (j32 == 0) {
            *(float4*)(als + node * 4) = make_float4(a[0], a[1], a[2], a[3]);
            if (isd) *(float4*)(ald + node * 4) = make_float4(bv[0], bv[1], bv[2], bv[3]);
        }
    }
}

// ==================== L2/L3: al_src + al_dst in one pass (bf16 features) ====================
__global__ void al1024f_kernel(const unsigned short* __restrict__ xb, const float* __restrict__ vs,
                               const float* __restrict__ vd,
                               float* __restrict__ als, float* __restrict__ ald, int n, int ndst)
{
    int lane = threadIdx.x & 63;
    int wave = (blockIdx.x * 256 + threadIdx.x) >> 6;
    int nw = (gridDim.x * 256) >> 6;
    float vsr[4][16], vdr[4][16];
    #pragma unroll
    for (int h = 0; h < 4; ++h)
        #pragma unroll
        for (int it = 0; it < 2; ++it) {
            ld4(vs + h * 1024 + it * 512 + lane * 8,     &vsr[h][it * 8]);
            ld4(vs + h * 1024 + it * 512 + lane * 8 + 4, &vsr[h][it * 8 + 4]);
            ld4(vd + h * 1024 + it * 512 + lane * 8,     &vdr[h][it * 8]);
            ld4(vd + h * 1024 + it * 512 + lane * 8 + 4, &vdr[h][it * 8 + 4]);
        }
    for (long node = wave; node < n; node += nw) {
        const unsigned short* xr = xb + node * 1024;
        bool isd = node < ndst;   // wave-uniform
        float a[4] = {0.f, 0.f, 0.f, 0.f}, bv[4] = {0.f, 0.f, 0.f, 0.f};
        #pragma unroll
        for (int it = 0; it < 2; ++it) {
            short8 u = *(const short8*)(xr + it * 512 + lane * 8);
            float xf[8];
            #pragma unroll
            for (int j = 0; j < 8; ++j) xf[j] = b2f((unsigned short)u[j]);
            #pragma unroll
            for (int h = 0; h < 4; ++h)
                #pragma unroll
                for (int j = 0; j < 8; ++j) a[h] += xf[j] * vsr[h][it * 8 + j];
            if (isd)
                #pragma unroll
                for (int h = 0; h < 4; ++h)
                    #pragma unroll
                    for (int j = 0; j < 8; ++j) bv[h] += xf[j] * vdr[h][it * 8 + j];
        }
        #pragma unroll
        for (int off = 32; off > 0; off >>= 1) {
            #pragma unroll
            for (int h = 0; h < 4; ++h) a[h] += __shfl_xor(a[h], off);
            if (isd)
                #pragma unroll
                for (int h = 0; h < 4; ++h) bv[h] += __shfl_xor(bv[h], off);
        }
        if (lane == 0) {
            *(float4*)(als + node * 4) = make_float4(a[0], a[1], a[2], a[3]);
            if (isd) *(float4*)(ald + node * 4) = make_float4(bv[0], bv[1], bv[2], bv[3]);
        }
    }
}

// ==================== CSR build ====================
__global__ void count_kernel(const int* __restrict__ dst, int E, int* __restrict__ counts)
{
    int e = blockIdx.x * 256 + threadIdx.x;
    if (e < E) atomicAdd(&counts[dst[e]], 1);
}

__global__ void scan_kernel(const int* __restrict__ counts, int* __restrict__ offsets,
                            int* __restrict__ cursor, int size)
{
    __shared__ int lds[1024];
    int t = threadIdx.x;
    int chunk = (size + 1023) >> 10;
    int begin = t * chunk;
    int end = begin + chunk; if (end > size) end = size;
    if (begin > size) begin = size;
    int s = 0;
    if ((chunk & 3) == 0) {
        for (int i = begin; i < end; i += 4) {
            int4 v = *(const int4*)(counts + i);
            s += v.x + v.y + v.z + v.w;
        }
    } else {
        for (int i = begin; i < end; ++i) s += counts[i];
    }
    lds[t] = s;
    __syncthreads();
    for (int d = 1; d < 1024; d <<= 1) {
        int v = (t >= d) ? lds[t - d] : 0;
        __syncthreads();
        lds[t] += v;
        __syncthreads();
    }
    int base = (t > 0) ? lds[t - 1] : 0;
    for (int i = begin; i < end; ++i) {
        offsets[i] = base; cursor[i] = base;
        base += counts[i];
    }
    if (t == 1023) offsets[size] = lds[1023];
}

__global__ void scatter_kernel(const int* __restrict__ dst, int E,
                               int* __restrict__ cursor, int* __restrict__ elist)
{
    int e = blockIdx.x * 256 + threadIdx.x;
    if (e < E) { int p = atomicAdd(&cursor[dst[e]], 1); elist[p] = e; }
}

// ==================== per-destination softmax stats ====================
__global__ void mdn_kernel(const float* __restrict__ als, const float* __restrict__ ald,
                           const int* __restrict__ offsets, const int* __restrict__ elist,
                           const int* __restrict__ esrc, int size,
                           float* __restrict__ m4, float* __restrict__ rdn,
                           float* __restrict__ aself)
{
    int d = blockIdx.x * 256 + threadIdx.x;
    if (d >= size) return;
    float ad[4], sl[4], m[4], q[4], dn[4];
    ld4(ald + 4 * (size_t)d, ad);
    ld4(als + 4 * (size_t)d, q);
    #pragma unroll
    for (int h = 0; h < 4; ++h) { sl[h] = lrelu(q[h] + ad[h]); m[h] = sl[h]; }
    int beg = offsets[d], end = offsets[d + 1];
    for (int p = beg; p < end; ++p) {
        int s = esrc[elist[p]];
        ld4(als + 4 * (size_t)s, q);
        #pragma unroll
        for (int h = 0; h < 4; ++h) m[h] = fmaxf(m[h], lrelu(q[h] + ad[h]));
    }
    #pragma unroll
    for (int h = 0; h < 4; ++h) dn[h] = expf(sl[h] - m[h]);
    for (int p = beg; p < end; ++p) {
        int s = esrc[elist[p]];
        ld4(als + 4 * (size_t)s, q);
        #pragma unroll
        for (int h = 0; h < 4; ++h) dn[h] += expf(lrelu(q[h] + ad[h]) - m[h]);
    }
    #pragma unroll
    for (int h = 0; h < 4; ++h) {
        float r = 1.f / (dn[h] + 1e-16f);
        m4[4 * (size_t)d + h] = m[h];
        rdn[4 * (size_t)d + h] = r;
        aself[4 * (size_t)d + h] = expf(sl[h] - m[h]) * r;
    }
}

// ==================== per-edge alpha ====================
__global__ void alpha_kernel(const float* __restrict__ als, const float* __restrict__ ald,
                             const int* __restrict__ esrc, const int* __restrict__ edst,
                             const float* __restrict__ m4, const float* __restrict__ rdn,
                             int E, float* __restrict__ walpha)
{
    int e = blockIdx.x * 256 + threadIdx.x;
    if (e >= E) return;
    int d = edst[e], s = esrc[e];
    float as_[4], ad_[4], m[4], r[4];
    ld4(als + 4 * (size_t)s, as_);
    ld4(ald + 4 * (size_t)d, ad_);
    ld4(m4 + 4 * (size_t)d, m);
    ld4(rdn + 4 * (size_t)d, r);
    float4 w;
    w.x = expf(lrelu(as_[0] + ad_[0]) - m[0]) * r[0];
    w.y = expf(lrelu(as_[1] + ad_[1]) - m[1]) * r[1];
    w.z = expf(lrelu(as_[2] + ad_[2]) - m[2]) * r[2];
    w.w = expf(lrelu(as_[3] + ad_[3]) - m[3]) * r[3];
    *(float4*)(walpha + 4 * (size_t)e) = w;
}

// ==================== aggregation (precomputed alpha) ====================
__global__ void agg128_kernel(const unsigned short* __restrict__ xb, const float* __restrict__ walpha,
                              const float* __restrict__ aself,
                              const int* __restrict__ offsets, const int* __restrict__ elist,
                              const int* __restrict__ esrc, unsigned short* __restrict__ aggb)
{
    int d = blockIdx.x, lane = threadIdx.x;
    int beg = offsets[d], end = offsets[d + 1];
    float w[4], acc[4][2];
    ld4(aself + 4 * (size_t)d, w);
    {
        unsigned int u = *(const unsigned int*)(xb + (size_t)d * 128 + lane * 2);
        float x0 = b2f((unsigned short)(u & 0xFFFF)), x1 = b2f((unsigned short)(u >> 16));
        #pragma unroll
        for (int h = 0; h < 4; ++h) { acc[h][0] = w[h] * x0; acc[h][1] = w[h] * x1; }
    }
    for (int p = beg; p < end; ++p) {
        int e = elist[p];
        int s = esrc[e];
        ld4(walpha + 4 * (size_t)e, w);
        unsigned int u = *(const unsigned int*)(xb + (size_t)s * 128 + lane * 2);
        float x0 = b2f((unsigned short)(u & 0xFFFF)), x1 = b2f((unsigned short)(u >> 16));
        #pragma unroll
        for (int h = 0; h < 4; ++h) { acc[h][0] += w[h] * x0; acc[h][1] += w[h] * x1; }
    }
    unsigned int* og = (unsigned int*)(aggb + (size_t)d * 512);
    #pragma unroll
    for (int h = 0; h < 4; ++h)
        og[h * 64 + lane] = (unsigned int)f2b(acc[h][0]) | ((unsigned int)f2b(acc[h][1]) << 16);
}

__global__ void agg1024_kernel(const unsigned short* __restrict__ xb, const float* __restrict__ walpha,
                               const float* __restrict__ aself,
                               const int* __restrict__ offsets, const int* __restrict__ elist,
                               const int* __restrict__ esrc, unsigned short* __restrict__ aggb)
{
    int d = blockIdx.x, t = threadIdx.x;
    int beg = offsets[d], end = offsets[d + 1];
    float w[4], acc[4][4];
    ld4(aself + 4 * (size_t)d, w);
    {
        ushort4 u = *(const ushort4*)(xb + (size_t)d * 1024 + t * 4);
        float xv[4] = { b2f(u.x), b2f(u.y), b2f(u.z), b2f(u.w) };
        #pragma unroll
        for (int h = 0; h < 4; ++h)
            #pragma unroll
            for (int j = 0; j < 4; ++j) acc[h][j] = w[h] * xv[j];
    }
    for (int p = beg; p < end; ++p) {
        int e = elist[p];
        int s = esrc[e];
        ld4(walpha + 4 * (size_t)e, w);
        ushort4 u = *(const ushort4*)(xb + (size_t)s * 1024 + t * 4);
        float xv[4] = { b2f(u.x), b2f(u.y), b2f(u.z), b2f(u.w) };
        #pragma unroll
        for (int h = 0; h < 4; ++h)
            #pragma unroll
            for (int j = 0; j < 4; ++j) acc[h][j] += w[h] * xv[j];
    }
    unsigned short* og = aggb + (size_t)d * 4096;
    #pragma unroll
    for (int h = 0; h < 4; ++h) {
        ushort4 u;
        u.x = f2b(acc[h][0]); u.y = f2b(acc[h][1]);
        u.z = f2b(acc[h][2]); u.w = f2b(acc[h][3]);
        *(ushort4*)(og + h * 1024 + t * 4) = u;
    }
}

// ==================== fused dual-phase bf16 MFMA GEMM + BN stats ====================
// LDS row stride 32 shorts; 16B chunk c of row r stored at chunk (c ^ ((r>>1)&3)).
#define SWZ(r, c) ((((c) ^ (((r) >> 1) & 3)) << 3))

template<int BM, int BN>
__global__ __launch_bounds__(256) void gemm2_kernel(
    const unsigned short* __restrict__ A1, int lda1, const unsigned short* __restrict__ W1, int K1,
    const unsigned short* __restrict__ A2, int lda2, const unsigned short* __restrict__ W2, int K2,
    int hs2, int cph2,
    unsigned short* __restrict__ C, int N,
    float* __restrict__ bnsum, float* __restrict__ bnsq)
{
    constexpr int WM = BM / 2, WN = BN / 2;
    constexpr int TM = WM / 16, TN = WN / 16;
    __shared__ __align__(16) unsigned short As[BM * 32];
    __shared__ __align__(16) unsigned short Bs[BN * 32];
    __shared__ float sbn[2 * BN];
    int tid = threadIdx.x;
    int n0 = blockIdx.x * BN, m0 = blockIdx.y * BM;
    int l = tid & 63, l16 = l & 15, kq = l >> 4;
    int wid = tid >> 6, wr = wid >> 1, wc = wid & 1;

    f32x4 acc[TM][TN];
    #pragma unroll
    for (int mi = 0; mi < TM; ++mi)
        #pragma unroll
        for (int ni = 0; ni < TN; ++ni) acc[mi][ni] = (f32x4){0.f, 0.f, 0.f, 0.f};

    #pragma unroll
    for (int ph = 0; ph < 2; ++ph) {
        const unsigned short* Ap = ph ? A2 + (size_t)m0 * lda2 + (cph2 ? (size_t)(n0 / cph2) * hs2 : 0)
                                      : A1 + (size_t)m0 * lda1;
        int lda = ph ? lda2 : lda1;
        const unsigned short* Wp = ph ? W2 + (size_t)n0 * K2 : W1 + (size_t)n0 * K1;
        int ldw = ph ? K2 : K1;
        int K = ph ? K2 : K1;
        for (int k0 = 0; k0 < K; k0 += 32) {
            for (int c = tid; c < BM * 4; c += 256) {
                int r = c >> 2, ch = c & 3;
                *(uint4*)&As[r * 32 + SWZ(r, ch)] = *(const uint4*)(Ap + (size_t)r * lda + k0 + (ch << 3));
            }
            for (int c = tid; c < BN * 4; c += 256) {
                int r = c >> 2, ch = c & 3;
                *(uint4*)&Bs[r * 32 + SWZ(r, ch)] = *(const uint4*)(Wp + (size_t)r * ldw + k0 + (ch << 3));
            }
            __syncthreads();
            short8 af[TM], bfr[TN];
            #pragma unroll
            for (int mi = 0; mi < TM; ++mi) {
                int r = wr * WM + mi * 16 + l16;
                af[mi] = *(const short8*)&As[r * 32 + SWZ(r, kq)];
            }
            #pragma unroll
            for (int ni = 0; ni < TN; ++ni) {
                int r = wc * WN + ni * 16 + l16;
                bfr[ni] = *(const short8*)&Bs[r * 32 + SWZ(r, kq)];
            }
            #pragma unroll
            for (int mi = 0; mi < TM; ++mi)
                #pragma unroll
                for (int ni = 0; ni < TN; ++ni)
                    acc[mi][ni] = __builtin_amdgcn_mfma_f32_16x16x32_bf16(
                        af[mi], bfr[ni], acc[mi][ni], 0, 0, 0);
            __syncthreads();
        }
    }

    if (tid < 2 * BN) sbn[tid] = 0.f;
    __syncthreads();

    #pragma unroll
    for (int ni = 0; ni < TN; ++ni) {
        int col = wc * WN + ni * 16 + l16;
        float s = 0.f, q = 0.f;
        #pragma unroll
        for (int mi = 0; mi < TM; ++mi) {
            int rowb = wr * WM + mi * 16 + (kq << 2);
            #pragma unroll
            for (int r = 0; r < 4; ++r) {
                float v = acc[mi][ni][r];
                C[(size_t)(m0 + rowb + r) * N + n0 + col] = f2b(v);
                s += v; q += v * v;
            }
        }
        atomicAdd(&sbn[col * 2 + 0], s);
        atomicAdd(&sbn[col * 2 + 1], q);
    }
    __syncthreads();
    if (tid < BN) {
        atomicAdd(&bnsum[n0 + tid], sbn[tid * 2 + 0]);
        atomicAdd(&bnsq[n0 + tid], sbn[tid * 2 + 1]);
    }
}

// ==================== BN finalize fused into apply + ELU ====================
__global__ void norm_elu_bb(const unsigned short* __restrict__ h,
                            const float* __restrict__ sum, const float* __restrict__ sq,
                            const float* __restrict__ gamma, const float* __restrict__ beta,
                            unsigned short* __restrict__ out, int N, float invM, long total)
{
    long i = ((long)blockIdx.x * 256 + threadIdx.x) * 4;
    if (i >= total) return;
    int c = (int)(i % N);
    float4 sm = *(const float4*)(sum + c);
    float4 qq = *(const float4*)(sq + c);
    float4 gm = *(const float4*)(gamma + c);
    float4 bt = *(const float4*)(beta + c);
    float mu0 = sm.x * invM, mu1 = sm.y * invM, mu2 = sm.z * invM, mu3 = sm.w * invM;
    float sc0 = gm.x * rsqrtf(qq.x * invM - mu0 * mu0 + BN_EPS);
    float sc1 = gm.y * rsqrtf(qq.y * invM - mu1 * mu1 + BN_EPS);
    float sc2 = gm.z * rsqrtf(qq.z * invM - mu2 * mu2 + BN_EPS);
    float sc3 = gm.w * rsqrtf(qq.w * invM - mu3 * mu3 + BN_EPS);
    float sh0 = bt.x - mu0 * sc0, sh1 = bt.y - mu1 * sc1;
    float sh2 = bt.z - mu2 * sc2, sh3 = bt.w - mu3 * sc3;
    ushort4 u = *(const ushort4*)(h + i);
    float v0 = b2f(u.x) * sc0 + sh0;
    float v1 = b2f(u.y) * sc1 + sh1;
    float v2 = b2f(u.z) * sc2 + sh2;
    float v3 = b2f(u.w) * sc3 + sh3;
    v0 = v0 > 0.f ? v0 : expm1f(v0);
    v1 = v1 > 0.f ? v1 : expm1f(v1);
    v2 = v2 > 0.f ? v2 : expm1f(v2);
    v3 = v3 > 0.f ? v3 : expm1f(v3);
    ushort4 o;
    o.x = f2b(v0); o.y = f2b(v1); o.z = f2b(v2); o.w = f2b(v3);
    *(ushort4*)(out + i) = o;
}

__global__ void norm_elu_bf(const unsigned short* __restrict__ h,
                            const float* __restrict__ sum, const float* __restrict__ sq,
                            const float* __restrict__ gamma, const float* __restrict__ beta,
                            float* __restrict__ out, int N, float invM, long total)
{
    long i = ((long)blockIdx.x * 256 + threadIdx.x) * 4;
    if (i >= total) return;
    int c = (int)(i % N);
    float4 sm = *(const float4*)(sum + c);
    float4 qq = *(const float4*)(sq + c);
    float4 gm = *(const float4*)(gamma + c);
    float4 bt = *(const float4*)(beta + c);
    float mu0 = sm.x * invM, mu1 = sm.y * invM, mu2 = sm.z * invM, mu3 = sm.w * invM;
    float sc0 = gm.x * rsqrtf(qq.x * invM - mu0 * mu0 + BN_EPS);
    float sc1 = gm.y * rsqrtf(qq.y * invM - mu1 * mu1 + BN_EPS);
    float sc2 = gm.z * rsqrtf(qq.z * invM - mu2 * mu2 + BN_EPS);
    float sc3 = gm.w * rsqrtf(qq.w * invM - mu3 * mu3 + BN_EPS);
    ushort4 u = *(const ushort4*)(h + i);
    float4 o;
    o.x = b2f(u.x) * sc0 + (bt.x - mu0 * sc0);
    o.y = b2f(u.y) * sc1 + (bt.y - mu1 * sc1);
    o.z = b2f(u.z) * sc2 + (bt.z - mu2 * sc2);
    o.w = b2f(u.w) * sc3 + (bt.w - mu3 * sc3);
    o.x = o.x > 0.f ? o.x : expm1f(o.x);
    o.y = o.y > 0.f ? o.y : expm1f(o.y);
    o.z = o.z > 0.f ? o.z : expm1f(o.z);
    o.w = o.w > 0.f ? o.w : expm1f(o.w);
    *(float4*)(out + i) = o;
}

// =====================================================================
extern "C" void kernel_launch(void* const* d_in, const int* in_sizes, int n_in,
                              void* d_out, int out_size, void* d_ws, size_t ws_size,
                              hipStream_t stream)
{
    const float* x = (const float*)d_in[0];
    auto P = [&](int layer, int slot) -> const float* {
        return (const float*)d_in[1 + (layer - 1) * 9 + slot];
    };
    const int* edge_src[3] = { (const int*)d_in[28], (const int*)d_in[30], (const int*)d_in[32] };
    const int* edge_dst[3] = { (const int*)d_in[29], (const int*)d_in[31], (const int*)d_in[33] };
    const int Es[3] = { E1, E2, E3 };

    // -------- workspace carve --------
    char* wsb = (char*)d_ws;
    size_t off = 0;
    auto alloc = [&](size_t bytes) -> void* {
        void* p = wsb + off;
        off = (off + bytes + 255) & ~(size_t)255;
        return p;
    };
    unsigned short* xb0   = (unsigned short*)alloc((size_t)N0 * 128 * 2);
    unsigned short* x1b   = (unsigned short*)alloc((size_t)S1 * 1024 * 2);
    unsigned short* x2b   = (unsigned short*)alloc((size_t)S2 * 1024 * 2);
    unsigned short* hb    = (unsigned short*)alloc((size_t)S1 * 1024 * 2);
    unsigned short* aggb  = (unsigned short*)alloc((size_t)S2 * 4096 * 2);
    unsigned short* wskipb[3] = {
        (unsigned short*)alloc(131072 * 2),
        (unsigned short*)alloc(1048576 * 2),
        (unsigned short*)alloc(262144 * 2) };
    unsigned short* wsrcb[3] = {
        (unsigned short*)alloc(131072 * 2),
        (unsigned short*)alloc(1048576 * 2),
        (unsigned short*)alloc(1048576 * 2) };
    float* vbuf[6];
    vbuf[0] = (float*)alloc(512 * 4);
    vbuf[1] = (float*)alloc(512 * 4);
    vbuf[2] = (float*)alloc(4096 * 4);
    vbuf[3] = (float*)alloc(4096 * 4);
    vbuf[4] = (float*)alloc(4096 * 4);
    vbuf[5] = (float*)alloc(4096 * 4);
    float* als     = (float*)alloc((size_t)N0 * 4 * 4);
    float* ald     = (float*)alloc((size_t)S1 * 4 * 4);
    float* m4      = (float*)alloc((size_t)S1 * 4 * 4);
    float* rdn     = (float*)alloc((size_t)S1 * 4 * 4);
    float* aself   = (float*)alloc((size_t)S1 * 4 * 4);
    float* walpha  = (float*)alloc((size_t)E1 * 4 * 4);
    int*   offsets = (int*)alloc((size_t)(S1 + 1) * 4);
    int*   cursor  = (int*)alloc((size_t)S1 * 4);
    int*   elist   = (int*)alloc((size_t)E1 * 4);
    // contiguous zero region: counts x3 + bn stats (sum,sq) x3 layers
    int zn = S1 + S2 + S3 + 6 * 1024;            // 43520 ints, 16B-divisible
    int* zreg = (int*)alloc((size_t)zn * 4);
    int* counts[3] = { zreg, zreg + S1, zreg + S1 + S2 };
    float* bnsum[3] = { (float*)(zreg + S1 + S2 + S3),
                        (float*)(zreg + S1 + S2 + S3 + 2048),
                        (float*)(zreg + S1 + S2 + S3 + 4096) };
    float* bnsq[3]  = { bnsum[0] + 1024, bnsum[1] + 1024, bnsum[2] + 1024 };

    // -------- one-shot prep: folds + weight bf16 + zeroing --------
    PrepArgs pa;
    for (int L = 0; L < 3; ++L) {
        pa.att[2 * L]     = P(L + 1, 2); pa.wf[2 * L]     = P(L + 1, 0); pa.v[2 * L]     = vbuf[2 * L];
        pa.att[2 * L + 1] = P(L + 1, 3); pa.wf[2 * L + 1] = P(L + 1, 1); pa.v[2 * L + 1] = vbuf[2 * L + 1];
    }
    pa.csrc[0] = P(1, 5); pa.cdst[0] = wskipb[0];
    pa.csrc[1] = P(1, 0); pa.cdst[1] = wsrcb[0];
    pa.csrc[2] = P(2, 5); pa.cdst[2] = wskipb[1];
    pa.csrc[3] = P(2, 0); pa.cdst[3] = wsrcb[1];
    pa.csrc[4] = P(3, 5); pa.cdst[4] = wskipb[2];
    pa.csrc[5] = P(3, 0); pa.cdst[5] = wsrcb[2];
    pa.zptr = zreg; pa.zn4 = zn / 4;
    prep_kernel<<<167, 256, 0, stream>>>(pa);

    auto csr_and_agg = [&](int L, const unsigned short* xa, int size, int din)
    {
        const int* es = edge_src[L - 1];
        const int* ed = edge_dst[L - 1];
        int E = Es[L - 1];
        count_kernel<<<(E + 255) / 256, 256, 0, stream>>>(ed, E, counts[L - 1]);
        scan_kernel<<<1, 1024, 0, stream>>>(counts[L - 1], offsets, cursor, size);
        scatter_kernel<<<(E + 255) / 256, 256, 0, stream>>>(ed, E, cursor, elist);
        mdn_kernel<<<(size + 255) / 256, 256, 0, stream>>>(als, ald, offsets, elist, es,
                                                           size, m4, rdn, aself);
        alpha_kernel<<<(E + 255) / 256, 256, 0, stream>>>(als, ald, es, ed, m4, rdn, E, walpha);
        if (din == 128)
            agg128_kernel<<<size, 64, 0, stream>>>(xa, walpha, aself, offsets, elist, es, aggb);
        else
            agg1024_kernel<<<size, 256, 0, stream>>>(xa, walpha, aself, offsets, elist, es, aggb);
    };

    // ---------------- layer 1 ----------------
    al128f_kernel<<<2048, 256, 0, stream>>>(x, vbuf[0], vbuf[1], xb0, als, ald, N0, S1);
    csr_and_agg(1, xb0, S1, 128);
    gemm2_kernel<128, 128><<<dim3(1024 / 128, S1 / 128), 256, 0, stream>>>(
        xb0, 128, wskipb[0], 128,
        aggb, 512, wsrcb[0], 128, 128, 256,
        hb, 1024, bnsum[0], bnsq[0]);
    norm_elu_bb<<<(int)(((long)S1 * 1024 / 4 + 255) / 256), 256, 0, stream>>>(
        hb, bnsum[0], bnsq[0], P(1, 7), P(1, 8), x1b, 1024, 1.f / S1, (long)S1 * 1024);

    // ---------------- layer 2 ----------------
    al1024f_kernel<<<512, 256, 0, stream>>>(x1b, vbuf[2], vbuf[3], als, ald, S1, S2);
    csr_and_agg(2, x1b, S2, 1024);
    gemm2_kernel<64, 64><<<dim3(1024 / 64, S2 / 64), 256, 0, stream>>>(
        x1b, 1024, wskipb[1], 1024,
        aggb, 4096, wsrcb[1], 1024, 1024, 256,
        hb, 1024, bnsum[1], bnsq[1]);
    norm_elu_bb<<<(int)(((long)S2 * 1024 / 4 + 255) / 256), 256, 0, stream>>>(
        hb, bnsum[1], bnsq[1], P(2, 7), P(2, 8), x2b, 1024, 1.f / S2, (long)S2 * 1024);

    // ---------------- layer 3 ----------------
    al1024f_kernel<<<64, 256, 0, stream>>>(x2b, vbuf[4], vbuf[5], als, ald, S2, S3);
    csr_and_agg(3, x2b, S3, 1024);
    gemm2_kernel<64, 64><<<dim3(256 / 64, S3 / 64), 256, 0, stream>>>(
        x2b, 1024, wskipb[2], 1024,
        aggb, 4096, wsrcb[2], 4096, 0, 0,
        hb, 256, bnsum[2], bnsq[2]);
    norm_elu_bf<<<(int)(((long)S3 * 256 / 4 + 255) / 256), 256, 0, stream>>>(
        hb, bnsum[2], bnsq[2], P(3, 7), P(3, 8), (float*)d_out, 256, 1.f / S3, (long)S3 * 256);
}

// Round 7
// 721.614 us; speedup vs baseline: 2.7174x; 1.0498x over previous
//
#include <hip/hip_runtime.h>
#include <math.h>

// ---------------- problem constants (from reference) ----------------
constexpr int N0 = 262144, S1 = 32768, S2 = 4096, S3 = 512;
constexpr int E1 = 327680, E2 = 40960, E3 = 5120;
constexpr float NEG = 0.2f, BN_EPS = 1e-5f;

typedef __attribute__((ext_vector_type(8))) short short8;   // 8 bf16 (4 VGPRs)
typedef __attribute__((ext_vector_type(4))) float f32x4;    // MFMA acc

__device__ __forceinline__ float lrelu(float x) { return x > 0.f ? x : NEG * x; }

__device__ __forceinline__ unsigned short f2b(float f) {  // f32 -> bf16 RNE
    unsigned int u = __float_as_uint(f);
    return (unsigned short)((u + 0x7FFFu + ((u >> 16) & 1u)) >> 16);
}
__device__ __forceinline__ float b2f(unsigned short u) {
    return __uint_as_float(((unsigned int)u) << 16);
}
__device__ __forceinline__ void ld4(const float* __restrict__ p, float* o) {
    float4 v = *(const float4*)p;
    o[0] = v.x; o[1] = v.y; o[2] = v.z; o[3] = v.w;
}

// ==================== one-shot prep ====================
// blocks 0..67   : attention folds, 256 outputs/block
// blocks 68..123 : weight f32->bf16 convs, 65536 elems/block
// blocks 124..166: zero region (counts x3 + bn stats x6), int4 stores
struct PrepArgs {
    const float* att[6]; const float* wf[6]; float* v[6];
    const float* csrc[6]; unsigned short* cdst[6];
    int* zptr; int zn4;
};

__global__ void prep_kernel(PrepArgs a)
{
    int b = blockIdx.x, t = threadIdx.x;
    if (b < 68) {
        int f, cb;
        if (b < 2)       { f = 0; cb = b; }
        else if (b < 4)  { f = 1; cb = b - 2; }
        else if (b < 20) { f = 2; cb = b - 4; }
        else if (b < 36) { f = 3; cb = b - 20; }
        else if (b < 52) { f = 4; cb = b - 36; }
        else             { f = 5; cb = b - 52; }
        int din = (f < 2) ? 128 : 1024;
        int idx = cb * 256 + t;
        int h = idx / din, k = idx - h * din;
        const float* ar = a.att[f] + h * 256;
        const float* wr = a.wf[f] + (size_t)(h * 256) * din + k;
        float acc = 0.f;
        for (int j = 0; j < 256; ++j) acc += ar[j] * wr[(size_t)j * din];
        a.v[f][idx] = acc;
    } else if (b < 124) {
        int c = b - 68, j, ob;
        if (c < 2)       { j = 0; ob = c; }
        else if (c < 4)  { j = 1; ob = c - 2; }
        else if (c < 20) { j = 2; ob = c - 4; }
        else if (c < 36) { j = 3; ob = c - 20; }
        else if (c < 40) { j = 4; ob = c - 36; }
        else             { j = 5; ob = c - 40; }
        long base = (long)ob * 65536;
        if (j < 5) {
            const float* src = a.csrc[j];
            unsigned short* dst = a.cdst[j];
            for (int it = 0; it < 64; ++it) {
                long e = base + (long)(it * 256 + t) * 4;
                float4 v = *(const float4*)(src + e);
                ushort4 u;
                u.x = f2b(v.x); u.y = f2b(v.y); u.z = f2b(v.z); u.w = f2b(v.w);
                *(ushort4*)(dst + e) = u;
            }
        } else {  // w3 repack: wp[row*4096 + h*1024 + k] = 0.25*w[(h*256+row)*1024+k]
            const float* src = a.csrc[5];
            unsigned short* dst = a.cdst[5];
            for (int it = 0; it < 64; ++it) {
                long e = base + (long)(it * 256 + t) * 4;
                int row = (int)(e >> 12);
                int hk = (int)(e & 4095);
                int h = hk >> 10, k = hk & 1023;
                float4 v = *(const float4*)(src + ((size_t)(h * 256 + row) << 10) + k);
                ushort4 u;
                u.x = f2b(0.25f * v.x); u.y = f2b(0.25f * v.y);
                u.z = f2b(0.25f * v.z); u.w = f2b(0.25f * v.w);
                *(ushort4*)(dst + e) = u;
            }
        }
    } else {
        int i = (b - 124) * 256 + t;
        if (i < a.zn4) ((int4*)a.zptr)[i] = make_int4(0, 0, 0, 0);
    }
}

// ==================== L1: fused f32->bf16 conv + al_src + al_dst ====================
// v-state: 32+32 floats/lane -> register-fit (no spill).
__global__ void al128f_kernel(const float* __restrict__ x, const float* __restrict__ vs,
                              const float* __restrict__ vd, unsigned short* __restrict__ xb,
                              float* __restrict__ als, float* __restrict__ ald, int n, int ndst)
{
    int lane = threadIdx.x & 63;
    int wave = (blockIdx.x * 256 + threadIdx.x) >> 6;
    int nw = (gridDim.x * 256) >> 6;
    int j32 = lane & 31, half = lane >> 5;
    float vsr[4][4], vdr[4][4];
    #pragma unroll
    for (int h = 0; h < 4; ++h) {
        ld4(vs + h * 128 + j32 * 4, vsr[h]);
        ld4(vd + h * 128 + j32 * 4, vdr[h]);
    }
    for (long node = (long)wave * 2 + half; node < n; node += (long)nw * 2) {
        float4 xv = *(const float4*)(x + node * 128 + j32 * 4);
        ushort4 u;
        u.x = f2b(xv.x); u.y = f2b(xv.y); u.z = f2b(xv.z); u.w = f2b(xv.w);
        *(ushort4*)(xb + node * 128 + j32 * 4) = u;
        float xf[4] = { xv.x, xv.y, xv.z, xv.w };
        float a[4], bv[4];
        bool isd = node < ndst;   // uniform within each 32-lane half
        #pragma unroll
        for (int h = 0; h < 4; ++h)
            a[h] = xf[0]*vsr[h][0] + xf[1]*vsr[h][1] + xf[2]*vsr[h][2] + xf[3]*vsr[h][3];
        if (isd) {
            #pragma unroll
            for (int h = 0; h < 4; ++h)
                bv[h] = xf[0]*vdr[h][0] + xf[1]*vdr[h][1] + xf[2]*vdr[h][2] + xf[3]*vdr[h][3];
        }
        #pragma unroll
        for (int off = 16; off > 0; off >>= 1) {
            #pragma unroll
            for (int h = 0; h < 4; ++h) a[h] += __shfl_xor(a[h], off);
            if (isd)
                #pragma unroll
                for (int h = 0; h < 4; ++h) bv[h] += __shfl_xor(bv[h], off);
        }
        if (j32 == 0) {
            *(float4*)(als + node * 4) = make_float4(a[0], a[1], a[2], a[3]);
            if (isd) *(float4*)(ald + node * 4) = make_float4(bv[0], bv[1], bv[2], bv[3]);
        }
    }
}

// ==================== L2/L3: al[n,h]=dot(x[n],v[h]) — 64 v-floats/lane, register-fit ====================
__global__ void al1024_kernel(const unsigned short* __restrict__ xb, const float* __restrict__ v,
                              float* __restrict__ al, int n)
{
    int lane = threadIdx.x & 63;
    int wave = (blockIdx.x * 256 + threadIdx.x) >> 6;
    int nwaves = (gridDim.x * 256) >> 6;
    float vr[4][16];
    #pragma unroll
    for (int h = 0; h < 4; ++h)
        #pragma unroll
        for (int it = 0; it < 2; ++it) {
            ld4(v + h * 1024 + it * 512 + lane * 8,     &vr[h][it * 8]);
            ld4(v + h * 1024 + it * 512 + lane * 8 + 4, &vr[h][it * 8 + 4]);
        }
    for (long node = wave; node < n; node += nwaves) {
        const unsigned short* xr = xb + node * 1024;
        float a[4] = {0.f, 0.f, 0.f, 0.f};
        #pragma unroll
        for (int it = 0; it < 2; ++it) {
            short8 u = *(const short8*)(xr + it * 512 + lane * 8);
            #pragma unroll
            for (int j = 0; j < 8; ++j) {
                float xv = b2f((unsigned short)u[j]);
                #pragma unroll
                for (int h = 0; h < 4; ++h) a[h] += xv * vr[h][it * 8 + j];
            }
        }
        #pragma unroll
        for (int off = 32; off > 0; off >>= 1)
            #pragma unroll
            for (int h = 0; h < 4; ++h) a[h] += __shfl_xor(a[h], off);
        if (lane == 0) *(float4*)(al + node * 4) = make_float4(a[0], a[1], a[2], a[3]);
    }
}

// ==================== CSR build ====================
__global__ void count_kernel(const int* __restrict__ dst, int E, int* __restrict__ counts)
{
    int e = blockIdx.x * 256 + threadIdx.x;
    if (e < E) atomicAdd(&counts[dst[e]], 1);
}

__global__ void scan_kernel(const int* __restrict__ counts, int* __restrict__ offsets,
                            int* __restrict__ cursor, int size)
{
    __shared__ int lds[1024];
    int t = threadIdx.x;
    int chunk = (size + 1023) >> 10;
    int begin = t * chunk;
    int end = begin + chunk; if (end > size) end = size;
    if (begin > size) begin = size;
    int s = 0;
    if ((chunk & 3) == 0) {
        for (int i = begin; i < end; i += 4) {
            int4 v = *(const int4*)(counts + i);
            s += v.x + v.y + v.z + v.w;
        }
    } else {
        for (int i = begin; i < end; ++i) s += counts[i];
    }
    lds[t] = s;
    __syncthreads();
    for (int d = 1; d < 1024; d <<= 1) {
        int v = (t >= d) ? lds[t - d] : 0;
        __syncthreads();
        lds[t] += v;
        __syncthreads();
    }
    int base = (t > 0) ? lds[t - 1] : 0;
    for (int i = begin; i < end; ++i) {
        offsets[i] = base; cursor[i] = base;
        base += counts[i];
    }
    if (t == 1023) offsets[size] = lds[1023];
}

__global__ void scatter_kernel(const int* __restrict__ dst, int E,
                               int* __restrict__ cursor, int* __restrict__ elist)
{
    int e = blockIdx.x * 256 + threadIdx.x;
    if (e < E) { int p = atomicAdd(&cursor[dst[e]], 1); elist[p] = e; }
}

// ==================== per-destination softmax stats + per-edge alpha ====================
// Third edge loop emits walpha[e] directly (same FP ops as the old alpha_kernel);
// each CSR slot e appears exactly once -> race-free.
__global__ void mdn_kernel(const float* __restrict__ als, const float* __restrict__ ald,
                           const int* __restrict__ offsets, const int* __restrict__ elist,
                           const int* __restrict__ esrc, int size,
                           float* __restrict__ aself, float* __restrict__ walpha)
{
    int d = blockIdx.x * 256 + threadIdx.x;
    if (d >= size) return;
    float ad[4], sl[4], m[4], q[4], dn[4];
    ld4(ald + 4 * (size_t)d, ad);
    ld4(als + 4 * (size_t)d, q);
    #pragma unroll
    for (int h = 0; h < 4; ++h) { sl[h] = lrelu(q[h] + ad[h]); m[h] = sl[h]; }
    int beg = offsets[d], end = offsets[d + 1];
    for (int p = beg; p < end; ++p) {
        int s = esrc[elist[p]];
        ld4(als + 4 * (size_t)s, q);
        #pragma unroll
        for (int h = 0; h < 4; ++h) m[h] = fmaxf(m[h], lrelu(q[h] + ad[h]));
    }
    #pragma unroll
    for (int h = 0; h < 4; ++h) dn[h] = expf(sl[h] - m[h]);
    for (int p = beg; p < end; ++p) {
        int s = esrc[elist[p]];
        ld4(als + 4 * (size_t)s, q);
        #pragma unroll
        for (int h = 0; h < 4; ++h) dn[h] += expf(lrelu(q[h] + ad[h]) - m[h]);
    }
    float r[4];
    #pragma unroll
    for (int h = 0; h < 4; ++h) {
        r[h] = 1.f / (dn[h] + 1e-16f);
        aself[4 * (size_t)d + h] = expf(sl[h] - m[h]) * r[h];
    }
    for (int p = beg; p < end; ++p) {
        int e = elist[p];
        int s = esrc[e];
        ld4(als + 4 * (size_t)s, q);
        float4 w;
        w.x = expf(lrelu(q[0] + ad[0]) - m[0]) * r[0];
        w.y = expf(lrelu(q[1] + ad[1]) - m[1]) * r[1];
        w.z = expf(lrelu(q[2] + ad[2]) - m[2]) * r[2];
        w.w = expf(lrelu(q[3] + ad[3]) - m[3]) * r[3];
        *(float4*)(walpha + 4 * (size_t)e) = w;
    }
}

// ==================== aggregation (precomputed alpha) ====================
__global__ void agg128_kernel(const unsigned short* __restrict__ xb, const float* __restrict__ walpha,
                              const float* __restrict__ aself,
                              const int* __restrict__ offsets, const int* __restrict__ elist,
                              const int* __restrict__ esrc, unsigned short* __restrict__ aggb)
{
    int d = blockIdx.x, lane = threadIdx.x;
    int beg = offsets[d], end = offsets[d + 1];
    float w[4], acc[4][2];
    ld4(aself + 4 * (size_t)d, w);
    {
        unsigned int u = *(const unsigned int*)(xb + (size_t)d * 128 + lane * 2);
        float x0 = b2f((unsigned short)(u & 0xFFFF)), x1 = b2f((unsigned short)(u >> 16));
        #pragma unroll
        for (int h = 0; h < 4; ++h) { acc[h][0] = w[h] * x0; acc[h][1] = w[h] * x1; }
    }
    for (int p = beg; p < end; ++p) {
        int e = elist[p];
        int s = esrc[e];
        ld4(walpha + 4 * (size_t)e, w);
        unsigned int u = *(const unsigned int*)(xb + (size_t)s * 128 + lane * 2);
        float x0 = b2f((unsigned short)(u & 0xFFFF)), x1 = b2f((unsigned short)(u >> 16));
        #pragma unroll
        for (int h = 0; h < 4; ++h) { acc[h][0] += w[h] * x0; acc[h][1] += w[h] * x1; }
    }
    unsigned int* og = (unsigned int*)(aggb + (size_t)d * 512);
    #pragma unroll
    for (int h = 0; h < 4; ++h)
        og[h * 64 + lane] = (unsigned int)f2b(acc[h][0]) | ((unsigned int)f2b(acc[h][1]) << 16);
}

__global__ void agg1024_kernel(const unsigned short* __restrict__ xb, const float* __restrict__ walpha,
                               const float* __restrict__ aself,
                               const int* __restrict__ offsets, const int* __restrict__ elist,
                               const int* __restrict__ esrc, unsigned short* __restrict__ aggb)
{
    int d = blockIdx.x, t = threadIdx.x;
    int beg = offsets[d], end = offsets[d + 1];
    float w[4], acc[4][4];
    ld4(aself + 4 * (size_t)d, w);
    {
        ushort4 u = *(const ushort4*)(xb + (size_t)d * 1024 + t * 4);
        float xv[4] = { b2f(u.x), b2f(u.y), b2f(u.z), b2f(u.w) };
        #pragma unroll
        for (int h = 0; h < 4; ++h)
            #pragma unroll
            for (int j = 0; j < 4; ++j) acc[h][j] = w[h] * xv[j];
    }
    for (int p = beg; p < end; ++p) {
        int e = elist[p];
        int s = esrc[e];
        ld4(walpha + 4 * (size_t)e, w);
        ushort4 u = *(const ushort4*)(xb + (size_t)s * 1024 + t * 4);
        float xv[4] = { b2f(u.x), b2f(u.y), b2f(u.z), b2f(u.w) };
        #pragma unroll
        for (int h = 0; h < 4; ++h)
            #pragma unroll
            for (int j = 0; j < 4; ++j) acc[h][j] += w[h] * xv[j];
    }
    unsigned short* og = aggb + (size_t)d * 4096;
    #pragma unroll
    for (int h = 0; h < 4; ++h) {
        ushort4 u;
        u.x = f2b(acc[h][0]); u.y = f2b(acc[h][1]);
        u.z = f2b(acc[h][2]); u.w = f2b(acc[h][3]);
        *(ushort4*)(og + h * 1024 + t * 4) = u;
    }
}

// ==================== fused dual-phase bf16 MFMA GEMM + BN stats ====================
// LDS row stride 32 shorts; 16B chunk c of row r stored at chunk (c ^ ((r>>1)&3)).
#define SWZ(r, c) ((((c) ^ (((r) >> 1) & 3)) << 3))

template<int BM, int BN>
__global__ __launch_bounds__(256) void gemm2_kernel(
    const unsigned short* __restrict__ A1, int lda1, const unsigned short* __restrict__ W1, int K1,
    const unsigned short* __restrict__ A2, int lda2, const unsigned short* __restrict__ W2, int K2,
    int hs2, int cph2,
    unsigned short* __restrict__ C, int N,
    float* __restrict__ bnsum, float* __restrict__ bnsq)
{
    constexpr int WM = BM / 2, WN = BN / 2;
    constexpr int TM = WM / 16, TN = WN / 16;
    __shared__ __align__(16) unsigned short As[BM * 32];
    __shared__ __align__(16) unsigned short Bs[BN * 32];
    __shared__ float sbn[2 * BN];
    int tid = threadIdx.x;
    int n0 = blockIdx.x * BN, m0 = blockIdx.y * BM;
    int l = tid & 63, l16 = l & 15, kq = l >> 4;
    int wid = tid >> 6, wr = wid >> 1, wc = wid & 1;

    f32x4 acc[TM][TN];
    #pragma unroll
    for (int mi = 0; mi < TM; ++mi)
        #pragma unroll
        for (int ni = 0; ni < TN; ++ni) acc[mi][ni] = (f32x4){0.f, 0.f, 0.f, 0.f};

    #pragma unroll
    for (int ph = 0; ph < 2; ++ph) {
        const unsigned short* Ap = ph ? A2 + (size_t)m0 * lda2 + (cph2 ? (size_t)(n0 / cph2) * hs2 : 0)
                                      : A1 + (size_t)m0 * lda1;
        int lda = ph ? lda2 : lda1;
        const unsigned short* Wp = ph ? W2 + (size_t)n0 * K2 : W1 + (size_t)n0 * K1;
        int ldw = ph ? K2 : K1;
        int K = ph ? K2 : K1;
        for (int k0 = 0; k0 < K; k0 += 32) {
            for (int c = tid; c < BM * 4; c += 256) {
                int r = c >> 2, ch = c & 3;
                *(uint4*)&As[r * 32 + SWZ(r, ch)] = *(const uint4*)(Ap + (size_t)r * lda + k0 + (ch << 3));
            }
            for (int c = tid; c < BN * 4; c += 256) {
                int r = c >> 2, ch = c & 3;
                *(uint4*)&Bs[r * 32 + SWZ(r, ch)] = *(const uint4*)(Wp + (size_t)r * ldw + k0 + (ch << 3));
            }
            __syncthreads();
            short8 af[TM], bfr[TN];
            #pragma unroll
            for (int mi = 0; mi < TM; ++mi) {
                int r = wr * WM + mi * 16 + l16;
                af[mi] = *(const short8*)&As[r * 32 + SWZ(r, kq)];
            }
            #pragma unroll
            for (int ni = 0; ni < TN; ++ni) {
                int r = wc * WN + ni * 16 + l16;
                bfr[ni] = *(const short8*)&Bs[r * 32 + SWZ(r, kq)];
            }
            #pragma unroll
            for (int mi = 0; mi < TM; ++mi)
                #pragma unroll
                for (int ni = 0; ni < TN; ++ni)
                    acc[mi][ni] = __builtin_amdgcn_mfma_f32_16x16x32_bf16(
                        af[mi], bfr[ni], acc[mi][ni], 0, 0, 0);
            __syncthreads();
        }
    }

    if (tid < 2 * BN) sbn[tid] = 0.f;
    __syncthreads();

    #pragma unroll
    for (int ni = 0; ni < TN; ++ni) {
        int col = wc * WN + ni * 16 + l16;
        float s = 0.f, q = 0.f;
        #pragma unroll
        for (int mi = 0; mi < TM; ++mi) {
            int rowb = wr * WM + mi * 16 + (kq << 2);
            #pragma unroll
            for (int r = 0; r < 4; ++r) {
                float v = acc[mi][ni][r];
                C[(size_t)(m0 + rowb + r) * N + n0 + col] = f2b(v);
                s += v; q += v * v;
            }
        }
        atomicAdd(&sbn[col * 2 + 0], s);
        atomicAdd(&sbn[col * 2 + 1], q);
    }
    __syncthreads();
    if (tid < BN) {
        atomicAdd(&bnsum[n0 + tid], sbn[tid * 2 + 0]);
        atomicAdd(&bnsq[n0 + tid], sbn[tid * 2 + 1]);
    }
}

// ==================== BN finalize fused into apply + ELU ====================
__global__ void norm_elu_bb(const unsigned short* __restrict__ h,
                            const float* __restrict__ sum, const float* __restrict__ sq,
                            const float* __restrict__ gamma, const float* __restrict__ beta,
                            unsigned short* __restrict__ out, int N, float invM, long total)
{
    long i = ((long)blockIdx.x * 256 + threadIdx.x) * 4;
    if (i >= total) return;
    int c = (int)(i % N);
    float4 sm = *(const float4*)(sum + c);
    float4 qq = *(const float4*)(sq + c);
    float4 gm = *(const float4*)(gamma + c);
    float4 bt = *(const float4*)(beta + c);
    float mu0 = sm.x * invM, mu1 = sm.y * invM, mu2 = sm.z * invM, mu3 = sm.w * invM;
    float sc0 = gm.x * rsqrtf(qq.x * invM - mu0 * mu0 + BN_EPS);
    float sc1 = gm.y * rsqrtf(qq.y * invM - mu1 * mu1 + BN_EPS);
    float sc2 = gm.z * rsqrtf(qq.z * invM - mu2 * mu2 + BN_EPS);
    float sc3 = gm.w * rsqrtf(qq.w * invM - mu3 * mu3 + BN_EPS);
    float sh0 = bt.x - mu0 * sc0, sh1 = bt.y - mu1 * sc1;
    float sh2 = bt.z - mu2 * sc2, sh3 = bt.w - mu3 * sc3;
    ushort4 u = *(const ushort4*)(h + i);
    float v0 = b2f(u.x) * sc0 + sh0;
    float v1 = b2f(u.y) * sc1 + sh1;
    float v2 = b2f(u.z) * sc2 + sh2;
    float v3 = b2f(u.w) * sc3 + sh3;
    v0 = v0 > 0.f ? v0 : expm1f(v0);
    v1 = v1 > 0.f ? v1 : expm1f(v1);
    v2 = v2 > 0.f ? v2 : expm1f(v2);
    v3 = v3 > 0.f ? v3 : expm1f(v3);
    ushort4 o;
    o.x = f2b(v0); o.y = f2b(v1); o.z = f2b(v2); o.w = f2b(v3);
    *(ushort4*)(out + i) = o;
}

__global__ void norm_elu_bf(const unsigned short* __restrict__ h,
                            const float* __restrict__ sum, const float* __restrict__ sq,
                            const float* __restrict__ gamma, const float* __restrict__ beta,
                            float* __restrict__ out, int N, float invM, long total)
{
    long i = ((long)blockIdx.x * 256 + threadIdx.x) * 4;
    if (i >= total) return;
    int c = (int)(i % N);
    float4 sm = *(const float4*)(sum + c);
    float4 qq = *(const float4*)(sq + c);
    float4 gm = *(const float4*)(gamma + c);
    float4 bt = *(const float4*)(beta + c);
    float mu0 = sm.x * invM, mu1 = sm.y * invM, mu2 = sm.z * invM, mu3 = sm.w * invM;
    float sc0 = gm.x * rsqrtf(qq.x * invM - mu0 * mu0 + BN_EPS);
    float sc1 = gm.y * rsqrtf(qq.y * invM - mu1 * mu1 + BN_EPS);
    float sc2 = gm.z * rsqrtf(qq.z * invM - mu2 * mu2 + BN_EPS);
    float sc3 = gm.w * rsqrtf(qq.w * invM - mu3 * mu3 + BN_EPS);
    ushort4 u = *(const ushort4*)(h + i);
    float4 o;
    o.x = b2f(u.x) * sc0 + (bt.x - mu0 * sc0);
    o.y = b2f(u.y) * sc1 + (bt.y - mu1 * sc1);
    o.z = b2f(u.z) * sc2 + (bt.z - mu2 * sc2);
    o.w = b2f(u.w) * sc3 + (bt.w - mu3 * sc3);
    o.x = o.x > 0.f ? o.x : expm1f(o.x);
    o.y = o.y > 0.f ? o.y : expm1f(o.y);
    o.z = o.z > 0.f ? o.z : expm1f(o.z);
    o.w = o.w > 0.f ? o.w : expm1f(o.w);
    *(float4*)(out + i) = o;
}

// =====================================================================
extern "C" void kernel_launch(void* const* d_in, const int* in_sizes, int n_in,
                              void* d_out, int out_size, void* d_ws, size_t ws_size,
                              hipStream_t stream)
{
    const float* x = (const float*)d_in[0];
    auto P = [&](int layer, int slot) -> const float* {
        return (const float*)d_in[1 + (layer - 1) * 9 + slot];
    };
    const int* edge_src[3] = { (const int*)d_in[28], (const int*)d_in[30], (const int*)d_in[32] };
    const int* edge_dst[3] = { (const int*)d_in[29], (const int*)d_in[31], (const int*)d_in[33] };
    const int Es[3] = { E1, E2, E3 };

    // -------- workspace carve --------
    char* wsb = (char*)d_ws;
    size_t off = 0;
    auto alloc = [&](size_t bytes) -> void* {
        void* p = wsb + off;
        off = (off + bytes + 255) & ~(size_t)255;
        return p;
    };
    unsigned short* xb0   = (unsigned short*)alloc((size_t)N0 * 128 * 2);
    unsigned short* x1b   = (unsigned short*)alloc((size_t)S1 * 1024 * 2);
    unsigned short* x2b   = (unsigned short*)alloc((size_t)S2 * 1024 * 2);
    unsigned short* hb    = (unsigned short*)alloc((size_t)S1 * 1024 * 2);
    unsigned short* aggb  = (unsigned short*)alloc((size_t)S2 * 4096 * 2);
    unsigned short* wskipb[3] = {
        (unsigned short*)alloc(131072 * 2),
        (unsigned short*)alloc(1048576 * 2),
        (unsigned short*)alloc(262144 * 2) };
    unsigned short* wsrcb[3] = {
        (unsigned short*)alloc(131072 * 2),
        (unsigned short*)alloc(1048576 * 2),
        (unsigned short*)alloc(1048576 * 2) };
    float* vbuf[6];
    vbuf[0] = (float*)alloc(512 * 4);
    vbuf[1] = (float*)alloc(512 * 4);
    vbuf[2] = (float*)alloc(4096 * 4);
    vbuf[3] = (float*)alloc(4096 * 4);
    vbuf[4] = (float*)alloc(4096 * 4);
    vbuf[5] = (float*)alloc(4096 * 4);
    float* als     = (float*)alloc((size_t)N0 * 4 * 4);
    float* ald     = (float*)alloc((size_t)S1 * 4 * 4);
    float* aself   = (float*)alloc((size_t)S1 * 4 * 4);
    float* walpha  = (float*)alloc((size_t)E1 * 4 * 4);
    int*   offsets = (int*)alloc((size_t)(S1 + 1) * 4);
    int*   cursor  = (int*)alloc((size_t)S1 * 4);
    int*   elist   = (int*)alloc((size_t)E1 * 4);
    // contiguous zero region: counts x3 + bn stats (sum,sq) x3 layers
    int zn = S1 + S2 + S3 + 6 * 1024;
    int* zreg = (int*)alloc((size_t)zn * 4);
    int* counts[3] = { zreg, zreg + S1, zreg + S1 + S2 };
    float* bnsum[3] = { (float*)(zreg + S1 + S2 + S3),
                        (float*)(zreg + S1 + S2 + S3 + 2048),
                        (float*)(zreg + S1 + S2 + S3 + 4096) };
    float* bnsq[3]  = { bnsum[0] + 1024, bnsum[1] + 1024, bnsum[2] + 1024 };

    // -------- one-shot prep: folds + weight bf16 + zeroing --------
    PrepArgs pa;
    for (int L = 0; L < 3; ++L) {
        pa.att[2 * L]     = P(L + 1, 2); pa.wf[2 * L]     = P(L + 1, 0); pa.v[2 * L]     = vbuf[2 * L];
        pa.att[2 * L + 1] = P(L + 1, 3); pa.wf[2 * L + 1] = P(L + 1, 1); pa.v[2 * L + 1] = vbuf[2 * L + 1];
    }
    pa.csrc[0] = P(1, 5); pa.cdst[0] = wskipb[0];
    pa.csrc[1] = P(1, 0); pa.cdst[1] = wsrcb[0];
    pa.csrc[2] = P(2, 5); pa.cdst[2] = wskipb[1];
    pa.csrc[3] = P(2, 0); pa.cdst[3] = wsrcb[1];
    pa.csrc[4] = P(3, 5); pa.cdst[4] = wskipb[2];
    pa.csrc[5] = P(3, 0); pa.cdst[5] = wsrcb[2];
    pa.zptr = zreg; pa.zn4 = zn / 4;
    prep_kernel<<<167, 256, 0, stream>>>(pa);

    auto csr_and_agg = [&](int L, const unsigned short* xa, int size, int din)
    {
        const int* es = edge_src[L - 1];
        const int* ed = edge_dst[L - 1];
        int E = Es[L - 1];
        count_kernel<<<(E + 255) / 256, 256, 0, stream>>>(ed, E, counts[L - 1]);
        scan_kernel<<<1, 1024, 0, stream>>>(counts[L - 1], offsets, cursor, size);
        scatter_kernel<<<(E + 255) / 256, 256, 0, stream>>>(ed, E, cursor, elist);
        mdn_kernel<<<(size + 255) / 256, 256, 0, stream>>>(als, ald, offsets, elist, es,
                                                           size, aself, walpha);
        if (din == 128)
            agg128_kernel<<<size, 64, 0, stream>>>(xa, walpha, aself, offsets, elist, es, aggb);
        else
            agg1024_kernel<<<size, 256, 0, stream>>>(xa, walpha, aself, offsets, elist, es, aggb);
    };

    // ---------------- layer 1 ----------------
    al128f_kernel<<<2048, 256, 0, stream>>>(x, vbuf[0], vbuf[1], xb0, als, ald, N0, S1);
    csr_and_agg(1, xb0, S1, 128);
    gemm2_kernel<128, 128><<<dim3(1024 / 128, S1 / 128), 256, 0, stream>>>(
        xb0, 128, wskipb[0], 128,
        aggb, 512, wsrcb[0], 128, 128, 256,
        hb, 1024, bnsum[0], bnsq[0]);
    norm_elu_bb<<<(int)(((long)S1 * 1024 / 4 + 255) / 256), 256, 0, stream>>>(
        hb, bnsum[0], bnsq[0], P(1, 7), P(1, 8), x1b, 1024, 1.f / S1, (long)S1 * 1024);

    // ---------------- layer 2 ----------------
    al1024_kernel<<<512, 256, 0, stream>>>(x1b, vbuf[2], als, S1);
    al1024_kernel<<<64, 256, 0, stream>>>(x1b, vbuf[3], ald, S2);
    csr_and_agg(2, x1b, S2, 1024);
    gemm2_kernel<64, 64><<<dim3(1024 / 64, S2 / 64), 256, 0, stream>>>(
        x1b, 1024, wskipb[1], 1024,
        aggb, 4096, wsrcb[1], 1024, 1024, 256,
        hb, 1024, bnsum[1], bnsq[1]);
    norm_elu_bb<<<(int)(((long)S2 * 1024 / 4 + 255) / 256), 256, 0, stream>>>(
        hb, bnsum[1], bnsq[1], P(2, 7), P(2, 8), x2b, 1024, 1.f / S2, (long)S2 * 1024);

    // ---------------- layer 3 ----------------
    al1024_kernel<<<64, 256, 0, stream>>>(x2b, vbuf[4], als, S2);
    al1024_kernel<<<8, 256, 0, stream>>>(x2b, vbuf[5], ald, S3);
    csr_and_agg(3, x2b, S3, 1024);
    gemm2_kernel<64, 64><<<dim3(256 / 64, S3 / 64), 256, 0, stream>>>(
        x2b, 1024, wskipb[2], 1024,
        aggb, 4096, wsrcb[2], 4096, 0, 0,
        hb, 256, bnsum[2], bnsq[2]);
    norm_elu_bf<<<(int)(((long)S3 * 256 / 4 + 255) / 256), 256, 0, stream>>>(
        hb, bnsum[2], bnsq[2], P(3, 7), P(3, 8), (float*)d_out, 256, 1.f / S3, (long)S3 * 256);
}

// Round 8
// 678.175 us; speedup vs baseline: 2.8915x; 1.0641x over previous
//
#include <hip/hip_runtime.h>
#include <math.h>

// ---------------- problem constants (from reference) ----------------
constexpr int N0 = 262144, S1 = 32768, S2 = 4096, S3 = 512;
constexpr int E1 = 327680, E2 = 40960, E3 = 5120;
constexpr float NEG = 0.2f, BN_EPS = 1e-5f;

typedef __attribute__((ext_vector_type(8))) short short8;   // 8 bf16 (4 VGPRs)
typedef __attribute__((ext_vector_type(4))) float f32x4;    // MFMA acc

__device__ __forceinline__ float lrelu(float x) { return x > 0.f ? x : NEG * x; }

__device__ __forceinline__ unsigned short f2b(float f) {  // f32 -> bf16 RNE
    unsigned int u = __float_as_uint(f);
    return (unsigned short)((u + 0x7FFFu + ((u >> 16) & 1u)) >> 16);
}
__device__ __forceinline__ float b2f(unsigned short u) {
    return __uint_as_float(((unsigned int)u) << 16);
}
__device__ __forceinline__ void ld4(const float* __restrict__ p, float* o) {
    float4 v = *(const float4*)p;
    o[0] = v.x; o[1] = v.y; o[2] = v.z; o[3] = v.w;
}

// ==================== one-shot prep ====================
// blocks 0..67   : attention folds, 256 outputs/block
// blocks 68..123 : weight f32->bf16 convs, 65536 elems/block
// blocks 124..166: zero region (counts x3 + bn stats x6), int4 stores
struct PrepArgs {
    const float* att[6]; const float* wf[6]; float* v[6];
    const float* csrc[6]; unsigned short* cdst[6];
    int* zptr; int zn4;
};

__global__ void prep_kernel(PrepArgs a)
{
    int b = blockIdx.x, t = threadIdx.x;
    if (b < 68) {
        int f, cb;
        if (b < 2)       { f = 0; cb = b; }
        else if (b < 4)  { f = 1; cb = b - 2; }
        else if (b < 20) { f = 2; cb = b - 4; }
        else if (b < 36) { f = 3; cb = b - 20; }
        else if (b < 52) { f = 4; cb = b - 36; }
        else             { f = 5; cb = b - 52; }
        int din = (f < 2) ? 128 : 1024;
        int idx = cb * 256 + t;
        int h = idx / din, k = idx - h * din;
        const float* ar = a.att[f] + h * 256;
        const float* wr = a.wf[f] + (size_t)(h * 256) * din + k;
        float acc = 0.f;
        for (int j = 0; j < 256; ++j) acc += ar[j] * wr[(size_t)j * din];
        a.v[f][idx] = acc;
    } else if (b < 124) {
        int c = b - 68, j, ob;
        if (c < 2)       { j = 0; ob = c; }
        else if (c < 4)  { j = 1; ob = c - 2; }
        else if (c < 20) { j = 2; ob = c - 4; }
        else if (c < 36) { j = 3; ob = c - 20; }
        else if (c < 40) { j = 4; ob = c - 36; }
        else             { j = 5; ob = c - 40; }
        long base = (long)ob * 65536;
        if (j < 5) {
            const float* src = a.csrc[j];
            unsigned short* dst = a.cdst[j];
            for (int it = 0; it < 64; ++it) {
                long e = base + (long)(it * 256 + t) * 4;
                float4 v = *(const float4*)(src + e);
                ushort4 u;
                u.x = f2b(v.x); u.y = f2b(v.y); u.z = f2b(v.z); u.w = f2b(v.w);
                *(ushort4*)(dst + e) = u;
            }
        } else {  // w3 repack: wp[row*4096 + h*1024 + k] = 0.25*w[(h*256+row)*1024+k]
            const float* src = a.csrc[5];
            unsigned short* dst = a.cdst[5];
            for (int it = 0; it < 64; ++it) {
                long e = base + (long)(it * 256 + t) * 4;
                int row = (int)(e >> 12);
                int hk = (int)(e & 4095);
                int h = hk >> 10, k = hk & 1023;
                float4 v = *(const float4*)(src + ((size_t)(h * 256 + row) << 10) + k);
                ushort4 u;
                u.x = f2b(0.25f * v.x); u.y = f2b(0.25f * v.y);
                u.z = f2b(0.25f * v.z); u.w = f2b(0.25f * v.w);
                *(ushort4*)(dst + e) = u;
            }
        }
    } else {
        int i = (b - 124) * 256 + t;
        if (i < a.zn4) ((int4*)a.zptr)[i] = make_int4(0, 0, 0, 0);
    }
}

// ==================== CSR build for ALL layers (input-only) ====================
struct CsrArgs {
    const int* edst[3];
    int* counts[3]; int* offsets[3]; int* cursor[3]; int* elist[3];
    int sizes[3];
};

__global__ void count_all(CsrArgs a)
{
    int id = blockIdx.x * 256 + threadIdx.x;
    int L, e;
    if (id < E1)           { L = 0; e = id; }
    else if (id < E1 + E2) { L = 1; e = id - E1; }
    else if (id < E1 + E2 + E3) { L = 2; e = id - E1 - E2; }
    else return;
    atomicAdd(&a.counts[L][a.edst[L][e]], 1);
}

__global__ void scan_all(CsrArgs a)
{
    __shared__ int lds[1024];
    int L = blockIdx.x;
    int size = a.sizes[L];
    const int* counts = a.counts[L];
    int* offsets = a.offsets[L];
    int* cursor = a.cursor[L];
    int t = threadIdx.x;
    int chunk = (size + 1023) >> 10;
    int begin = t * chunk;
    int end = begin + chunk; if (end > size) end = size;
    if (begin > size) begin = size;
    int s = 0;
    if ((chunk & 3) == 0) {
        for (int i = begin; i < end; i += 4) {
            int4 v = *(const int4*)(counts + i);
            s += v.x + v.y + v.z + v.w;
        }
    } else {
        for (int i = begin; i < end; ++i) s += counts[i];
    }
    lds[t] = s;
    __syncthreads();
    for (int d = 1; d < 1024; d <<= 1) {
        int v = (t >= d) ? lds[t - d] : 0;
        __syncthreads();
        lds[t] += v;
        __syncthreads();
    }
    int base = (t > 0) ? lds[t - 1] : 0;
    for (int i = begin; i < end; ++i) {
        offsets[i] = base; cursor[i] = base;
        base += counts[i];
    }
    if (t == 1023) offsets[size] = lds[1023];
}

__global__ void scatter_all(CsrArgs a)
{
    int id = blockIdx.x * 256 + threadIdx.x;
    int L, e;
    if (id < E1)           { L = 0; e = id; }
    else if (id < E1 + E2) { L = 1; e = id - E1; }
    else if (id < E1 + E2 + E3) { L = 2; e = id - E1 - E2; }
    else return;
    int p = atomicAdd(&a.cursor[L][a.edst[L][e]], 1);
    a.elist[L][p] = e;
}

// ==================== L1: fused f32->bf16 conv + al_src + al_dst ====================
__global__ void al128f_kernel(const float* __restrict__ x, const float* __restrict__ vs,
                              const float* __restrict__ vd, unsigned short* __restrict__ xb,
                              float* __restrict__ als, float* __restrict__ ald, int n, int ndst)
{
    int lane = threadIdx.x & 63;
    int wave = (blockIdx.x * 256 + threadIdx.x) >> 6;
    int nw = (gridDim.x * 256) >> 6;
    int j32 = lane & 31, half = lane >> 5;
    float vsr[4][4], vdr[4][4];
    #pragma unroll
    for (int h = 0; h < 4; ++h) {
        ld4(vs + h * 128 + j32 * 4, vsr[h]);
        ld4(vd + h * 128 + j32 * 4, vdr[h]);
    }
    for (long node = (long)wave * 2 + half; node < n; node += (long)nw * 2) {
        float4 xv = *(const float4*)(x + node * 128 + j32 * 4);
        ushort4 u;
        u.x = f2b(xv.x); u.y = f2b(xv.y); u.z = f2b(xv.z); u.w = f2b(xv.w);
        *(ushort4*)(xb + node * 128 + j32 * 4) = u;
        float xf[4] = { xv.x, xv.y, xv.z, xv.w };
        float a[4], bv[4];
        bool isd = node < ndst;
        #pragma unroll
        for (int h = 0; h < 4; ++h)
            a[h] = xf[0]*vsr[h][0] + xf[1]*vsr[h][1] + xf[2]*vsr[h][2] + xf[3]*vsr[h][3];
        if (isd) {
            #pragma unroll
            for (int h = 0; h < 4; ++h)
                bv[h] = xf[0]*vdr[h][0] + xf[1]*vdr[h][1] + xf[2]*vdr[h][2] + xf[3]*vdr[h][3];
        }
        #pragma unroll
        for (int off = 16; off > 0; off >>= 1) {
            #pragma unroll
            for (int h = 0; h < 4; ++h) a[h] += __shfl_xor(a[h], off);
            if (isd)
                #pragma unroll
                for (int h = 0; h < 4; ++h) bv[h] += __shfl_xor(bv[h], off);
        }
        if (j32 == 0) {
            *(float4*)(als + node * 4) = make_float4(a[0], a[1], a[2], a[3]);
            if (isd) *(float4*)(ald + node * 4) = make_float4(bv[0], bv[1], bv[2], bv[3]);
        }
    }
}

// ==================== L2/L3: al[n,h]=dot(x[n],v[h]) ====================
__global__ void al1024_kernel(const unsigned short* __restrict__ xb, const float* __restrict__ v,
                              float* __restrict__ al, int n)
{
    int lane = threadIdx.x & 63;
    int wave = (blockIdx.x * 256 + threadIdx.x) >> 6;
    int nwaves = (gridDim.x * 256) >> 6;
    float vr[4][16];
    #pragma unroll
    for (int h = 0; h < 4; ++h)
        #pragma unroll
        for (int it = 0; it < 2; ++it) {
            ld4(v + h * 1024 + it * 512 + lane * 8,     &vr[h][it * 8]);
            ld4(v + h * 1024 + it * 512 + lane * 8 + 4, &vr[h][it * 8 + 4]);
        }
    for (long node = wave; node < n; node += nwaves) {
        const unsigned short* xr = xb + node * 1024;
        float a[4] = {0.f, 0.f, 0.f, 0.f};
        #pragma unroll
        for (int it = 0; it < 2; ++it) {
            short8 u = *(const short8*)(xr + it * 512 + lane * 8);
            #pragma unroll
            for (int j = 0; j < 8; ++j) {
                float xv = b2f((unsigned short)u[j]);
                #pragma unroll
                for (int h = 0; h < 4; ++h) a[h] += xv * vr[h][it * 8 + j];
            }
        }
        #pragma unroll
        for (int off = 32; off > 0; off >>= 1)
            #pragma unroll
            for (int h = 0; h < 4; ++h) a[h] += __shfl_xor(a[h], off);
        if (lane == 0) *(float4*)(al + node * 4) = make_float4(a[0], a[1], a[2], a[3]);
    }
}

// ==================== per-destination softmax stats + per-edge alpha ====================
__global__ void mdn_kernel(const float* __restrict__ als, const float* __restrict__ ald,
                           const int* __restrict__ offsets, const int* __restrict__ elist,
                           const int* __restrict__ esrc, int size,
                           float* __restrict__ aself, float* __restrict__ walpha)
{
    int d = blockIdx.x * 256 + threadIdx.x;
    if (d >= size) return;
    float ad[4], sl[4], m[4], q[4], dn[4];
    ld4(ald + 4 * (size_t)d, ad);
    ld4(als + 4 * (size_t)d, q);
    #pragma unroll
    for (int h = 0; h < 4; ++h) { sl[h] = lrelu(q[h] + ad[h]); m[h] = sl[h]; }
    int beg = offsets[d], end = offsets[d + 1];
    for (int p = beg; p < end; ++p) {
        int s = esrc[elist[p]];
        ld4(als + 4 * (size_t)s, q);
        #pragma unroll
        for (int h = 0; h < 4; ++h) m[h] = fmaxf(m[h], lrelu(q[h] + ad[h]));
    }
    #pragma unroll
    for (int h = 0; h < 4; ++h) dn[h] = expf(sl[h] - m[h]);
    for (int p = beg; p < end; ++p) {
        int s = esrc[elist[p]];
        ld4(als + 4 * (size_t)s, q);
        #pragma unroll
        for (int h = 0; h < 4; ++h) dn[h] += expf(lrelu(q[h] + ad[h]) - m[h]);
    }
    float r[4];
    #pragma unroll
    for (int h = 0; h < 4; ++h) {
        r[h] = 1.f / (dn[h] + 1e-16f);
        aself[4 * (size_t)d + h] = expf(sl[h] - m[h]) * r[h];
    }
    for (int p = beg; p < end; ++p) {
        int e = elist[p];
        int s = esrc[e];
        ld4(als + 4 * (size_t)s, q);
        float4 w;
        w.x = expf(lrelu(q[0] + ad[0]) - m[0]) * r[0];
        w.y = expf(lrelu(q[1] + ad[1]) - m[1]) * r[1];
        w.z = expf(lrelu(q[2] + ad[2]) - m[2]) * r[2];
        w.w = expf(lrelu(q[3] + ad[3]) - m[3]) * r[3];
        *(float4*)(walpha + 4 * (size_t)e) = w;
    }
}

// ==================== aggregation (precomputed alpha) ====================
__global__ void agg128_kernel(const unsigned short* __restrict__ xb, const float* __restrict__ walpha,
                              const float* __restrict__ aself,
                              const int* __restrict__ offsets, const int* __restrict__ elist,
                              const int* __restrict__ esrc, unsigned short* __restrict__ aggb)
{
    int d = blockIdx.x, lane = threadIdx.x;
    int beg = offsets[d], end = offsets[d + 1];
    float w[4], acc[4][2];
    ld4(aself + 4 * (size_t)d, w);
    {
        unsigned int u = *(const unsigned int*)(xb + (size_t)d * 128 + lane * 2);
        float x0 = b2f((unsigned short)(u & 0xFFFF)), x1 = b2f((unsigned short)(u >> 16));
        #pragma unroll
        for (int h = 0; h < 4; ++h) { acc[h][0] = w[h] * x0; acc[h][1] = w[h] * x1; }
    }
    for (int p = beg; p < end; ++p) {
        int e = elist[p];
        int s = esrc[e];
        ld4(walpha + 4 * (size_t)e, w);
        unsigned int u = *(const unsigned int*)(xb + (size_t)s * 128 + lane * 2);
        float x0 = b2f((unsigned short)(u & 0xFFFF)), x1 = b2f((unsigned short)(u >> 16));
        #pragma unroll
        for (int h = 0; h < 4; ++h) { acc[h][0] += w[h] * x0; acc[h][1] += w[h] * x1; }
    }
    unsigned int* og = (unsigned int*)(aggb + (size_t)d * 512);
    #pragma unroll
    for (int h = 0; h < 4; ++h)
        og[h * 64 + lane] = (unsigned int)f2b(acc[h][0]) | ((unsigned int)f2b(acc[h][1]) << 16);
}

__global__ void agg1024_kernel(const unsigned short* __restrict__ xb, const float* __restrict__ walpha,
                               const float* __restrict__ aself,
                               const int* __restrict__ offsets, const int* __restrict__ elist,
                               const int* __restrict__ esrc, unsigned short* __restrict__ aggb)
{
    int d = blockIdx.x, t = threadIdx.x;
    int beg = offsets[d], end = offsets[d + 1];
    float w[4], acc[4][4];
    ld4(aself + 4 * (size_t)d, w);
    {
        ushort4 u = *(const ushort4*)(xb + (size_t)d * 1024 + t * 4);
        float xv[4] = { b2f(u.x), b2f(u.y), b2f(u.z), b2f(u.w) };
        #pragma unroll
        for (int h = 0; h < 4; ++h)
            #pragma unroll
            for (int j = 0; j < 4; ++j) acc[h][j] = w[h] * xv[j];
    }
    for (int p = beg; p < end; ++p) {
        int e = elist[p];
        int s = esrc[e];
        ld4(walpha + 4 * (size_t)e, w);
        ushort4 u = *(const ushort4*)(xb + (size_t)s * 1024 + t * 4);
        float xv[4] = { b2f(u.x), b2f(u.y), b2f(u.z), b2f(u.w) };
        #pragma unroll
        for (int h = 0; h < 4; ++h)
            #pragma unroll
            for (int j = 0; j < 4; ++j) acc[h][j] += w[h] * xv[j];
    }
    unsigned short* og = aggb + (size_t)d * 4096;
    #pragma unroll
    for (int h = 0; h < 4; ++h) {
        ushort4 u;
        u.x = f2b(acc[h][0]); u.y = f2b(acc[h][1]);
        u.z = f2b(acc[h][2]); u.w = f2b(acc[h][3]);
        *(ushort4*)(og + h * 1024 + t * 4) = u;
    }
}

// ==================== fused dual-phase bf16 MFMA GEMM + BN stats (L1/L2) ====================
#define SWZ(r, c) ((((c) ^ (((r) >> 1) & 3)) << 3))

template<int BM, int BN>
__global__ __launch_bounds__(256) void gemm2_kernel(
    const unsigned short* __restrict__ A1, int lda1, const unsigned short* __restrict__ W1, int K1,
    const unsigned short* __restrict__ A2, int lda2, const unsigned short* __restrict__ W2, int K2,
    int hs2, int cph2,
    unsigned short* __restrict__ C, int N,
    float* __restrict__ bnsum, float* __restrict__ bnsq)
{
    constexpr int WM = BM / 2, WN = BN / 2;
    constexpr int TM = WM / 16, TN = WN / 16;
    __shared__ __align__(16) unsigned short As[BM * 32];
    __shared__ __align__(16) unsigned short Bs[BN * 32];
    __shared__ float sbn[2 * BN];
    int tid = threadIdx.x;
    int n0 = blockIdx.x * BN, m0 = blockIdx.y * BM;
    int l = tid & 63, l16 = l & 15, kq = l >> 4;
    int wid = tid >> 6, wr = wid >> 1, wc = wid & 1;

    f32x4 acc[TM][TN];
    #pragma unroll
    for (int mi = 0; mi < TM; ++mi)
        #pragma unroll
        for (int ni = 0; ni < TN; ++ni) acc[mi][ni] = (f32x4){0.f, 0.f, 0.f, 0.f};

    #pragma unroll
    for (int ph = 0; ph < 2; ++ph) {
        const unsigned short* Ap = ph ? A2 + (size_t)m0 * lda2 + (cph2 ? (size_t)(n0 / cph2) * hs2 : 0)
                                      : A1 + (size_t)m0 * lda1;
        int lda = ph ? lda2 : lda1;
        const unsigned short* Wp = ph ? W2 + (size_t)n0 * K2 : W1 + (size_t)n0 * K1;
        int ldw = ph ? K2 : K1;
        int K = ph ? K2 : K1;
        for (int k0 = 0; k0 < K; k0 += 32) {
            for (int c = tid; c < BM * 4; c += 256) {
                int r = c >> 2, ch = c & 3;
                *(uint4*)&As[r * 32 + SWZ(r, ch)] = *(const uint4*)(Ap + (size_t)r * lda + k0 + (ch << 3));
            }
            for (int c = tid; c < BN * 4; c += 256) {
                int r = c >> 2, ch = c & 3;
                *(uint4*)&Bs[r * 32 + SWZ(r, ch)] = *(const uint4*)(Wp + (size_t)r * ldw + k0 + (ch << 3));
            }
            __syncthreads();
            short8 af[TM], bfr[TN];
            #pragma unroll
            for (int mi = 0; mi < TM; ++mi) {
                int r = wr * WM + mi * 16 + l16;
                af[mi] = *(const short8*)&As[r * 32 + SWZ(r, kq)];
            }
            #pragma unroll
            for (int ni = 0; ni < TN; ++ni) {
                int r = wc * WN + ni * 16 + l16;
                bfr[ni] = *(const short8*)&Bs[r * 32 + SWZ(r, kq)];
            }
            #pragma unroll
            for (int mi = 0; mi < TM; ++mi)
                #pragma unroll
                for (int ni = 0; ni < TN; ++ni)
                    acc[mi][ni] = __builtin_amdgcn_mfma_f32_16x16x32_bf16(
                        af[mi], bfr[ni], acc[mi][ni], 0, 0, 0);
            __syncthreads();
        }
    }

    if (tid < 2 * BN) sbn[tid] = 0.f;
    __syncthreads();

    #pragma unroll
    for (int ni = 0; ni < TN; ++ni) {
        int col = wc * WN + ni * 16 + l16;
        float s = 0.f, q = 0.f;
        #pragma unroll
        for (int mi = 0; mi < TM; ++mi) {
            int rowb = wr * WM + mi * 16 + (kq << 2);
            #pragma unroll
            for (int r = 0; r < 4; ++r) {
                float v = acc[mi][ni][r];
                C[(size_t)(m0 + rowb + r) * N + n0 + col] = f2b(v);
                s += v; q += v * v;
            }
        }
        atomicAdd(&sbn[col * 2 + 0], s);
        atomicAdd(&sbn[col * 2 + 1], q);
    }
    __syncthreads();
    if (tid < BN) {
        atomicAdd(&bnsum[n0 + tid], sbn[tid * 2 + 0]);
        atomicAdd(&bnsq[n0 + tid], sbn[tid * 2 + 1]);
    }
}

// ==================== L3: split-K GEMM -> Cpart[z][512][256] (deterministic) ====================
// z<2: skip phase, K-slice [z*512, z*512+512) of K1=1024
// z>=2: GAT phase, K-slice [(z-2)*512, ...) of K2=4096
__global__ __launch_bounds__(256) void gemm3_splitk(
    const unsigned short* __restrict__ A1, const unsigned short* __restrict__ W1,
    const unsigned short* __restrict__ A2, const unsigned short* __restrict__ W2,
    float* __restrict__ Cpart)
{
    constexpr int BM = 64, BN = 64, WM = 32, WN = 32, TM = 2, TN = 2;
    __shared__ __align__(16) unsigned short As[BM * 32];
    __shared__ __align__(16) unsigned short Bs[BN * 32];
    int tid = threadIdx.x;
    int n0 = blockIdx.x * BN, m0 = blockIdx.y * BM;
    int z = blockIdx.z;
    int ph = (z >= 2);
    int ks = ph ? (z - 2) * 512 : z * 512;
    const unsigned short* Ap = ph ? A2 + (size_t)m0 * 4096 : A1 + (size_t)m0 * 1024;
    const unsigned short* Wp = ph ? W2 + (size_t)n0 * 4096 : W1 + (size_t)n0 * 1024;
    int lda = ph ? 4096 : 1024;
    int l = tid & 63, l16 = l & 15, kq = l >> 4;
    int wid = tid >> 6, wr = wid >> 1, wc = wid & 1;

    f32x4 acc[TM][TN];
    #pragma unroll
    for (int mi = 0; mi < TM; ++mi)
        #pragma unroll
        for (int ni = 0; ni < TN; ++ni) acc[mi][ni] = (f32x4){0.f, 0.f, 0.f, 0.f};

    for (int k0 = ks; k0 < ks + 512; k0 += 32) {
        for (int c = tid; c < BM * 4; c += 256) {
            int r = c >> 2, ch = c & 3;
            *(uint4*)&As[r * 32 + SWZ(r, ch)] = *(const uint4*)(Ap + (size_t)r * lda + k0 + (ch << 3));
        }
        for (int c = tid; c < BN * 4; c += 256) {
            int r = c >> 2, ch = c & 3;
            *(uint4*)&Bs[r * 32 + SWZ(r, ch)] = *(const uint4*)(Wp + (size_t)r * lda + k0 + (ch << 3));
        }
        __syncthreads();
        short8 af[TM], bfr[TN];
        #pragma unroll
        for (int mi = 0; mi < TM; ++mi) {
            int r = wr * WM + mi * 16 + l16;
            af[mi] = *(const short8*)&As[r * 32 + SWZ(r, kq)];
        }
        #pragma unroll
        for (int ni = 0; ni < TN; ++ni) {
            int r = wc * WN + ni * 16 + l16;
            bfr[ni] = *(const short8*)&Bs[r * 32 + SWZ(r, kq)];
        }
        #pragma unroll
        for (int mi = 0; mi < TM; ++mi)
            #pragma unroll
            for (int ni = 0; ni < TN; ++ni)
                acc[mi][ni] = __builtin_amdgcn_mfma_f32_16x16x32_bf16(
                    af[mi], bfr[ni], acc[mi][ni], 0, 0, 0);
        __syncthreads();
    }

    float* Cz = Cpart + (size_t)z * S3 * 256;
    #pragma unroll
    for (int ni = 0; ni < TN; ++ni) {
        int col = wc * WN + ni * 16 + l16;
        #pragma unroll
        for (int mi = 0; mi < TM; ++mi) {
            int rowb = wr * WM + mi * 16 + (kq << 2);
            #pragma unroll
            for (int r = 0; r < 4; ++r)
                Cz[(size_t)(m0 + rowb + r) * 256 + n0 + col] = acc[mi][ni][r];
        }
    }
}

// reduce Cpart over z -> hb32, accumulate BN column stats
__global__ void bnstat3_kernel(const float* __restrict__ Cpart, float* __restrict__ hb32,
                               float* __restrict__ bnsum, float* __restrict__ bnsq)
{
    int c = threadIdx.x;             // column 0..255
    int r0 = blockIdx.x * 64;        // 8 blocks x 64 rows
    float s = 0.f, q = 0.f;
    for (int r = r0; r < r0 + 64; ++r) {
        float v = 0.f;
        #pragma unroll
        for (int z = 0; z < 10; ++z)
            v += Cpart[((size_t)z * S3 + r) * 256 + c];
        hb32[(size_t)r * 256 + c] = v;
        s += v; q += v * v;
    }
    atomicAdd(&bnsum[c], s);
    atomicAdd(&bnsq[c], q);
}

// ==================== BN finalize fused into apply + ELU ====================
__global__ void norm_elu_bb(const unsigned short* __restrict__ h,
                            const float* __restrict__ sum, const float* __restrict__ sq,
                            const float* __restrict__ gamma, const float* __restrict__ beta,
                            unsigned short* __restrict__ out, int N, float invM, long total)
{
    long i = ((long)blockIdx.x * 256 + threadIdx.x) * 4;
    if (i >= total) return;
    int c = (int)(i % N);
    float4 sm = *(const float4*)(sum + c);
    float4 qq = *(const float4*)(sq + c);
    float4 gm = *(const float4*)(gamma + c);
    float4 bt = *(const float4*)(beta + c);
    float mu0 = sm.x * invM, mu1 = sm.y * invM, mu2 = sm.z * invM, mu3 = sm.w * invM;
    float sc0 = gm.x * rsqrtf(qq.x * invM - mu0 * mu0 + BN_EPS);
    float sc1 = gm.y * rsqrtf(qq.y * invM - mu1 * mu1 + BN_EPS);
    float sc2 = gm.z * rsqrtf(qq.z * invM - mu2 * mu2 + BN_EPS);
    float sc3 = gm.w * rsqrtf(qq.w * invM - mu3 * mu3 + BN_EPS);
    float sh0 = bt.x - mu0 * sc0, sh1 = bt.y - mu1 * sc1;
    float sh2 = bt.z - mu2 * sc2, sh3 = bt.w - mu3 * sc3;
    ushort4 u = *(const ushort4*)(h + i);
    float v0 = b2f(u.x) * sc0 + sh0;
    float v1 = b2f(u.y) * sc1 + sh1;
    float v2 = b2f(u.z) * sc2 + sh2;
    float v3 = b2f(u.w) * sc3 + sh3;
    v0 = v0 > 0.f ? v0 : expm1f(v0);
    v1 = v1 > 0.f ? v1 : expm1f(v1);
    v2 = v2 > 0.f ? v2 : expm1f(v2);
    v3 = v3 > 0.f ? v3 : expm1f(v3);
    ushort4 o;
    o.x = f2b(v0); o.y = f2b(v1); o.z = f2b(v2); o.w = f2b(v3);
    *(ushort4*)(out + i) = o;
}

__global__ void norm_elu_ff(const float* __restrict__ h,
                            const float* __restrict__ sum, const float* __restrict__ sq,
                            const float* __restrict__ gamma, const float* __restrict__ beta,
                            float* __restrict__ out, int N, float invM, long total)
{
    long i = ((long)blockIdx.x * 256 + threadIdx.x) * 4;
    if (i >= total) return;
    int c = (int)(i % N);
    float4 sm = *(const float4*)(sum + c);
    float4 qq = *(const float4*)(sq + c);
    float4 gm = *(const float4*)(gamma + c);
    float4 bt = *(const float4*)(beta + c);
    float mu0 = sm.x * invM, mu1 = sm.y * invM, mu2 = sm.z * invM, mu3 = sm.w * invM;
    float sc0 = gm.x * rsqrtf(qq.x * invM - mu0 * mu0 + BN_EPS);
    float sc1 = gm.y * rsqrtf(qq.y * invM - mu1 * mu1 + BN_EPS);
    float sc2 = gm.z * rsqrtf(qq.z * invM - mu2 * mu2 + BN_EPS);
    float sc3 = gm.w * rsqrtf(qq.w * invM - mu3 * mu3 + BN_EPS);
    float4 hv = *(const float4*)(h + i);
    float4 o;
    o.x = hv.x * sc0 + (bt.x - mu0 * sc0);
    o.y = hv.y * sc1 + (bt.y - mu1 * sc1);
    o.z = hv.z * sc2 + (bt.z - mu2 * sc2);
    o.w = hv.w * sc3 + (bt.w - mu3 * sc3);
    o.x = o.x > 0.f ? o.x : expm1f(o.x);
    o.y = o.y > 0.f ? o.y : expm1f(o.y);
    o.z = o.z > 0.f ? o.z : expm1f(o.z);
    o.w = o.w > 0.f ? o.w : expm1f(o.w);
    *(float4*)(out + i) = o;
}

// =====================================================================
extern "C" void kernel_launch(void* const* d_in, const int* in_sizes, int n_in,
                              void* d_out, int out_size, void* d_ws, size_t ws_size,
                              hipStream_t stream)
{
    const float* x = (const float*)d_in[0];
    auto P = [&](int layer, int slot) -> const float* {
        return (const float*)d_in[1 + (layer - 1) * 9 + slot];
    };
    const int* edge_src[3] = { (const int*)d_in[28], (const int*)d_in[30], (const int*)d_in[32] };
    const int* edge_dst[3] = { (const int*)d_in[29], (const int*)d_in[31], (const int*)d_in[33] };

    // -------- workspace carve --------
    char* wsb = (char*)d_ws;
    size_t off = 0;
    auto alloc = [&](size_t bytes) -> void* {
        void* p = wsb + off;
        off = (off + bytes + 255) & ~(size_t)255;
        return p;
    };
    unsigned short* xb0   = (unsigned short*)alloc((size_t)N0 * 128 * 2);
    unsigned short* x1b   = (unsigned short*)alloc((size_t)S1 * 1024 * 2);
    unsigned short* x2b   = (unsigned short*)alloc((size_t)S2 * 1024 * 2);
    unsigned short* hb    = (unsigned short*)alloc((size_t)S1 * 1024 * 2);
    unsigned short* aggb  = (unsigned short*)alloc((size_t)S2 * 4096 * 2);
    unsigned short* wskipb[3] = {
        (unsigned short*)alloc(131072 * 2),
        (unsigned short*)alloc(1048576 * 2),
        (unsigned short*)alloc(262144 * 2) };
    unsigned short* wsrcb[3] = {
        (unsigned short*)alloc(131072 * 2),
        (unsigned short*)alloc(1048576 * 2),
        (unsigned short*)alloc(1048576 * 2) };
    float* vbuf[6];
    vbuf[0] = (float*)alloc(512 * 4);
    vbuf[1] = (float*)alloc(512 * 4);
    vbuf[2] = (float*)alloc(4096 * 4);
    vbuf[3] = (float*)alloc(4096 * 4);
    vbuf[4] = (float*)alloc(4096 * 4);
    vbuf[5] = (float*)alloc(4096 * 4);
    float* als     = (float*)alloc((size_t)N0 * 4 * 4);
    float* ald     = (float*)alloc((size_t)S1 * 4 * 4);
    float* aself   = (float*)alloc((size_t)S1 * 4 * 4);
    float* walpha  = (float*)alloc((size_t)E1 * 4 * 4);
    float* Cpart   = (float*)alloc((size_t)10 * S3 * 256 * 4);   // 5.2 MB
    float* hb32    = (float*)alloc((size_t)S3 * 256 * 4);        // 0.5 MB
    int* offsets3[3] = { (int*)alloc((S1 + 1) * 4), (int*)alloc((S2 + 1) * 4), (int*)alloc((S3 + 1) * 4) };
    int* cursor3 [3] = { (int*)alloc(S1 * 4), (int*)alloc(S2 * 4), (int*)alloc(S3 * 4) };
    int* elist3  [3] = { (int*)alloc(E1 * 4), (int*)alloc(E2 * 4), (int*)alloc(E3 * 4) };
    // contiguous zero region: counts x3 + bn stats (sum,sq) x3 layers
    int zn = S1 + S2 + S3 + 6 * 1024;
    int* zreg = (int*)alloc((size_t)zn * 4);
    int* counts[3] = { zreg, zreg + S1, zreg + S1 + S2 };
    float* bnsum[3] = { (float*)(zreg + S1 + S2 + S3),
                        (float*)(zreg + S1 + S2 + S3 + 2048),
                        (float*)(zreg + S1 + S2 + S3 + 4096) };
    float* bnsq[3]  = { bnsum[0] + 1024, bnsum[1] + 1024, bnsum[2] + 1024 };

    // -------- one-shot prep: folds + weight bf16 + zeroing --------
    PrepArgs pa;
    for (int L = 0; L < 3; ++L) {
        pa.att[2 * L]     = P(L + 1, 2); pa.wf[2 * L]     = P(L + 1, 0); pa.v[2 * L]     = vbuf[2 * L];
        pa.att[2 * L + 1] = P(L + 1, 3); pa.wf[2 * L + 1] = P(L + 1, 1); pa.v[2 * L + 1] = vbuf[2 * L + 1];
    }
    pa.csrc[0] = P(1, 5); pa.cdst[0] = wskipb[0];
    pa.csrc[1] = P(1, 0); pa.cdst[1] = wsrcb[0];
    pa.csrc[2] = P(2, 5); pa.cdst[2] = wskipb[1];
    pa.csrc[3] = P(2, 0); pa.cdst[3] = wsrcb[1];
    pa.csrc[4] = P(3, 5); pa.cdst[4] = wskipb[2];
    pa.csrc[5] = P(3, 0); pa.cdst[5] = wsrcb[2];
    pa.zptr = zreg; pa.zn4 = zn / 4;
    prep_kernel<<<167, 256, 0, stream>>>(pa);

    // -------- CSR build for all layers (input-only, once) --------
    CsrArgs ca;
    for (int L = 0; L < 3; ++L) {
        ca.edst[L] = edge_dst[L];
        ca.counts[L] = counts[L]; ca.offsets[L] = offsets3[L];
        ca.cursor[L] = cursor3[L]; ca.elist[L] = elist3[L];
    }
    ca.sizes[0] = S1; ca.sizes[1] = S2; ca.sizes[2] = S3;
    count_all<<<(E1 + E2 + E3) / 256, 256, 0, stream>>>(ca);
    scan_all<<<3, 1024, 0, stream>>>(ca);
    scatter_all<<<(E1 + E2 + E3) / 256, 256, 0, stream>>>(ca);

    // ---------------- layer 1 ----------------
    al128f_kernel<<<2048, 256, 0, stream>>>(x, vbuf[0], vbuf[1], xb0, als, ald, N0, S1);
    mdn_kernel<<<(S1 + 255) / 256, 256, 0, stream>>>(als, ald, offsets3[0], elist3[0], edge_src[0],
                                                     S1, aself, walpha);
    agg128_kernel<<<S1, 64, 0, stream>>>(xb0, walpha, aself, offsets3[0], elist3[0], edge_src[0], aggb);
    gemm2_kernel<128, 128><<<dim3(1024 / 128, S1 / 128), 256, 0, stream>>>(
        xb0, 128, wskipb[0], 128,
        aggb, 512, wsrcb[0], 128, 128, 256,
        hb, 1024, bnsum[0], bnsq[0]);
    norm_elu_bb<<<(int)(((long)S1 * 1024 / 4 + 255) / 256), 256, 0, stream>>>(
        hb, bnsum[0], bnsq[0], P(1, 7), P(1, 8), x1b, 1024, 1.f / S1, (long)S1 * 1024);

    // ---------------- layer 2 ----------------
    al1024_kernel<<<512, 256, 0, stream>>>(x1b, vbuf[2], als, S1);
    al1024_kernel<<<64, 256, 0, stream>>>(x1b, vbuf[3], ald, S2);
    mdn_kernel<<<(S2 + 255) / 256, 256, 0, stream>>>(als, ald, offsets3[1], elist3[1], edge_src[1],
                                                     S2, aself, walpha);
    agg1024_kernel<<<S2, 256, 0, stream>>>(x1b, walpha, aself, offsets3[1], elist3[1], edge_src[1], aggb);
    gemm2_kernel<64, 64><<<dim3(1024 / 64, S2 / 64), 256, 0, stream>>>(
        x1b, 1024, wskipb[1], 1024,
        aggb, 4096, wsrcb[1], 1024, 1024, 256,
        hb, 1024, bnsum[1], bnsq[1]);
    norm_elu_bb<<<(int)(((long)S2 * 1024 / 4 + 255) / 256), 256, 0, stream>>>(
        hb, bnsum[1], bnsq[1], P(2, 7), P(2, 8), x2b, 1024, 1.f / S2, (long)S2 * 1024);

    // ---------------- layer 3 ----------------
    al1024_kernel<<<64, 256, 0, stream>>>(x2b, vbuf[4], als, S2);
    al1024_kernel<<<8, 256, 0, stream>>>(x2b, vbuf[5], ald, S3);
    mdn_kernel<<<(S3 + 255) / 256, 256, 0, stream>>>(als, ald, offsets3[2], elist3[2], edge_src[2],
                                                     S3, aself, walpha);
    agg1024_kernel<<<S3, 256, 0, stream>>>(x2b, walpha, aself, offsets3[2], elist3[2], edge_src[2], aggb);
    gemm3_splitk<<<dim3(256 / 64, S3 / 64, 10), 256, 0, stream>>>(
        x2b, wskipb[2], aggb, wsrcb[2], Cpart);
    bnstat3_kernel<<<8, 256, 0, stream>>>(Cpart, hb32, bnsum[2], bnsq[2]);
    norm_elu_ff<<<(int)(((long)S3 * 256 / 4 + 255) / 256), 256, 0, stream>>>(
        hb32, bnsum[2], bnsq[2], P(3, 7), P(3, 8), (float*)d_out, 256, 1.f / S3, (long)S3 * 256);
}

// Round 9
// 539.553 us; speedup vs baseline: 3.6344x; 1.2569x over previous
//
#include <hip/hip_runtime.h>
#include <math.h>

// ---------------- problem constants (from reference) ----------------
constexpr int N0 = 262144, S1 = 32768, S2 = 4096, S3 = 512;
constexpr int E1 = 327680, E2 = 40960, E3 = 5120;
constexpr float NEG = 0.2f, BN_EPS = 1e-5f;

typedef __attribute__((ext_vector_type(8))) short short8;   // 8 bf16 (4 VGPRs)
typedef __attribute__((ext_vector_type(4))) float f32x4;    // MFMA acc

__device__ __forceinline__ float lrelu(float x) { return x > 0.f ? x : NEG * x; }

__device__ __forceinline__ unsigned short f2b(float f) {  // f32 -> bf16 RNE
    unsigned int u = __float_as_uint(f);
    return (unsigned short)((u + 0x7FFFu + ((u >> 16) & 1u)) >> 16);
}
__device__ __forceinline__ float b2f(unsigned short u) {
    return __uint_as_float(((unsigned int)u) << 16);
}
__device__ __forceinline__ void ld4(const float* __restrict__ p, float* o) {
    float4 v = *(const float4*)p;
    o[0] = v.x; o[1] = v.y; o[2] = v.z; o[3] = v.w;
}

// async global->LDS, 16B per lane; LDS dest = wave-uniform base + lane*16
__device__ __forceinline__ void gload_lds16(const unsigned short* g, unsigned short* l) {
    __builtin_amdgcn_global_load_lds(
        (const __attribute__((address_space(1))) unsigned int*)g,
        (__attribute__((address_space(3))) unsigned int*)l, 16, 0, 0);
}

// ==================== one-shot prep ====================
struct PrepArgs {
    const float* att[6]; const float* wf[6]; float* v[6];
    const float* csrc[6]; unsigned short* cdst[6];
    int* zptr; int zn4;
};

__global__ void prep_kernel(PrepArgs a)
{
    int b = blockIdx.x, t = threadIdx.x;
    if (b < 68) {
        int f, cb;
        if (b < 2)       { f = 0; cb = b; }
        else if (b < 4)  { f = 1; cb = b - 2; }
        else if (b < 20) { f = 2; cb = b - 4; }
        else if (b < 36) { f = 3; cb = b - 20; }
        else if (b < 52) { f = 4; cb = b - 36; }
        else             { f = 5; cb = b - 52; }
        int din = (f < 2) ? 128 : 1024;
        int idx = cb * 256 + t;
        int h = idx / din, k = idx - h * din;
        const float* ar = a.att[f] + h * 256;
        const float* wr = a.wf[f] + (size_t)(h * 256) * din + k;
        float acc = 0.f;
        for (int j = 0; j < 256; ++j) acc += ar[j] * wr[(size_t)j * din];
        a.v[f][idx] = acc;
    } else if (b < 124) {
        int c = b - 68, j, ob;
        if (c < 2)       { j = 0; ob = c; }
        else if (c < 4)  { j = 1; ob = c - 2; }
        else if (c < 20) { j = 2; ob = c - 4; }
        else if (c < 36) { j = 3; ob = c - 20; }
        else if (c < 40) { j = 4; ob = c - 36; }
        else             { j = 5; ob = c - 40; }
        long base = (long)ob * 65536;
        if (j < 5) {
            const float* src = a.csrc[j];
            unsigned short* dst = a.cdst[j];
            for (int it = 0; it < 64; ++it) {
                long e = base + (long)(it * 256 + t) * 4;
                float4 v = *(const float4*)(src + e);
                ushort4 u;
                u.x = f2b(v.x); u.y = f2b(v.y); u.z = f2b(v.z); u.w = f2b(v.w);
                *(ushort4*)(dst + e) = u;
            }
        } else {  // w3 repack: wp[row*4096 + h*1024 + k] = 0.25*w[(h*256+row)*1024+k]
            const float* src = a.csrc[5];
            unsigned short* dst = a.cdst[5];
            for (int it = 0; it < 64; ++it) {
                long e = base + (long)(it * 256 + t) * 4;
                int row = (int)(e >> 12);
                int hk = (int)(e & 4095);
                int h = hk >> 10, k = hk & 1023;
                float4 v = *(const float4*)(src + ((size_t)(h * 256 + row) << 10) + k);
                ushort4 u;
                u.x = f2b(0.25f * v.x); u.y = f2b(0.25f * v.y);
                u.z = f2b(0.25f * v.z); u.w = f2b(0.25f * v.w);
                *(ushort4*)(dst + e) = u;
            }
        }
    } else {
        int i = (b - 124) * 256 + t;
        if (i < a.zn4) ((int4*)a.zptr)[i] = make_int4(0, 0, 0, 0);
    }
}

// ==================== CSR build for ALL layers (input-only) ====================
struct CsrArgs {
    const int* edst[3];
    int* counts[3]; int* offsets[3]; int* cursor[3]; int* elist[3];
    int sizes[3];
};

__global__ void count_all(CsrArgs a)
{
    int id = blockIdx.x * 256 + threadIdx.x;
    int L, e;
    if (id < E1)           { L = 0; e = id; }
    else if (id < E1 + E2) { L = 1; e = id - E1; }
    else if (id < E1 + E2 + E3) { L = 2; e = id - E1 - E2; }
    else return;
    atomicAdd(&a.counts[L][a.edst[L][e]], 1);
}

__global__ void scan_all(CsrArgs a)
{
    __shared__ int lds[1024];
    int L = blockIdx.x;
    int size = a.sizes[L];
    const int* counts = a.counts[L];
    int* offsets = a.offsets[L];
    int* cursor = a.cursor[L];
    int t = threadIdx.x;
    int chunk = (size + 1023) >> 10;
    int begin = t * chunk;
    int end = begin + chunk; if (end > size) end = size;
    if (begin > size) begin = size;
    int s = 0;
    if ((chunk & 3) == 0) {
        for (int i = begin; i < end; i += 4) {
            int4 v = *(const int4*)(counts + i);
            s += v.x + v.y + v.z + v.w;
        }
    } else {
        for (int i = begin; i < end; ++i) s += counts[i];
    }
    lds[t] = s;
    __syncthreads();
    for (int d = 1; d < 1024; d <<= 1) {
        int v = (t >= d) ? lds[t - d] : 0;
        __syncthreads();
        lds[t] += v;
        __syncthreads();
    }
    int base = (t > 0) ? lds[t - 1] : 0;
    for (int i = begin; i < end; ++i) {
        offsets[i] = base; cursor[i] = base;
        base += counts[i];
    }
    if (t == 1023) offsets[size] = lds[1023];
}

__global__ void scatter_all(CsrArgs a)
{
    int id = blockIdx.x * 256 + threadIdx.x;
    int L, e;
    if (id < E1)           { L = 0; e = id; }
    else if (id < E1 + E2) { L = 1; e = id - E1; }
    else if (id < E1 + E2 + E3) { L = 2; e = id - E1 - E2; }
    else return;
    int p = atomicAdd(&a.cursor[L][a.edst[L][e]], 1);
    a.elist[L][p] = e;
}

// ==================== L1: fused f32->bf16 conv + al_src + al_dst ====================
__global__ void al128f_kernel(const float* __restrict__ x, const float* __restrict__ vs,
                              const float* __restrict__ vd, unsigned short* __restrict__ xb,
                              float* __restrict__ als, float* __restrict__ ald, int n, int ndst)
{
    int lane = threadIdx.x & 63;
    int wave = (blockIdx.x * 256 + threadIdx.x) >> 6;
    int nw = (gridDim.x * 256) >> 6;
    int j32 = lane & 31, half = lane >> 5;
    float vsr[4][4], vdr[4][4];
    #pragma unroll
    for (int h = 0; h < 4; ++h) {
        ld4(vs + h * 128 + j32 * 4, vsr[h]);
        ld4(vd + h * 128 + j32 * 4, vdr[h]);
    }
    for (long node = (long)wave * 2 + half; node < n; node += (long)nw * 2) {
        float4 xv = *(const float4*)(x + node * 128 + j32 * 4);
        ushort4 u;
        u.x = f2b(xv.x); u.y = f2b(xv.y); u.z = f2b(xv.z); u.w = f2b(xv.w);
        *(ushort4*)(xb + node * 128 + j32 * 4) = u;
        float xf[4] = { xv.x, xv.y, xv.z, xv.w };
        float a[4], bv[4];
        bool isd = node < ndst;
        #pragma unroll
        for (int h = 0; h < 4; ++h)
            a[h] = xf[0]*vsr[h][0] + xf[1]*vsr[h][1] + xf[2]*vsr[h][2] + xf[3]*vsr[h][3];
        if (isd) {
            #pragma unroll
            for (int h = 0; h < 4; ++h)
                bv[h] = xf[0]*vdr[h][0] + xf[1]*vdr[h][1] + xf[2]*vdr[h][2] + xf[3]*vdr[h][3];
        }
        #pragma unroll
        for (int off = 16; off > 0; off >>= 1) {
            #pragma unroll
            for (int h = 0; h < 4; ++h) a[h] += __shfl_xor(a[h], off);
            if (isd)
                #pragma unroll
                for (int h = 0; h < 4; ++h) bv[h] += __shfl_xor(bv[h], off);
        }
        if (j32 == 0) {
            *(float4*)(als + node * 4) = make_float4(a[0], a[1], a[2], a[3]);
            if (isd) *(float4*)(ald + node * 4) = make_float4(bv[0], bv[1], bv[2], bv[3]);
        }
    }
}

// ==================== L2/L3: al src+dst in ONE launch (grid split) ====================
__global__ void al1024d_kernel(const unsigned short* __restrict__ xb,
                               const float* __restrict__ vs, const float* __restrict__ vd,
                               float* __restrict__ als, float* __restrict__ ald,
                               int nsrc, int ndst, int bsrc)
{
    bool isdst = (int)blockIdx.x >= bsrc;
    const float* v = isdst ? vd : vs;
    float* al = isdst ? ald : als;
    int n = isdst ? ndst : nsrc;
    int b0 = isdst ? blockIdx.x - bsrc : blockIdx.x;
    int nb = isdst ? gridDim.x - bsrc : bsrc;
    int lane = threadIdx.x & 63;
    int wave = (b0 * 256 + threadIdx.x) >> 6;
    int nwaves = (nb * 256) >> 6;
    float vr[4][16];
    #pragma unroll
    for (int h = 0; h < 4; ++h)
        #pragma unroll
        for (int it = 0; it < 2; ++it) {
            ld4(v + h * 1024 + it * 512 + lane * 8,     &vr[h][it * 8]);
            ld4(v + h * 1024 + it * 512 + lane * 8 + 4, &vr[h][it * 8 + 4]);
        }
    for (long node = wave; node < n; node += nwaves) {
        const unsigned short* xr = xb + node * 1024;
        float a[4] = {0.f, 0.f, 0.f, 0.f};
        #pragma unroll
        for (int it = 0; it < 2; ++it) {
            short8 u = *(const short8*)(xr + it * 512 + lane * 8);
            #pragma unroll
            for (int j = 0; j < 8; ++j) {
                float xv = b2f((unsigned short)u[j]);
                #pragma unroll
                for (int h = 0; h < 4; ++h) a[h] += xv * vr[h][it * 8 + j];
            }
        }
        #pragma unroll
        for (int off = 32; off > 0; off >>= 1)
            #pragma unroll
            for (int h = 0; h < 4; ++h) a[h] += __shfl_xor(a[h], off);
        if (lane == 0) *(float4*)(al + node * 4) = make_float4(a[0], a[1], a[2], a[3]);
    }
}

// ==================== wave-parallel softmax stats + per-edge alpha ====================
// one wave per dst; lanes stride edges; shfl reduce (max exact; sum reassociated, deterministic)
__global__ void mdnw_kernel(const float* __restrict__ als, const float* __restrict__ ald,
                            const int* __restrict__ offsets, const int* __restrict__ elist,
                            const int* __restrict__ esrc, int size,
                            float* __restrict__ aself, float* __restrict__ walpha)
{
    int d = blockIdx.x * 4 + (threadIdx.x >> 6);
    if (d >= size) return;
    int lane = threadIdx.x & 63;
    float ad[4], sl[4], q[4];
    ld4(ald + 4 * (size_t)d, ad);
    ld4(als + 4 * (size_t)d, q);
    #pragma unroll
    for (int h = 0; h < 4; ++h) sl[h] = lrelu(q[h] + ad[h]);
    int beg = offsets[d], deg = offsets[d + 1] - beg;
    // pass 1: max (self included via init)
    float m[4] = { sl[0], sl[1], sl[2], sl[3] };
    for (int p = lane; p < deg; p += 64) {
        int s = esrc[elist[beg + p]];
        ld4(als + 4 * (size_t)s, q);
        #pragma unroll
        for (int h = 0; h < 4; ++h) m[h] = fmaxf(m[h], lrelu(q[h] + ad[h]));
    }
    #pragma unroll
    for (int off = 32; off > 0; off >>= 1)
        #pragma unroll
        for (int h = 0; h < 4; ++h) m[h] = fmaxf(m[h], __shfl_xor(m[h], off));
    // pass 2: denom
    float dn[4] = {0.f, 0.f, 0.f, 0.f};
    for (int p = lane; p < deg; p += 64) {
        int s = esrc[elist[beg + p]];
        ld4(als + 4 * (size_t)s, q);
        #pragma unroll
        for (int h = 0; h < 4; ++h) dn[h] += expf(lrelu(q[h] + ad[h]) - m[h]);
    }
    #pragma unroll
    for (int off = 32; off > 0; off >>= 1)
        #pragma unroll
        for (int h = 0; h < 4; ++h) dn[h] += __shfl_xor(dn[h], off);
    float r[4];
    #pragma unroll
    for (int h = 0; h < 4; ++h)
        r[h] = 1.f / (dn[h] + expf(sl[h] - m[h]) + 1e-16f);
    if (lane == 0) {
        float4 w;
        w.x = expf(sl[0] - m[0]) * r[0];
        w.y = expf(sl[1] - m[1]) * r[1];
        w.z = expf(sl[2] - m[2]) * r[2];
        w.w = expf(sl[3] - m[3]) * r[3];
        *(float4*)(aself + 4 * (size_t)d) = w;
    }
    // pass 3: per-edge alpha (each slot written once)
    for (int p = lane; p < deg; p += 64) {
        int e = elist[beg + p];
        int s = esrc[e];
        ld4(als + 4 * (size_t)s, q);
        float4 w;
        w.x = expf(lrelu(q[0] + ad[0]) - m[0]) * r[0];
        w.y = expf(lrelu(q[1] + ad[1]) - m[1]) * r[1];
        w.z = expf(lrelu(q[2] + ad[2]) - m[2]) * r[2];
        w.w = expf(lrelu(q[3] + ad[3]) - m[3]) * r[3];
        *(float4*)(walpha + 4 * (size_t)e) = w;
    }
}

// ==================== aggregation (precomputed alpha) ====================
__global__ void agg128_kernel(const unsigned short* __restrict__ xb, const float* __restrict__ walpha,
                              const float* __restrict__ aself,
                              const int* __restrict__ offsets, const int* __restrict__ elist,
                              const int* __restrict__ esrc, unsigned short* __restrict__ aggb)
{
    int d = blockIdx.x, lane = threadIdx.x;
    int beg = offsets[d], end = offsets[d + 1];
    float w[4], acc[4][2];
    ld4(aself + 4 * (size_t)d, w);
    {
        unsigned int u = *(const unsigned int*)(xb + (size_t)d * 128 + lane * 2);
        float x0 = b2f((unsigned short)(u & 0xFFFF)), x1 = b2f((unsigned short)(u >> 16));
        #pragma unroll
        for (int h = 0; h < 4; ++h) { acc[h][0] = w[h] * x0; acc[h][1] = w[h] * x1; }
    }
    for (int p = beg; p < end; ++p) {
        int e = elist[p];
        int s = esrc[e];
        ld4(walpha + 4 * (size_t)e, w);
        unsigned int u = *(const unsigned int*)(xb + (size_t)s * 128 + lane * 2);
        float x0 = b2f((unsigned short)(u & 0xFFFF)), x1 = b2f((unsigned short)(u >> 16));
        #pragma unroll
        for (int h = 0; h < 4; ++h) { acc[h][0] += w[h] * x0; acc[h][1] += w[h] * x1; }
    }
    unsigned int* og = (unsigned int*)(aggb + (size_t)d * 512);
    #pragma unroll
    for (int h = 0; h < 4; ++h)
        og[h * 64 + lane] = (unsigned int)f2b(acc[h][0]) | ((unsigned int)f2b(acc[h][1]) << 16);
}

__global__ void agg1024_kernel(const unsigned short* __restrict__ xb, const float* __restrict__ walpha,
                               const float* __restrict__ aself,
                               const int* __restrict__ offsets, const int* __restrict__ elist,
                               const int* __restrict__ esrc, unsigned short* __restrict__ aggb)
{
    int d = blockIdx.x, t = threadIdx.x;
    int beg = offsets[d], end = offsets[d + 1];
    float w[4], acc[4][4];
    ld4(aself + 4 * (size_t)d, w);
    {
        ushort4 u = *(const ushort4*)(xb + (size_t)d * 1024 + t * 4);
        float xv[4] = { b2f(u.x), b2f(u.y), b2f(u.z), b2f(u.w) };
        #pragma unroll
        for (int h = 0; h < 4; ++h)
            #pragma unroll
            for (int j = 0; j < 4; ++j) acc[h][j] = w[h] * xv[j];
    }
    for (int p = beg; p < end; ++p) {
        int e = elist[p];
        int s = esrc[e];
        ld4(walpha + 4 * (size_t)e, w);
        ushort4 u = *(const ushort4*)(xb + (size_t)s * 1024 + t * 4);
        float xv[4] = { b2f(u.x), b2f(u.y), b2f(u.z), b2f(u.w) };
        #pragma unroll
        for (int h = 0; h < 4; ++h)
            #pragma unroll
            for (int j = 0; j < 4; ++j) acc[h][j] += w[h] * xv[j];
    }
    unsigned short* og = aggb + (size_t)d * 4096;
    #pragma unroll
    for (int h = 0; h < 4; ++h) {
        ushort4 u;
        u.x = f2b(acc[h][0]); u.y = f2b(acc[h][1]);
        u.z = f2b(acc[h][2]); u.w = f2b(acc[h][3]);
        *(ushort4*)(og + h * 1024 + t * 4) = u;
    }
}

// ==================== fused dual-phase bf16 MFMA GEMM + BN stats (L1/L2) ====================
// LDS slot s (16B) holds global chunk (s&3)^sw(s>>2); staged via global_load_lds with
// chunk-permuted per-lane SOURCE address (linear LDS dest, rule #21). Read path uses SWZ.
#define SWZ(r, c) ((((c) ^ (((r) >> 1) & 3)) << 3))

template<int BM, int BN>
__global__ __launch_bounds__(256) void gemm2_kernel(
    const unsigned short* __restrict__ A1, int lda1, const unsigned short* __restrict__ W1, int K1,
    const unsigned short* __restrict__ A2, int lda2, const unsigned short* __restrict__ W2, int K2,
    int hs2, int cph2,
    unsigned short* __restrict__ C, int N,
    float* __restrict__ bnsum, float* __restrict__ bnsq)
{
    constexpr int WM = BM / 2, WN = BN / 2;
    constexpr int TM = WM / 16, TN = WN / 16;
    constexpr int APASS = (BM * 4) / 256, BPASS = (BN * 4) / 256;
    __shared__ __align__(16) unsigned short As[BM * 32];
    __shared__ __align__(16) unsigned short Bs[BN * 32];
    __shared__ float sbn[2 * BN];
    int tid = threadIdx.x;
    int n0 = blockIdx.x * BN, m0 = blockIdx.y * BM;
    int l = tid & 63, l16 = l & 15, kq = l >> 4;
    int wid = tid >> 6, wr = wid >> 1, wc = wid & 1;

    f32x4 acc[TM][TN];
    #pragma unroll
    for (int mi = 0; mi < TM; ++mi)
        #pragma unroll
        for (int ni = 0; ni < TN; ++ni) acc[mi][ni] = (f32x4){0.f, 0.f, 0.f, 0.f};

    #pragma unroll
    for (int ph = 0; ph < 2; ++ph) {
        const unsigned short* Ap = ph ? A2 + (size_t)m0 * lda2 + (cph2 ? (size_t)(n0 / cph2) * hs2 : 0)
                                      : A1 + (size_t)m0 * lda1;
        int lda = ph ? lda2 : lda1;
        const unsigned short* Wp = ph ? W2 + (size_t)n0 * K2 : W1 + (size_t)n0 * K1;
        int ldw = ph ? K2 : K1;
        int K = ph ? K2 : K1;
        for (int k0 = 0; k0 < K; k0 += 32) {
            #pragma unroll
            for (int ps = 0; ps < APASS; ++ps) {
                int sbase = ps * 256 + wid * 64;
                int s = sbase + l;
                int r = s >> 2, cc = s & 3;
                gload_lds16(Ap + (size_t)r * lda + k0 + ((cc ^ ((r >> 1) & 3)) << 3),
                            &As[(size_t)sbase * 8]);
            }
            #pragma unroll
            for (int ps = 0; ps < BPASS; ++ps) {
                int sbase = ps * 256 + wid * 64;
                int s = sbase + l;
                int r = s >> 2, cc = s & 3;
                gload_lds16(Wp + (size_t)r * ldw + k0 + ((cc ^ ((r >> 1) & 3)) << 3),
                            &Bs[(size_t)sbase * 8]);
            }
            __syncthreads();
            short8 af[TM], bfr[TN];
            #pragma unroll
            for (int mi = 0; mi < TM; ++mi) {
                int r = wr * WM + mi * 16 + l16;
                af[mi] = *(const short8*)&As[r * 32 + SWZ(r, kq)];
            }
            #pragma unroll
            for (int ni = 0; ni < TN; ++ni) {
                int r = wc * WN + ni * 16 + l16;
                bfr[ni] = *(const short8*)&Bs[r * 32 + SWZ(r, kq)];
            }
            #pragma unroll
            for (int mi = 0; mi < TM; ++mi)
                #pragma unroll
                for (int ni = 0; ni < TN; ++ni)
                    acc[mi][ni] = __builtin_amdgcn_mfma_f32_16x16x32_bf16(
                        af[mi], bfr[ni], acc[mi][ni], 0, 0, 0);
            __syncthreads();
        }
    }

    if (tid < 2 * BN) sbn[tid] = 0.f;
    __syncthreads();

    #pragma unroll
    for (int ni = 0; ni < TN; ++ni) {
        int col = wc * WN + ni * 16 + l16;
        float s = 0.f, q = 0.f;
        #pragma unroll
        for (int mi = 0; mi < TM; ++mi) {
            int rowb = wr * WM + mi * 16 + (kq << 2);
            #pragma unroll
            for (int r = 0; r < 4; ++r) {
                float v = acc[mi][ni][r];
                C[(size_t)(m0 + rowb + r) * N + n0 + col] = f2b(v);
                s += v; q += v * v;
            }
        }
        atomicAdd(&sbn[col * 2 + 0], s);
        atomicAdd(&sbn[col * 2 + 1], q);
    }
    __syncthreads();
    if (tid < BN) {
        atomicAdd(&bnsum[n0 + tid], sbn[tid * 2 + 0]);
        atomicAdd(&bnsq[n0 + tid], sbn[tid * 2 + 1]);
    }
}

// ==================== L3: split-K GEMM -> Cpart[z][512][256] (deterministic) ====================
__global__ __launch_bounds__(256) void gemm3_splitk(
    const unsigned short* __restrict__ A1, const unsigned short* __restrict__ W1,
    const unsigned short* __restrict__ A2, const unsigned short* __restrict__ W2,
    float* __restrict__ Cpart)
{
    constexpr int BM = 64, BN = 64, WM = 32, WN = 32, TM = 2, TN = 2;
    __shared__ __align__(16) unsigned short As[BM * 32];
    __shared__ __align__(16) unsigned short Bs[BN * 32];
    int tid = threadIdx.x;
    int n0 = blockIdx.x * BN, m0 = blockIdx.y * BM;
    int z = blockIdx.z;
    int ph = (z >= 2);
    int ks = ph ? (z - 2) * 512 : z * 512;
    const unsigned short* Ap = ph ? A2 + (size_t)m0 * 4096 : A1 + (size_t)m0 * 1024;
    const unsigned short* Wp = ph ? W2 + (size_t)n0 * 4096 : W1 + (size_t)n0 * 1024;
    int lda = ph ? 4096 : 1024;
    int l = tid & 63, l16 = l & 15, kq = l >> 4;
    int wid = tid >> 6, wr = wid >> 1, wc = wid & 1;

    f32x4 acc[TM][TN];
    #pragma unroll
    for (int mi = 0; mi < TM; ++mi)
        #pragma unroll
        for (int ni = 0; ni < TN; ++ni) acc[mi][ni] = (f32x4){0.f, 0.f, 0.f, 0.f};

    for (int k0 = ks; k0 < ks + 512; k0 += 32) {
        {
            int sbase = wid * 64;
            int s = sbase + l;
            int r = s >> 2, cc = s & 3;
            gload_lds16(Ap + (size_t)r * lda + k0 + ((cc ^ ((r >> 1) & 3)) << 3),
                        &As[(size_t)sbase * 8]);
            gload_lds16(Wp + (size_t)r * lda + k0 + ((cc ^ ((r >> 1) & 3)) << 3),
                        &Bs[(size_t)sbase * 8]);
        }
        __syncthreads();
        short8 af[TM], bfr[TN];
        #pragma unroll
        for (int mi = 0; mi < TM; ++mi) {
            int r = wr * WM + mi * 16 + l16;
            af[mi] = *(const short8*)&As[r * 32 + SWZ(r, kq)];
        }
        #pragma unroll
        for (int ni = 0; ni < TN; ++ni) {
            int r = wc * WN + ni * 16 + l16;
            bfr[ni] = *(const short8*)&Bs[r * 32 + SWZ(r, kq)];
        }
        #pragma unroll
        for (int mi = 0; mi < TM; ++mi)
            #pragma unroll
            for (int ni = 0; ni < TN; ++ni)
                acc[mi][ni] = __builtin_amdgcn_mfma_f32_16x16x32_bf16(
                    af[mi], bfr[ni], acc[mi][ni], 0, 0, 0);
        __syncthreads();
    }

    float* Cz = Cpart + (size_t)z * S3 * 256;
    #pragma unroll
    for (int ni = 0; ni < TN; ++ni) {
        int col = wc * WN + ni * 16 + l16;
        #pragma unroll
        for (int mi = 0; mi < TM; ++mi) {
            int rowb = wr * WM + mi * 16 + (kq << 2);
            #pragma unroll
            for (int r = 0; r < 4; ++r)
                Cz[(size_t)(m0 + rowb + r) * 256 + n0 + col] = acc[mi][ni][r];
        }
    }
}

// reduce Cpart over z -> hb32, accumulate BN column stats
__global__ void bnstat3_kernel(const float* __restrict__ Cpart, float* __restrict__ hb32,
                               float* __restrict__ bnsum, float* __restrict__ bnsq)
{
    int c = threadIdx.x;
    int r0 = blockIdx.x * 64;
    float s = 0.f, q = 0.f;
    for (int r = r0; r < r0 + 64; ++r) {
        float v = 0.f;
        #pragma unroll
        for (int z = 0; z < 10; ++z)
            v += Cpart[((size_t)z * S3 + r) * 256 + c];
        hb32[(size_t)r * 256 + c] = v;
        s += v; q += v * v;
    }
    atomicAdd(&bnsum[c], s);
    atomicAdd(&bnsq[c], q);
}

// ==================== BN finalize fused into apply + ELU ====================
__global__ void norm_elu_bb(const unsigned short* __restrict__ h,
                            const float* __restrict__ sum, const float* __restrict__ sq,
                            const float* __restrict__ gamma, const float* __restrict__ beta,
                            unsigned short* __restrict__ out, int N, float invM, long total)
{
    long i = ((long)blockIdx.x * 256 + threadIdx.x) * 4;
    if (i >= total) return;
    int c = (int)(i % N);
    float4 sm = *(const float4*)(sum + c);
    float4 qq = *(const float4*)(sq + c);
    float4 gm = *(const float4*)(gamma + c);
    float4 bt = *(const float4*)(beta + c);
    float mu0 = sm.x * invM, mu1 = sm.y * invM, mu2 = sm.z * invM, mu3 = sm.w * invM;
    float sc0 = gm.x * rsqrtf(qq.x * invM - mu0 * mu0 + BN_EPS);
    float sc1 = gm.y * rsqrtf(qq.y * invM - mu1 * mu1 + BN_EPS);
    float sc2 = gm.z * rsqrtf(qq.z * invM - mu2 * mu2 + BN_EPS);
    float sc3 = gm.w * rsqrtf(qq.w * invM - mu3 * mu3 + BN_EPS);
    float sh0 = bt.x - mu0 * sc0, sh1 = bt.y - mu1 * sc1;
    float sh2 = bt.z - mu2 * sc2, sh3 = bt.w - mu3 * sc3;
    ushort4 u = *(const ushort4*)(h + i);
    float v0 = b2f(u.x) * sc0 + sh0;
    float v1 = b2f(u.y) * sc1 + sh1;
    float v2 = b2f(u.z) * sc2 + sh2;
    float v3 = b2f(u.w) * sc3 + sh3;
    v0 = v0 > 0.f ? v0 : expm1f(v0);
    v1 = v1 > 0.f ? v1 : expm1f(v1);
    v2 = v2 > 0.f ? v2 : expm1f(v2);
    v3 = v3 > 0.f ? v3 : expm1f(v3);
    ushort4 o;
    o.x = f2b(v0); o.y = f2b(v1); o.z = f2b(v2); o.w = f2b(v3);
    *(ushort4*)(out + i) = o;
}

__global__ void norm_elu_ff(const float* __restrict__ h,
                            const float* __restrict__ sum, const float* __restrict__ sq,
                            const float* __restrict__ gamma, const float* __restrict__ beta,
                            float* __restrict__ out, int N, float invM, long total)
{
    long i = ((long)blockIdx.x * 256 + threadIdx.x) * 4;
    if (i >= total) return;
    int c = (int)(i % N);
    float4 sm = *(const float4*)(sum + c);
    float4 qq = *(const float4*)(sq + c);
    float4 gm = *(const float4*)(gamma + c);
    float4 bt = *(const float4*)(beta + c);
    float mu0 = sm.x * invM, mu1 = sm.y * invM, mu2 = sm.z * invM, mu3 = sm.w * invM;
    float sc0 = gm.x * rsqrtf(qq.x * invM - mu0 * mu0 + BN_EPS);
    float sc1 = gm.y * rsqrtf(qq.y * invM - mu1 * mu1 + BN_EPS);
    float sc2 = gm.z * rsqrtf(qq.z * invM - mu2 * mu2 + BN_EPS);
    float sc3 = gm.w * rsqrtf(qq.w * invM - mu3 * mu3 + BN_EPS);
    float4 hv = *(const float4*)(h + i);
    float4 o;
    o.x = hv.x * sc0 + (bt.x - mu0 * sc0);
    o.y = hv.y * sc1 + (bt.y - mu1 * sc1);
    o.z = hv.z * sc2 + (bt.z - mu2 * sc2);
    o.w = hv.w * sc3 + (bt.w - mu3 * sc3);
    o.x = o.x > 0.f ? o.x : expm1f(o.x);
    o.y = o.y > 0.f ? o.y : expm1f(o.y);
    o.z = o.z > 0.f ? o.z : expm1f(o.z);
    o.w = o.w > 0.f ? o.w : expm1f(o.w);
    *(float4*)(out + i) = o;
}

// =====================================================================
extern "C" void kernel_launch(void* const* d_in, const int* in_sizes, int n_in,
                              void* d_out, int out_size, void* d_ws, size_t ws_size,
                              hipStream_t stream)
{
    const float* x = (const float*)d_in[0];
    auto P = [&](int layer, int slot) -> const float* {
        return (const float*)d_in[1 + (layer - 1) * 9 + slot];
    };
    const int* edge_src[3] = { (const int*)d_in[28], (const int*)d_in[30], (const int*)d_in[32] };
    const int* edge_dst[3] = { (const int*)d_in[29], (const int*)d_in[31], (const int*)d_in[33] };

    // -------- workspace carve --------
    char* wsb = (char*)d_ws;
    size_t off = 0;
    auto alloc = [&](size_t bytes) -> void* {
        void* p = wsb + off;
        off = (off + bytes + 255) & ~(size_t)255;
        return p;
    };
    unsigned short* xb0   = (unsigned short*)alloc((size_t)N0 * 128 * 2);
    unsigned short* x1b   = (unsigned short*)alloc((size_t)S1 * 1024 * 2);
    unsigned short* x2b   = (unsigned short*)alloc((size_t)S2 * 1024 * 2);
    unsigned short* hb    = (unsigned short*)alloc((size_t)S1 * 1024 * 2);
    unsigned short* aggb  = (unsigned short*)alloc((size_t)S2 * 4096 * 2);
    unsigned short* wskipb[3] = {
        (unsigned short*)alloc(131072 * 2),
        (unsigned short*)alloc(1048576 * 2),
        (unsigned short*)alloc(262144 * 2) };
    unsigned short* wsrcb[3] = {
        (unsigned short*)alloc(131072 * 2),
        (unsigned short*)alloc(1048576 * 2),
        (unsigned short*)alloc(1048576 * 2) };
    float* vbuf[6];
    vbuf[0] = (float*)alloc(512 * 4);
    vbuf[1] = (float*)alloc(512 * 4);
    vbuf[2] = (float*)alloc(4096 * 4);
    vbuf[3] = (float*)alloc(4096 * 4);
    vbuf[4] = (float*)alloc(4096 * 4);
    vbuf[5] = (float*)alloc(4096 * 4);
    float* als     = (float*)alloc((size_t)N0 * 4 * 4);
    float* ald     = (float*)alloc((size_t)S1 * 4 * 4);
    float* aself   = (float*)alloc((size_t)S1 * 4 * 4);
    float* walpha  = (float*)alloc((size_t)E1 * 4 * 4);
    float* Cpart   = (float*)alloc((size_t)10 * S3 * 256 * 4);
    float* hb32    = (float*)alloc((size_t)S3 * 256 * 4);
    int* offsets3[3] = { (int*)alloc((S1 + 1) * 4), (int*)alloc((S2 + 1) * 4), (int*)alloc((S3 + 1) * 4) };
    int* cursor3 [3] = { (int*)alloc(S1 * 4), (int*)alloc(S2 * 4), (int*)alloc(S3 * 4) };
    int* elist3  [3] = { (int*)alloc(E1 * 4), (int*)alloc(E2 * 4), (int*)alloc(E3 * 4) };
    int zn = S1 + S2 + S3 + 6 * 1024;
    int* zreg = (int*)alloc((size_t)zn * 4);
    int* counts[3] = { zreg, zreg + S1, zreg + S1 + S2 };
    float* bnsum[3] = { (float*)(zreg + S1 + S2 + S3),
                        (float*)(zreg + S1 + S2 + S3 + 2048),
                        (float*)(zreg + S1 + S2 + S3 + 4096) };
    float* bnsq[3]  = { bnsum[0] + 1024, bnsum[1] + 1024, bnsum[2] + 1024 };

    // -------- one-shot prep: folds + weight bf16 + zeroing --------
    PrepArgs pa;
    for (int L = 0; L < 3; ++L) {
        pa.att[2 * L]     = P(L + 1, 2); pa.wf[2 * L]     = P(L + 1, 0); pa.v[2 * L]     = vbuf[2 * L];
        pa.att[2 * L + 1] = P(L + 1, 3); pa.wf[2 * L + 1] = P(L + 1, 1); pa.v[2 * L + 1] = vbuf[2 * L + 1];
    }
    pa.csrc[0] = P(1, 5); pa.cdst[0] = wskipb[0];
    pa.csrc[1] = P(1, 0); pa.cdst[1] = wsrcb[0];
    pa.csrc[2] = P(2, 5); pa.cdst[2] = wskipb[1];
    pa.csrc[3] = P(2, 0); pa.cdst[3] = wsrcb[1];
    pa.csrc[4] = P(3, 5); pa.cdst[4] = wskipb[2];
    pa.csrc[5] = P(3, 0); pa.cdst[5] = wsrcb[2];
    pa.zptr = zreg; pa.zn4 = zn / 4;
    prep_kernel<<<167, 256, 0, stream>>>(pa);

    // -------- CSR build for all layers --------
    CsrArgs ca;
    for (int L = 0; L < 3; ++L) {
        ca.edst[L] = edge_dst[L];
        ca.counts[L] = counts[L]; ca.offsets[L] = offsets3[L];
        ca.cursor[L] = cursor3[L]; ca.elist[L] = elist3[L];
    }
    ca.sizes[0] = S1; ca.sizes[1] = S2; ca.sizes[2] = S3;
    count_all<<<(E1 + E2 + E3) / 256, 256, 0, stream>>>(ca);
    scan_all<<<3, 1024, 0, stream>>>(ca);
    scatter_all<<<(E1 + E2 + E3) / 256, 256, 0, stream>>>(ca);

    // ---------------- layer 1 ----------------
    al128f_kernel<<<2048, 256, 0, stream>>>(x, vbuf[0], vbuf[1], xb0, als, ald, N0, S1);
    mdnw_kernel<<<(S1 + 3) / 4, 256, 0, stream>>>(als, ald, offsets3[0], elist3[0], edge_src[0],
                                                  S1, aself, walpha);
    agg128_kernel<<<S1, 64, 0, stream>>>(xb0, walpha, aself, offsets3[0], elist3[0], edge_src[0], aggb);
    gemm2_kernel<128, 128><<<dim3(1024 / 128, S1 / 128), 256, 0, stream>>>(
        xb0, 128, wskipb[0], 128,
        aggb, 512, wsrcb[0], 128, 128, 256,
        hb, 1024, bnsum[0], bnsq[0]);
    norm_elu_bb<<<(int)(((long)S1 * 1024 / 4 + 255) / 256), 256, 0, stream>>>(
        hb, bnsum[0], bnsq[0], P(1, 7), P(1, 8), x1b, 1024, 1.f / S1, (long)S1 * 1024);

    // ---------------- layer 2 ----------------
    al1024d_kernel<<<576, 256, 0, stream>>>(x1b, vbuf[2], vbuf[3], als, ald, S1, S2, 512);
    mdnw_kernel<<<(S2 + 3) / 4, 256, 0, stream>>>(als, ald, offsets3[1], elist3[1], edge_src[1],
                                                  S2, aself, walpha);
    agg1024_kernel<<<S2, 256, 0, stream>>>(x1b, walpha, aself, offsets3[1], elist3[1], edge_src[1], aggb);
    gemm2_kernel<64, 64><<<dim3(1024 / 64, S2 / 64), 256, 0, stream>>>(
        x1b, 1024, wskipb[1], 1024,
        aggb, 4096, wsrcb[1], 1024, 1024, 256,
        hb, 1024, bnsum[1], bnsq[1]);
    norm_elu_bb<<<(int)(((long)S2 * 1024 / 4 + 255) / 256), 256, 0, stream>>>(
        hb, bnsum[1], bnsq[1], P(2, 7), P(2, 8), x2b, 1024, 1.f / S2, (long)S2 * 1024);

    // ---------------- layer 3 ----------------
    al1024d_kernel<<<72, 256, 0, stream>>>(x2b, vbuf[4], vbuf[5], als, ald, S2, S3, 64);
    mdnw_kernel<<<(S3 + 3) / 4, 256, 0, stream>>>(als, ald, offsets3[2], elist3[2], edge_src[2],
                                                  S3, aself, walpha);
    agg1024_kernel<<<S3, 256, 0, stream>>>(x2b, walpha, aself, offsets3[2], elist3[2], edge_src[2], aggb);
    gemm3_splitk<<<dim3(256 / 64, S3 / 64, 10), 256, 0, stream>>>(
        x2b, wskipb[2], aggb, wsrcb[2], Cpart);
    bnstat3_kernel<<<8, 256, 0, stream>>>(Cpart, hb32, bnsum[2], bnsq[2]);
    norm_elu_ff<<<(int)(((long)S3 * 256 / 4 + 255) / 256), 256, 0, stream>>>(
        hb32, bnsum[2], bnsq[2], P(3, 7), P(3, 8), (float*)d_out, 256, 1.f / S3, (long)S3 * 256);
}

// Round 10
// 508.201 us; speedup vs baseline: 3.8586x; 1.0617x over previous
//
#include <hip/hip_runtime.h>
#include <math.h>

// ---------------- problem constants (from reference) ----------------
constexpr int N0 = 262144, S1 = 32768, S2 = 4096, S3 = 512;
constexpr int E1 = 327680, E2 = 40960, E3 = 5120;
constexpr float NEG = 0.2f, BN_EPS = 1e-5f;

typedef __attribute__((ext_vector_type(8))) short short8;   // 8 bf16 (4 VGPRs)
typedef __attribute__((ext_vector_type(4))) float f32x4;    // MFMA acc

__device__ __forceinline__ float lrelu(float x) { return x > 0.f ? x : NEG * x; }

__device__ __forceinline__ unsigned short f2b(float f) {  // f32 -> bf16 RNE
    unsigned int u = __float_as_uint(f);
    return (unsigned short)((u + 0x7FFFu + ((u >> 16) & 1u)) >> 16);
}
__device__ __forceinline__ float b2f(unsigned short u) {
    return __uint_as_float(((unsigned int)u) << 16);
}
__device__ __forceinline__ void ld4(const float* __restrict__ p, float* o) {
    float4 v = *(const float4*)p;
    o[0] = v.x; o[1] = v.y; o[2] = v.z; o[3] = v.w;
}

// async global->LDS, 16B per lane; LDS dest = wave-uniform base + lane*16
__device__ __forceinline__ void gload_lds16(const unsigned short* g, unsigned short* l) {
    __builtin_amdgcn_global_load_lds(
        (const __attribute__((address_space(1))) unsigned int*)g,
        (__attribute__((address_space(3))) unsigned int*)l, 16, 0, 0);
}

// ==================== one-shot prep ====================
struct PrepArgs {
    const float* att[6]; const float* wf[6]; float* v[6];
    const float* csrc[6]; unsigned short* cdst[6];
    int* zptr; int zn4;
};

__global__ void prep_kernel(PrepArgs a)
{
    int b = blockIdx.x, t = threadIdx.x;
    if (b < 68) {
        int f, cb;
        if (b < 2)       { f = 0; cb = b; }
        else if (b < 4)  { f = 1; cb = b - 2; }
        else if (b < 20) { f = 2; cb = b - 4; }
        else if (b < 36) { f = 3; cb = b - 20; }
        else if (b < 52) { f = 4; cb = b - 36; }
        else             { f = 5; cb = b - 52; }
        int din = (f < 2) ? 128 : 1024;
        int idx = cb * 256 + t;
        int h = idx / din, k = idx - h * din;
        const float* ar = a.att[f] + h * 256;
        const float* wr = a.wf[f] + (size_t)(h * 256) * din + k;
        float acc = 0.f;
        for (int j = 0; j < 256; ++j) acc += ar[j] * wr[(size_t)j * din];
        a.v[f][idx] = acc;
    } else if (b < 124) {
        int c = b - 68, j, ob;
        if (c < 2)       { j = 0; ob = c; }
        else if (c < 4)  { j = 1; ob = c - 2; }
        else if (c < 20) { j = 2; ob = c - 4; }
        else if (c < 36) { j = 3; ob = c - 20; }
        else if (c < 40) { j = 4; ob = c - 36; }
        else             { j = 5; ob = c - 40; }
        long base = (long)ob * 65536;
        if (j < 5) {
            const float* src = a.csrc[j];
            unsigned short* dst = a.cdst[j];
            for (int it = 0; it < 64; ++it) {
                long e = base + (long)(it * 256 + t) * 4;
                float4 v = *(const float4*)(src + e);
                ushort4 u;
                u.x = f2b(v.x); u.y = f2b(v.y); u.z = f2b(v.z); u.w = f2b(v.w);
                *(ushort4*)(dst + e) = u;
            }
        } else {  // w3 repack: wp[row*4096 + h*1024 + k] = 0.25*w[(h*256+row)*1024+k]
            const float* src = a.csrc[5];
            unsigned short* dst = a.cdst[5];
            for (int it = 0; it < 64; ++it) {
                long e = base + (long)(it * 256 + t) * 4;
                int row = (int)(e >> 12);
                int hk = (int)(e & 4095);
                int h = hk >> 10, k = hk & 1023;
                float4 v = *(const float4*)(src + ((size_t)(h * 256 + row) << 10) + k);
                ushort4 u;
                u.x = f2b(0.25f * v.x); u.y = f2b(0.25f * v.y);
                u.z = f2b(0.25f * v.z); u.w = f2b(0.25f * v.w);
                *(ushort4*)(dst + e) = u;
            }
        }
    } else {
        int i = (b - 124) * 256 + t;
        if (i < a.zn4) ((int4*)a.zptr)[i] = make_int4(0, 0, 0, 0);
    }
}

// ==================== CSR build for ALL layers (input-only) ====================
// scatter stores the SOURCE node id directly (slist) to kill the elist->esrc chase.
struct CsrArgs {
    const int* edst[3]; const int* esrc[3];
    int* counts[3]; int* offsets[3]; int* cursor[3]; int* slist[3];
    int sizes[3];
};

__global__ void count_all(CsrArgs a)
{
    int id = blockIdx.x * 256 + threadIdx.x;
    int L, e;
    if (id < E1)           { L = 0; e = id; }
    else if (id < E1 + E2) { L = 1; e = id - E1; }
    else if (id < E1 + E2 + E3) { L = 2; e = id - E1 - E2; }
    else return;
    atomicAdd(&a.counts[L][a.edst[L][e]], 1);
}

__global__ void scan_all(CsrArgs a)
{
    __shared__ int lds[1024];
    int L = blockIdx.x;
    int size = a.sizes[L];
    const int* counts = a.counts[L];
    int* offsets = a.offsets[L];
    int* cursor = a.cursor[L];
    int t = threadIdx.x;
    int chunk = (size + 1023) >> 10;
    int begin = t * chunk;
    int end = begin + chunk; if (end > size) end = size;
    if (begin > size) begin = size;
    int s = 0;
    if ((chunk & 3) == 0) {
        for (int i = begin; i < end; i += 4) {
            int4 v = *(const int4*)(counts + i);
            s += v.x + v.y + v.z + v.w;
        }
    } else {
        for (int i = begin; i < end; ++i) s += counts[i];
    }
    lds[t] = s;
    __syncthreads();
    for (int d = 1; d < 1024; d <<= 1) {
        int v = (t >= d) ? lds[t - d] : 0;
        __syncthreads();
        lds[t] += v;
        __syncthreads();
    }
    int base = (t > 0) ? lds[t - 1] : 0;
    for (int i = begin; i < end; ++i) {
        offsets[i] = base; cursor[i] = base;
        base += counts[i];
    }
    if (t == 1023) offsets[size] = lds[1023];
}

__global__ void scatter_all(CsrArgs a)
{
    int id = blockIdx.x * 256 + threadIdx.x;
    int L, e;
    if (id < E1)           { L = 0; e = id; }
    else if (id < E1 + E2) { L = 1; e = id - E1; }
    else if (id < E1 + E2 + E3) { L = 2; e = id - E1 - E2; }
    else return;
    int p = atomicAdd(&a.cursor[L][a.edst[L][e]], 1);
    a.slist[L][p] = a.esrc[L][e];
}

// ==================== L1: fused f32->bf16 conv + al_src + al_dst ====================
__global__ void al128f_kernel(const float* __restrict__ x, const float* __restrict__ vs,
                              const float* __restrict__ vd, unsigned short* __restrict__ xb,
                              float* __restrict__ als, float* __restrict__ ald, int n, int ndst)
{
    int lane = threadIdx.x & 63;
    int wave = (blockIdx.x * 256 + threadIdx.x) >> 6;
    int nw = (gridDim.x * 256) >> 6;
    int j32 = lane & 31, half = lane >> 5;
    float vsr[4][4], vdr[4][4];
    #pragma unroll
    for (int h = 0; h < 4; ++h) {
        ld4(vs + h * 128 + j32 * 4, vsr[h]);
        ld4(vd + h * 128 + j32 * 4, vdr[h]);
    }
    for (long node = (long)wave * 2 + half; node < n; node += (long)nw * 2) {
        float4 xv = *(const float4*)(x + node * 128 + j32 * 4);
        ushort4 u;
        u.x = f2b(xv.x); u.y = f2b(xv.y); u.z = f2b(xv.z); u.w = f2b(xv.w);
        *(ushort4*)(xb + node * 128 + j32 * 4) = u;
        float xf[4] = { xv.x, xv.y, xv.z, xv.w };
        float a[4], bv[4];
        bool isd = node < ndst;
        #pragma unroll
        for (int h = 0; h < 4; ++h)
            a[h] = xf[0]*vsr[h][0] + xf[1]*vsr[h][1] + xf[2]*vsr[h][2] + xf[3]*vsr[h][3];
        if (isd) {
            #pragma unroll
            for (int h = 0; h < 4; ++h)
                bv[h] = xf[0]*vdr[h][0] + xf[1]*vdr[h][1] + xf[2]*vdr[h][2] + xf[3]*vdr[h][3];
        }
        #pragma unroll
        for (int off = 16; off > 0; off >>= 1) {
            #pragma unroll
            for (int h = 0; h < 4; ++h) a[h] += __shfl_xor(a[h], off);
            if (isd)
                #pragma unroll
                for (int h = 0; h < 4; ++h) bv[h] += __shfl_xor(bv[h], off);
        }
        if (j32 == 0) {
            *(float4*)(als + node * 4) = make_float4(a[0], a[1], a[2], a[3]);
            if (isd) *(float4*)(ald + node * 4) = make_float4(bv[0], bv[1], bv[2], bv[3]);
        }
    }
}

// ==================== L2/L3: al src+dst in ONE launch (grid split) ====================
__global__ void al1024d_kernel(const unsigned short* __restrict__ xb,
                               const float* __restrict__ vs, const float* __restrict__ vd,
                               float* __restrict__ als, float* __restrict__ ald,
                               int nsrc, int ndst, int bsrc)
{
    bool isdst = (int)blockIdx.x >= bsrc;
    const float* v = isdst ? vd : vs;
    float* al = isdst ? ald : als;
    int n = isdst ? ndst : nsrc;
    int b0 = isdst ? blockIdx.x - bsrc : blockIdx.x;
    int nb = isdst ? gridDim.x - bsrc : bsrc;
    int lane = threadIdx.x & 63;
    int wave = (b0 * 256 + threadIdx.x) >> 6;
    int nwaves = (nb * 256) >> 6;
    float vr[4][16];
    #pragma unroll
    for (int h = 0; h < 4; ++h)
        #pragma unroll
        for (int it = 0; it < 2; ++it) {
            ld4(v + h * 1024 + it * 512 + lane * 8,     &vr[h][it * 8]);
            ld4(v + h * 1024 + it * 512 + lane * 8 + 4, &vr[h][it * 8 + 4]);
        }
    for (long node = wave; node < n; node += nwaves) {
        const unsigned short* xr = xb + node * 1024;
        float a[4] = {0.f, 0.f, 0.f, 0.f};
        #pragma unroll
        for (int it = 0; it < 2; ++it) {
            short8 u = *(const short8*)(xr + it * 512 + lane * 8);
            #pragma unroll
            for (int j = 0; j < 8; ++j) {
                float xv = b2f((unsigned short)u[j]);
                #pragma unroll
                for (int h = 0; h < 4; ++h) a[h] += xv * vr[h][it * 8 + j];
            }
        }
        #pragma unroll
        for (int off = 32; off > 0; off >>= 1)
            #pragma unroll
            for (int h = 0; h < 4; ++h) a[h] += __shfl_xor(a[h], off);
        if (lane == 0) *(float4*)(al + node * 4) = make_float4(a[0], a[1], a[2], a[3]);
    }
}

// ==================== wave-parallel softmax stats + per-slot alpha ====================
// one wave per dst; lanes stride edges; walpha indexed by CSR slot (coalesced writes)
__global__ void mdnw_kernel(const float* __restrict__ als, const float* __restrict__ ald,
                            const int* __restrict__ offsets, const int* __restrict__ slist,
                            int size, float* __restrict__ aself, float* __restrict__ walpha)
{
    int d = blockIdx.x * 4 + (threadIdx.x >> 6);
    if (d >= size) return;
    int lane = threadIdx.x & 63;
    float ad[4], sl[4], q[4];
    ld4(ald + 4 * (size_t)d, ad);
    ld4(als + 4 * (size_t)d, q);
    #pragma unroll
    for (int h = 0; h < 4; ++h) sl[h] = lrelu(q[h] + ad[h]);
    int beg = offsets[d], deg = offsets[d + 1] - beg;
    // pass 1: max (self included via init)
    float m[4] = { sl[0], sl[1], sl[2], sl[3] };
    for (int p = lane; p < deg; p += 64) {
        int s = slist[beg + p];
        ld4(als + 4 * (size_t)s, q);
        #pragma unroll
        for (int h = 0; h < 4; ++h) m[h] = fmaxf(m[h], lrelu(q[h] + ad[h]));
    }
    #pragma unroll
    for (int off = 32; off > 0; off >>= 1)
        #pragma unroll
        for (int h = 0; h < 4; ++h) m[h] = fmaxf(m[h], __shfl_xor(m[h], off));
    // pass 2: denom
    float dn[4] = {0.f, 0.f, 0.f, 0.f};
    for (int p = lane; p < deg; p += 64) {
        int s = slist[beg + p];
        ld4(als + 4 * (size_t)s, q);
        #pragma unroll
        for (int h = 0; h < 4; ++h) dn[h] += expf(lrelu(q[h] + ad[h]) - m[h]);
    }
    #pragma unroll
    for (int off = 32; off > 0; off >>= 1)
        #pragma unroll
        for (int h = 0; h < 4; ++h) dn[h] += __shfl_xor(dn[h], off);
    float r[4];
    #pragma unroll
    for (int h = 0; h < 4; ++h)
        r[h] = 1.f / (dn[h] + expf(sl[h] - m[h]) + 1e-16f);
    if (lane == 0) {
        float4 w;
        w.x = expf(sl[0] - m[0]) * r[0];
        w.y = expf(sl[1] - m[1]) * r[1];
        w.z = expf(sl[2] - m[2]) * r[2];
        w.w = expf(sl[3] - m[3]) * r[3];
        *(float4*)(aself + 4 * (size_t)d) = w;
    }
    // pass 3: per-slot alpha (coalesced float4 stores; each slot written once)
    for (int p = lane; p < deg; p += 64) {
        int s = slist[beg + p];
        ld4(als + 4 * (size_t)s, q);
        float4 w;
        w.x = expf(lrelu(q[0] + ad[0]) - m[0]) * r[0];
        w.y = expf(lrelu(q[1] + ad[1]) - m[1]) * r[1];
        w.z = expf(lrelu(q[2] + ad[2]) - m[2]) * r[2];
        w.w = expf(lrelu(q[3] + ad[3]) - m[3]) * r[3];
        *(float4*)(walpha + 4 * (size_t)(beg + p)) = w;
    }
}

// ==================== aggregation (slot-indexed alpha, direct src ids) ====================
__global__ void agg128_kernel(const unsigned short* __restrict__ xb, const float* __restrict__ walpha,
                              const float* __restrict__ aself,
                              const int* __restrict__ offsets, const int* __restrict__ slist,
                              unsigned short* __restrict__ aggb)
{
    int d = blockIdx.x, lane = threadIdx.x;
    int beg = offsets[d], end = offsets[d + 1];
    float w[4], acc[4][2];
    ld4(aself + 4 * (size_t)d, w);
    {
        unsigned int u = *(const unsigned int*)(xb + (size_t)d * 128 + lane * 2);
        float x0 = b2f((unsigned short)(u & 0xFFFF)), x1 = b2f((unsigned short)(u >> 16));
        #pragma unroll
        for (int h = 0; h < 4; ++h) { acc[h][0] = w[h] * x0; acc[h][1] = w[h] * x1; }
    }
    for (int p = beg; p < end; ++p) {
        int s = slist[p];
        ld4(walpha + 4 * (size_t)p, w);
        unsigned int u = *(const unsigned int*)(xb + (size_t)s * 128 + lane * 2);
        float x0 = b2f((unsigned short)(u & 0xFFFF)), x1 = b2f((unsigned short)(u >> 16));
        #pragma unroll
        for (int h = 0; h < 4; ++h) { acc[h][0] += w[h] * x0; acc[h][1] += w[h] * x1; }
    }
    unsigned int* og = (unsigned int*)(aggb + (size_t)d * 512);
    #pragma unroll
    for (int h = 0; h < 4; ++h)
        og[h * 64 + lane] = (unsigned int)f2b(acc[h][0]) | ((unsigned int)f2b(acc[h][1]) << 16);
}

__global__ void agg1024_kernel(const unsigned short* __restrict__ xb, const float* __restrict__ walpha,
                               const float* __restrict__ aself,
                               const int* __restrict__ offsets, const int* __restrict__ slist,
                               unsigned short* __restrict__ aggb)
{
    int d = blockIdx.x, t = threadIdx.x;
    int beg = offsets[d], end = offsets[d + 1];
    float w[4], acc[4][4];
    ld4(aself + 4 * (size_t)d, w);
    {
        ushort4 u = *(const ushort4*)(xb + (size_t)d * 1024 + t * 4);
        float xv[4] = { b2f(u.x), b2f(u.y), b2f(u.z), b2f(u.w) };
        #pragma unroll
        for (int h = 0; h < 4; ++h)
            #pragma unroll
            for (int j = 0; j < 4; ++j) acc[h][j] = w[h] * xv[j];
    }
    for (int p = beg; p < end; ++p) {
        int s = slist[p];
        ld4(walpha + 4 * (size_t)p, w);
        ushort4 u = *(const ushort4*)(xb + (size_t)s * 1024 + t * 4);
        float xv[4] = { b2f(u.x), b2f(u.y), b2f(u.z), b2f(u.w) };
        #pragma unroll
        for (int h = 0; h < 4; ++h)
            #pragma unroll
            for (int j = 0; j < 4; ++j) acc[h][j] += w[h] * xv[j];
    }
    unsigned short* og = aggb + (size_t)d * 4096;
    #pragma unroll
    for (int h = 0; h < 4; ++h) {
        ushort4 u;
        u.x = f2b(acc[h][0]); u.y = f2b(acc[h][1]);
        u.z = f2b(acc[h][2]); u.w = f2b(acc[h][3]);
        *(ushort4*)(og + h * 1024 + t * 4) = u;
    }
}

// ==================== fused dual-phase bf16 MFMA GEMM + BN stats (L1/L2) ====================
// gload_lds staging with chunk-permuted global source (linear LDS dest); XCD-contig block swizzle.
#define SWZ(r, c) ((((c) ^ (((r) >> 1) & 3)) << 3))

template<int BM, int BN>
__global__ __launch_bounds__(256) void gemm2_kernel(
    const unsigned short* __restrict__ A1, int lda1, const unsigned short* __restrict__ W1, int K1,
    const unsigned short* __restrict__ A2, int lda2, const unsigned short* __restrict__ W2, int K2,
    int hs2, int cph2,
    unsigned short* __restrict__ C, int N,
    float* __restrict__ bnsum, float* __restrict__ bnsq)
{
    constexpr int WM = BM / 2, WN = BN / 2;
    constexpr int TM = WM / 16, TN = WN / 16;
    constexpr int APASS = (BM * 4) / 256, BPASS = (BN * 4) / 256;
    __shared__ __align__(16) unsigned short As[BM * 32];
    __shared__ __align__(16) unsigned short Bs[BN * 32];
    __shared__ float sbn[2 * BN];
    int tid = threadIdx.x;
    // XCD-bijective swizzle (nwg % 8 == 0 for both instantiations)
    int gx = gridDim.x;
    int nwg = gx * gridDim.y;
    int bid = blockIdx.y * gx + blockIdx.x;
    int cpx = nwg >> 3;
    int swz = (bid & 7) * cpx + (bid >> 3);
    int n0 = (swz % gx) * BN, m0 = (swz / gx) * BM;
    int l = tid & 63, l16 = l & 15, kq = l >> 4;
    int wid = tid >> 6, wr = wid >> 1, wc = wid & 1;

    f32x4 acc[TM][TN];
    #pragma unroll
    for (int mi = 0; mi < TM; ++mi)
        #pragma unroll
        for (int ni = 0; ni < TN; ++ni) acc[mi][ni] = (f32x4){0.f, 0.f, 0.f, 0.f};

    #pragma unroll
    for (int ph = 0; ph < 2; ++ph) {
        const unsigned short* Ap = ph ? A2 + (size_t)m0 * lda2 + (cph2 ? (size_t)(n0 / cph2) * hs2 : 0)
                                      : A1 + (size_t)m0 * lda1;
        int lda = ph ? lda2 : lda1;
        const unsigned short* Wp = ph ? W2 + (size_t)n0 * K2 : W1 + (size_t)n0 * K1;
        int ldw = ph ? K2 : K1;
        int K = ph ? K2 : K1;
        for (int k0 = 0; k0 < K; k0 += 32) {
            #pragma unroll
            for (int ps = 0; ps < APASS; ++ps) {
                int sbase = ps * 256 + wid * 64;
                int s = sbase + l;
                int r = s >> 2, cc = s & 3;
                gload_lds16(Ap + (size_t)r * lda + k0 + ((cc ^ ((r >> 1) & 3)) << 3),
                            &As[(size_t)sbase * 8]);
            }
            #pragma unroll
            for (int ps = 0; ps < BPASS; ++ps) {
                int sbase = ps * 256 + wid * 64;
                int s = sbase + l;
                int r = s >> 2, cc = s & 3;
                gload_lds16(Wp + (size_t)r * ldw + k0 + ((cc ^ ((r >> 1) & 3)) << 3),
                            &Bs[(size_t)sbase * 8]);
            }
            __syncthreads();
            short8 af[TM], bfr[TN];
            #pragma unroll
            for (int mi = 0; mi < TM; ++mi) {
                int r = wr * WM + mi * 16 + l16;
                af[mi] = *(const short8*)&As[r * 32 + SWZ(r, kq)];
            }
            #pragma unroll
            for (int ni = 0; ni < TN; ++ni) {
                int r = wc * WN + ni * 16 + l16;
                bfr[ni] = *(const short8*)&Bs[r * 32 + SWZ(r, kq)];
            }
            #pragma unroll
            for (int mi = 0; mi < TM; ++mi)
                #pragma unroll
                for (int ni = 0; ni < TN; ++ni)
                    acc[mi][ni] = __builtin_amdgcn_mfma_f32_16x16x32_bf16(
                        af[mi], bfr[ni], acc[mi][ni], 0, 0, 0);
            __syncthreads();
        }
    }

    if (tid < 2 * BN) sbn[tid] = 0.f;
    __syncthreads();

    #pragma unroll
    for (int ni = 0; ni < TN; ++ni) {
        int col = wc * WN + ni * 16 + l16;
        float s = 0.f, q = 0.f;
        #pragma unroll
        for (int mi = 0; mi < TM; ++mi) {
            int rowb = wr * WM + mi * 16 + (kq << 2);
            #pragma unroll
            for (int r = 0; r < 4; ++r) {
                float v = acc[mi][ni][r];
                C[(size_t)(m0 + rowb + r) * N + n0 + col] = f2b(v);
                s += v; q += v * v;
            }
        }
        atomicAdd(&sbn[col * 2 + 0], s);
        atomicAdd(&sbn[col * 2 + 1], q);
    }
    __syncthreads();
    if (tid < BN) {
        atomicAdd(&bnsum[n0 + tid], sbn[tid * 2 + 0]);
        atomicAdd(&bnsq[n0 + tid], sbn[tid * 2 + 1]);
    }
}

// ==================== L3: split-K GEMM -> Cpart[z][512][256] (deterministic) ====================
__global__ __launch_bounds__(256) void gemm3_splitk(
    const unsigned short* __restrict__ A1, const unsigned short* __restrict__ W1,
    const unsigned short* __restrict__ A2, const unsigned short* __restrict__ W2,
    float* __restrict__ Cpart)
{
    constexpr int BM = 64, BN = 64, WM = 32, WN = 32, TM = 2, TN = 2;
    __shared__ __align__(16) unsigned short As[BM * 32];
    __shared__ __align__(16) unsigned short Bs[BN * 32];
    int tid = threadIdx.x;
    int n0 = blockIdx.x * BN, m0 = blockIdx.y * BM;
    int z = blockIdx.z;
    int ph = (z >= 2);
    int ks = ph ? (z - 2) * 512 : z * 512;
    const unsigned short* Ap = ph ? A2 + (size_t)m0 * 4096 : A1 + (size_t)m0 * 1024;
    const unsigned short* Wp = ph ? W2 + (size_t)n0 * 4096 : W1 + (size_t)n0 * 1024;
    int lda = ph ? 4096 : 1024;
    int l = tid & 63, l16 = l & 15, kq = l >> 4;
    int wid = tid >> 6, wr = wid >> 1, wc = wid & 1;

    f32x4 acc[TM][TN];
    #pragma unroll
    for (int mi = 0; mi < TM; ++mi)
        #pragma unroll
        for (int ni = 0; ni < TN; ++ni) acc[mi][ni] = (f32x4){0.f, 0.f, 0.f, 0.f};

    for (int k0 = ks; k0 < ks + 512; k0 += 32) {
        {
            int sbase = wid * 64;
            int s = sbase + l;
            int r = s >> 2, cc = s & 3;
            gload_lds16(Ap + (size_t)r * lda + k0 + ((cc ^ ((r >> 1) & 3)) << 3),
                        &As[(size_t)sbase * 8]);
            gload_lds16(Wp + (size_t)r * lda + k0 + ((cc ^ ((r >> 1) & 3)) << 3),
                        &Bs[(size_t)sbase * 8]);
        }
        __syncthreads();
        short8 af[TM], bfr[TN];
        #pragma unroll
        for (int mi = 0; mi < TM; ++mi) {
            int r = wr * WM + mi * 16 + l16;
            af[mi] = *(const short8*)&As[r * 32 + SWZ(r, kq)];
        }
        #pragma unroll
        for (int ni = 0; ni < TN; ++ni) {
            int r = wc * WN + ni * 16 + l16;
            bfr[ni] = *(const short8*)&Bs[r * 32 + SWZ(r, kq)];
        }
        #pragma unroll
        for (int mi = 0; mi < TM; ++mi)
            #pragma unroll
            for (int ni = 0; ni < TN; ++ni)
                acc[mi][ni] = __builtin_amdgcn_mfma_f32_16x16x32_bf16(
                    af[mi], bfr[ni], acc[mi][ni], 0, 0, 0);
        __syncthreads();
    }

    float* Cz = Cpart + (size_t)z * S3 * 256;
    #pragma unroll
    for (int ni = 0; ni < TN; ++ni) {
        int col = wc * WN + ni * 16 + l16;
        #pragma unroll
        for (int mi = 0; mi < TM; ++mi) {
            int rowb = wr * WM + mi * 16 + (kq << 2);
            #pragma unroll
            for (int r = 0; r < 4; ++r)
                Cz[(size_t)(m0 + rowb + r) * 256 + n0 + col] = acc[mi][ni][r];
        }
    }
}

// reduce Cpart over z -> hb32, accumulate BN column stats
__global__ void bnstat3_kernel(const float* __restrict__ Cpart, float* __restrict__ hb32,
                               float* __restrict__ bnsum, float* __restrict__ bnsq)
{
    int c = threadIdx.x;
    int r0 = blockIdx.x * 64;
    float s = 0.f, q = 0.f;
    for (int r = r0; r < r0 + 64; ++r) {
        float v = 0.f;
        #pragma unroll
        for (int z = 0; z < 10; ++z)
            v += Cpart[((size_t)z * S3 + r) * 256 + c];
        hb32[(size_t)r * 256 + c] = v;
        s += v; q += v * v;
    }
    atomicAdd(&bnsum[c], s);
    atomicAdd(&bnsq[c], q);
}

// ==================== BN finalize fused into apply + ELU (8 elems/thread) ====================
__global__ void norm_elu_bb(const unsigned short* __restrict__ h,
                            const float* __restrict__ sum, const float* __restrict__ sq,
                            const float* __restrict__ gamma, const float* __restrict__ beta,
                            unsigned short* __restrict__ out, int N, float invM, long total)
{
    long i0 = ((long)blockIdx.x * 256 + threadIdx.x) * 8;
    if (i0 >= total) return;
    #pragma unroll
    for (int g = 0; g < 2; ++g) {
        long i = i0 + g * 4;
        int c = (int)(i % N);
        float4 sm = *(const float4*)(sum + c);
        float4 qq = *(const float4*)(sq + c);
        float4 gm = *(const float4*)(gamma + c);
        float4 bt = *(const float4*)(beta + c);
        float mu0 = sm.x * invM, mu1 = sm.y * invM, mu2 = sm.z * invM, mu3 = sm.w * invM;
        float sc0 = gm.x * rsqrtf(qq.x * invM - mu0 * mu0 + BN_EPS);
        float sc1 = gm.y * rsqrtf(qq.y * invM - mu1 * mu1 + BN_EPS);
        float sc2 = gm.z * rsqrtf(qq.z * invM - mu2 * mu2 + BN_EPS);
        float sc3 = gm.w * rsqrtf(qq.w * invM - mu3 * mu3 + BN_EPS);
        float sh0 = bt.x - mu0 * sc0, sh1 = bt.y - mu1 * sc1;
        float sh2 = bt.z - mu2 * sc2, sh3 = bt.w - mu3 * sc3;
        ushort4 u = *(const ushort4*)(h + i);
        float v0 = b2f(u.x) * sc0 + sh0;
        float v1 = b2f(u.y) * sc1 + sh1;
        float v2 = b2f(u.z) * sc2 + sh2;
        float v3 = b2f(u.w) * sc3 + sh3;
        v0 = v0 > 0.f ? v0 : expm1f(v0);
        v1 = v1 > 0.f ? v1 : expm1f(v1);
        v2 = v2 > 0.f ? v2 : expm1f(v2);
        v3 = v3 > 0.f ? v3 : expm1f(v3);
        ushort4 o;
        o.x = f2b(v0); o.y = f2b(v1); o.z = f2b(v2); o.w = f2b(v3);
        *(ushort4*)(out + i) = o;
    }
}

__global__ void norm_elu_ff(const float* __restrict__ h,
                            const float* __restrict__ sum, const float* __restrict__ sq,
                            const float* __restrict__ gamma, const float* __restrict__ beta,
                            float* __restrict__ out, int N, float invM, long total)
{
    long i = ((long)blockIdx.x * 256 + threadIdx.x) * 4;
    if (i >= total) return;
    int c = (int)(i % N);
    float4 sm = *(const float4*)(sum + c);
    float4 qq = *(const float4*)(sq + c);
    float4 gm = *(const float4*)(gamma + c);
    float4 bt = *(const float4*)(beta + c);
    float mu0 = sm.x * invM, mu1 = sm.y * invM, mu2 = sm.z * invM, mu3 = sm.w * invM;
    float sc0 = gm.x * rsqrtf(qq.x * invM - mu0 * mu0 + BN_EPS);
    float sc1 = gm.y * rsqrtf(qq.y * invM - mu1 * mu1 + BN_EPS);
    float sc2 = gm.z * rsqrtf(qq.z * invM - mu2 * mu2 + BN_EPS);
    float sc3 = gm.w * rsqrtf(qq.w * invM - mu3 * mu3 + BN_EPS);
    float4 hv = *(const float4*)(h + i);
    float4 o;
    o.x = hv.x * sc0 + (bt.x - mu0 * sc0);
    o.y = hv.y * sc1 + (bt.y - mu1 * sc1);
    o.z = hv.z * sc2 + (bt.z - mu2 * sc2);
    o.w = hv.w * sc3 + (bt.w - mu3 * sc3);
    o.x = o.x > 0.f ? o.x : expm1f(o.x);
    o.y = o.y > 0.f ? o.y : expm1f(o.y);
    o.z = o.z > 0.f ? o.z : expm1f(o.z);
    o.w = o.w > 0.f ? o.w : expm1f(o.w);
    *(float4*)(out + i) = o;
}

// =====================================================================
extern "C" void kernel_launch(void* const* d_in, const int* in_sizes, int n_in,
                              void* d_out, int out_size, void* d_ws, size_t ws_size,
                              hipStream_t stream)
{
    const float* x = (const float*)d_in[0];
    auto P = [&](int layer, int slot) -> const float* {
        return (const float*)d_in[1 + (layer - 1) * 9 + slot];
    };
    const int* edge_src[3] = { (const int*)d_in[28], (const int*)d_in[30], (const int*)d_in[32] };
    const int* edge_dst[3] = { (const int*)d_in[29], (const int*)d_in[31], (const int*)d_in[33] };

    // -------- workspace carve --------
    char* wsb = (char*)d_ws;
    size_t off = 0;
    auto alloc = [&](size_t bytes) -> void* {
        void* p = wsb + off;
        off = (off + bytes + 255) & ~(size_t)255;
        return p;
    };
    unsigned short* xb0   = (unsigned short*)alloc((size_t)N0 * 128 * 2);
    unsigned short* x1b   = (unsigned short*)alloc((size_t)S1 * 1024 * 2);
    unsigned short* x2b   = (unsigned short*)alloc((size_t)S2 * 1024 * 2);
    unsigned short* hb    = (unsigned short*)alloc((size_t)S1 * 1024 * 2);
    unsigned short* aggb  = (unsigned short*)alloc((size_t)S2 * 4096 * 2);
    unsigned short* wskipb[3] = {
        (unsigned short*)alloc(131072 * 2),
        (unsigned short*)alloc(1048576 * 2),
        (unsigned short*)alloc(262144 * 2) };
    unsigned short* wsrcb[3] = {
        (unsigned short*)alloc(131072 * 2),
        (unsigned short*)alloc(1048576 * 2),
        (unsigned short*)alloc(1048576 * 2) };
    float* vbuf[6];
    vbuf[0] = (float*)alloc(512 * 4);
    vbuf[1] = (float*)alloc(512 * 4);
    vbuf[2] = (float*)alloc(4096 * 4);
    vbuf[3] = (float*)alloc(4096 * 4);
    vbuf[4] = (float*)alloc(4096 * 4);
    vbuf[5] = (float*)alloc(4096 * 4);
    float* als     = (float*)alloc((size_t)N0 * 4 * 4);
    float* ald     = (float*)alloc((size_t)S1 * 4 * 4);
    float* aself   = (float*)alloc((size_t)S1 * 4 * 4);
    float* walpha  = (float*)alloc((size_t)E1 * 4 * 4);
    float* Cpart   = (float*)alloc((size_t)10 * S3 * 256 * 4);
    float* hb32    = (float*)alloc((size_t)S3 * 256 * 4);
    int* offsets3[3] = { (int*)alloc((S1 + 1) * 4), (int*)alloc((S2 + 1) * 4), (int*)alloc((S3 + 1) * 4) };
    int* cursor3 [3] = { (int*)alloc(S1 * 4), (int*)alloc(S2 * 4), (int*)alloc(S3 * 4) };
    int* slist3  [3] = { (int*)alloc(E1 * 4), (int*)alloc(E2 * 4), (int*)alloc(E3 * 4) };
    int zn = S1 + S2 + S3 + 6 * 1024;
    int* zreg = (int*)alloc((size_t)zn * 4);
    int* counts[3] = { zreg, zreg + S1, zreg + S1 + S2 };
    float* bnsum[3] = { (float*)(zreg + S1 + S2 + S3),
                        (float*)(zreg + S1 + S2 + S3 + 2048),
                        (float*)(zreg + S1 + S2 + S3 + 4096) };
    float* bnsq[3]  = { bnsum[0] + 1024, bnsum[1] + 1024, bnsum[2] + 1024 };

    // -------- one-shot prep: folds + weight bf16 + zeroing --------
    PrepArgs pa;
    for (int L = 0; L < 3; ++L) {
        pa.att[2 * L]     = P(L + 1, 2); pa.wf[2 * L]     = P(L + 1, 0); pa.v[2 * L]     = vbuf[2 * L];
        pa.att[2 * L + 1] = P(L + 1, 3); pa.wf[2 * L + 1] = P(L + 1, 1); pa.v[2 * L + 1] = vbuf[2 * L + 1];
    }
    pa.csrc[0] = P(1, 5); pa.cdst[0] = wskipb[0];
    pa.csrc[1] = P(1, 0); pa.cdst[1] = wsrcb[0];
    pa.csrc[2] = P(2, 5); pa.cdst[2] = wskipb[1];
    pa.csrc[3] = P(2, 0); pa.cdst[3] = wsrcb[1];
    pa.csrc[4] = P(3, 5); pa.cdst[4] = wskipb[2];
    pa.csrc[5] = P(3, 0); pa.cdst[5] = wsrcb[2];
    pa.zptr = zreg; pa.zn4 = zn / 4;
    prep_kernel<<<167, 256, 0, stream>>>(pa);

    // -------- CSR build for all layers --------
    CsrArgs ca;
    for (int L = 0; L < 3; ++L) {
        ca.edst[L] = edge_dst[L]; ca.esrc[L] = edge_src[L];
        ca.counts[L] = counts[L]; ca.offsets[L] = offsets3[L];
        ca.cursor[L] = cursor3[L]; ca.slist[L] = slist3[L];
    }
    ca.sizes[0] = S1; ca.sizes[1] = S2; ca.sizes[2] = S3;
    count_all<<<(E1 + E2 + E3) / 256, 256, 0, stream>>>(ca);
    scan_all<<<3, 1024, 0, stream>>>(ca);
    scatter_all<<<(E1 + E2 + E3) / 256, 256, 0, stream>>>(ca);

    // ---------------- layer 1 ----------------
    al128f_kernel<<<2048, 256, 0, stream>>>(x, vbuf[0], vbuf[1], xb0, als, ald, N0, S1);
    mdnw_kernel<<<(S1 + 3) / 4, 256, 0, stream>>>(als, ald, offsets3[0], slist3[0], S1, aself, walpha);
    agg128_kernel<<<S1, 64, 0, stream>>>(xb0, walpha, aself, offsets3[0], slist3[0], aggb);
    gemm2_kernel<128, 128><<<dim3(1024 / 128, S1 / 128), 256, 0, stream>>>(
        xb0, 128, wskipb[0], 128,
        aggb, 512, wsrcb[0], 128, 128, 256,
        hb, 1024, bnsum[0], bnsq[0]);
    norm_elu_bb<<<(int)(((long)S1 * 1024 / 8 + 255) / 256), 256, 0, stream>>>(
        hb, bnsum[0], bnsq[0], P(1, 7), P(1, 8), x1b, 1024, 1.f / S1, (long)S1 * 1024);

    // ---------------- layer 2 ----------------
    al1024d_kernel<<<576, 256, 0, stream>>>(x1b, vbuf[2], vbuf[3], als, ald, S1, S2, 512);
    mdnw_kernel<<<(S2 + 3) / 4, 256, 0, stream>>>(als, ald, offsets3[1], slist3[1], S2, aself, walpha);
    agg1024_kernel<<<S2, 256, 0, stream>>>(x1b, walpha, aself, offsets3[1], slist3[1], aggb);
    gemm2_kernel<64, 64><<<dim3(1024 / 64, S2 / 64), 256, 0, stream>>>(
        x1b, 1024, wskipb[1], 1024,
        aggb, 4096, wsrcb[1], 1024, 1024, 256,
        hb, 1024, bnsum[1], bnsq[1]);
    norm_elu_bb<<<(int)(((long)S2 * 1024 / 8 + 255) / 256), 256, 0, stream>>>(
        hb, bnsum[1], bnsq[1], P(2, 7), P(2, 8), x2b, 1024, 1.f / S2, (long)S2 * 1024);

    // ---------------- layer 3 ----------------
    al1024d_kernel<<<72, 256, 0, stream>>>(x2b, vbuf[4], vbuf[5], als, ald, S2, S3, 64);
    mdnw_kernel<<<(S3 + 3) / 4, 256, 0, stream>>>(als, ald, offsets3[2], slist3[2], S3, aself, walpha);
    agg1024_kernel<<<S3, 256, 0, stream>>>(x2b, walpha, aself, offsets3[2], slist3[2], aggb);
    gemm3_splitk<<<dim3(256 / 64, S3 / 64, 10), 256, 0, stream>>>(
        x2b, wskipb[2], aggb, wsrcb[2], Cpart);
    bnstat3_kernel<<<8, 256, 0, stream>>>(Cpart, hb32, bnsum[2], bnsq[2]);
    norm_elu_ff<<<(int)(((long)S3 * 256 / 4 + 255) / 256), 256, 0, stream>>>(
        hb32, bnsum[2], bnsq[2], P(3, 7), P(3, 8), (float*)d_out, 256, 1.f / S3, (long)S3 * 256);
}